// Round 4
// baseline (4399.391 us; speedup 1.0000x reference)
//
#include <hip/hip_runtime.h>

#define B_ 4
#define S_ 2048
#define H_ 1024
#define L_ 4
#define N_ 4
#define D_ 256
#define V_ 256
#define EPSF 1e-5f
#define WH_ ((size_t)H_ * H_)   // 1<<20

typedef __attribute__((ext_vector_type(8))) short short8;
typedef __attribute__((ext_vector_type(4))) float f32x4;

__device__ inline float bf2f(unsigned short u) {
    union { unsigned int ui; float f; } c; c.ui = ((unsigned int)u) << 16; return c.f;
}
__device__ inline unsigned short f2bf(float f) {
    union { float f; unsigned int ui; } c; c.f = f;
    unsigned int u = c.ui;
    unsigned int r = (u + 0x7FFFu + ((u >> 16) & 1u)) >> 16;
    return (unsigned short)r;
}
__device__ inline float wave64_sum(float v) {
    for (int m = 32; m >= 1; m >>= 1) v += __shfl_xor(v, m, 64);
    return v;
}
__device__ inline void gl_lds16(const unsigned short* g, unsigned short* l) {
    __builtin_amdgcn_global_load_lds(
        (const __attribute__((address_space(1))) unsigned int*)g,
        (__attribute__((address_space(3))) unsigned int*)l, 16, 0, 0);
}

// ---------------------------------------------------------------------------
__global__ void wcvt_kernel(const float* __restrict__ W,
                            unsigned short* __restrict__ Wb, int n8) {
    int idx = blockIdx.x * 256 + threadIdx.x;
    if (idx >= n8) return;
    size_t base = (size_t)idx * 8;
    float4 a0 = *(const float4*)(W + base);
    float4 a1 = *(const float4*)(W + base + 4);
    short8 t;
    t[0] = f2bf(a0.x); t[1] = f2bf(a0.y); t[2] = f2bf(a0.z); t[3] = f2bf(a0.w);
    t[4] = f2bf(a1.x); t[5] = f2bf(a1.y); t[6] = f2bf(a1.z); t[7] = f2bf(a1.w);
    *(short8*)(Wb + base) = t;
}

// fp32 -> bf16 into QKV-fused layout: src (L,WH) -> dst layer*3WH + sel*WH
__global__ void wcvt_qkv(const float* __restrict__ W,
                         unsigned short* __restrict__ Wb, int n8, int sel) {
    int idx = blockIdx.x * 256 + threadIdx.x;
    if (idx >= n8) return;
    size_t p = (size_t)idx * 8;
    size_t layer = p >> 20;
    size_t within = p & (WH_ - 1);
    size_t dst = layer * 3 * WH_ + (size_t)sel * WH_ + within;
    float4 a0 = *(const float4*)(W + p);
    float4 a1 = *(const float4*)(W + p + 4);
    short8 t;
    t[0] = f2bf(a0.x); t[1] = f2bf(a0.y); t[2] = f2bf(a0.z); t[3] = f2bf(a0.w);
    t[4] = f2bf(a1.x); t[5] = f2bf(a1.y); t[6] = f2bf(a1.z); t[7] = f2bf(a1.w);
    *(short8*)(Wb + dst) = t;
}

// combined weight: Wo = bf16(Wa + Wb2 + I) per HxH layer (layers contiguous)
__global__ void wadd_kernel(const float* __restrict__ Wa, const float* __restrict__ Wb2,
                            unsigned short* __restrict__ Wo, int n8) {
    int idx = blockIdx.x * 256 + threadIdx.x;
    if (idx >= n8) return;
    size_t base = (size_t)idx * 8;
    short8 t;
#pragma unroll
    for (int e = 0; e < 8; e++) {
        size_t p = base + e;
        int pos = (int)(p & (WH_ - 1));
        float v = Wa[p] + Wb2[p] + (((pos >> 10) == (pos & (H_ - 1))) ? 1.f : 0.f);
        t[e] = f2bf(v);
    }
    *(short8*)(Wo + base) = t;
}

// ---------------------------------------------------------------------------
__global__ void gather_kernel(const int* __restrict__ ids,
                              const float* __restrict__ embed,
                              unsigned short* __restrict__ x) {
    size_t idx = (size_t)blockIdx.x * 256 + threadIdx.x;
    int bs = (int)(idx >> 10);
    int h  = (int)(idx & 1023);
    x[idx] = f2bf(embed[(size_t)ids[bs] * H_ + h]);
}

__global__ void mean_kernel(const unsigned short* __restrict__ Xin,
                            float* __restrict__ xmean) {
    int idx = blockIdx.x * 256 + threadIdx.x;
    int b = idx >> 10, h = idx & 1023;
    int s0 = blockIdx.y * 128;
    const unsigned short* p = Xin + ((size_t)b * S_ + s0) * H_ + h;
    float s = 0.f;
    for (int i = 0; i < 128; i++) s += bf2f(p[(size_t)i * H_]);
    atomicAdd(&xmean[idx], s);
}

__global__ void nm_kernel(const float* __restrict__ xmean,
                          const float* __restrict__ w,
                          const float* __restrict__ bias,
                          float* __restrict__ dopnor) {
    int wave = threadIdx.x >> 6, lane = threadIdx.x & 63;
    for (int p = wave; p < 2 * B_; p += 4) {
        int b = p >> 1, j = p & 1;
        float s = 0.f;
        for (int h = lane; h < H_; h += 64) s += xmean[b * H_ + h] * w[j * H_ + h];
        s = wave64_sum(s);
        if (lane == 0) dopnor[p] = s / (float)S_ + bias[j];
    }
}

__global__ void gain_kernel(const float* __restrict__ xmean,
                            const float* __restrict__ gw,
                            const float* __restrict__ gb,
                            float* __restrict__ qscale) {
    int wave = threadIdx.x >> 6, lane = threadIdx.x & 63;
    for (int p = wave; p < B_ * N_; p += 4) {
        int b = p >> 2, n = p & 3;
        float s = 0.f;
        for (int h = lane; h < H_; h += 64) s += xmean[b * H_ + h] * gw[n * H_ + h];
        s = wave64_sum(s);
        if (lane == 0) qscale[p] = (1.f + s / (float)S_ + gb[n]) * 0.0625f;
    }
}

// ---------------------------------------------------------------------------
// GEMM (m97 structure): C(MxN) = epilogue( A(MxK) @ W(NxK)^T + bias )
// modes: 0 plain->bf16; 1 gate; 2 noise; 3 residual; 4 silu; 5 plain->fp32;
//        6 V^T store
// ---------------------------------------------------------------------------
__global__ __launch_bounds__(256) void gemm_bt(
    const unsigned short* __restrict__ A, const unsigned short* __restrict__ W,
    const float* __restrict__ bias, void* __restrict__ Cout,
    const unsigned short* __restrict__ X, const float* __restrict__ scal,
    int K, int Nout, int mode) {
    __shared__ unsigned short As[128 * 32];
    __shared__ unsigned short Bs[128 * 32];
    int tid = threadIdx.x;
    int wave = tid >> 6, lane = tid & 63;
    int quad = lane >> 4, l16 = lane & 15;
    int bm = blockIdx.x * 128;
    int bn = blockIdx.y * 128;
    int mw = (wave >> 1) * 64, nw = (wave & 1) * 64;

    const unsigned short* Ag = A + (size_t)(bm + wave * 16 + (lane >> 2)) * K + (lane & 3) * 8;
    const unsigned short* Wg = W + (size_t)(bn + wave * 16 + (lane >> 2)) * K + (lane & 3) * 8;
    unsigned short* ldsA = As + wave * 512;
    unsigned short* ldsB = Bs + wave * 512;
    size_t rowskip = (size_t)64 * K;

    f32x4 acc[4][4];
#pragma unroll
    for (int i = 0; i < 4; i++)
#pragma unroll
        for (int j = 0; j < 4; j++)
#pragma unroll
            for (int r = 0; r < 4; r++) acc[i][j][r] = 0.f;

    for (int kk = 0; kk < K; kk += 32) {
        __syncthreads();
        gl_lds16(Ag + kk, ldsA);
        gl_lds16(Ag + rowskip + kk, ldsA + 2048);
        gl_lds16(Wg + kk, ldsB);
        gl_lds16(Wg + rowskip + kk, ldsB + 2048);
        __syncthreads();

        short8 af[4], bfr[4];
#pragma unroll
        for (int i = 0; i < 4; i++)
            af[i] = *(const short8*)&As[(mw + i * 16 + l16) * 32 + quad * 8];
#pragma unroll
        for (int j = 0; j < 4; j++)
            bfr[j] = *(const short8*)&Bs[(nw + j * 16 + l16) * 32 + quad * 8];
#pragma unroll
        for (int i = 0; i < 4; i++)
#pragma unroll
            for (int j = 0; j < 4; j++)
                acc[i][j] = __builtin_amdgcn_mfma_f32_16x16x32_bf16(af[i], bfr[j], acc[i][j], 0, 0, 0);
    }

    if (mode == 6) {
#pragma unroll
        for (int i = 0; i < 4; i++) {
#pragma unroll
            for (int j = 0; j < 4; j++) {
                int col = bn + nw + j * 16 + l16;
                float bv = bias ? bias[col] : 0.f;
                int n = col >> 8, d = col & 255;
                int row0 = bm + mw + i * 16 + quad * 4;
                int b = row0 >> 11, s0 = row0 & 2047;
                union { unsigned short u[4]; uint2 v; } pk;
#pragma unroll
                for (int r = 0; r < 4; r++) pk.u[r] = f2bf(acc[i][j][r] + bv);
                *(uint2*)((unsigned short*)Cout +
                          ((size_t)(b * N_ + n) * D_ + d) * S_ + s0) = pk.v;
            }
        }
        return;
    }

#pragma unroll
    for (int i = 0; i < 4; i++) {
#pragma unroll
        for (int j = 0; j < 4; j++) {
            int col = bn + nw + j * 16 + l16;
            float bv = bias ? bias[col] : 0.f;
#pragma unroll
            for (int r = 0; r < 4; r++) {
                int row = bm + mw + i * 16 + quad * 4 + r;
                float v = acc[i][j][r] + bv;
                size_t off = (size_t)row * Nout + col;
                if (mode == 5) {
                    ((float*)Cout)[off] = v;
                    continue;
                }
                float outv;
                if (mode == 0) {
                    outv = v;
                } else if (mode == 1) {
                    float sig = 1.f / (1.f + __expf(-v));
                    float dop = scal[(row >> 11) * 2];
                    outv = bf2f(X[off]) * (1.f + dop * sig);
                } else if (mode == 2) {
                    float nor = scal[(row >> 11) * 2 + 1];
                    outv = bf2f(X[off]) + nor * tanhf(v);
                } else if (mode == 3) {
                    outv = v + bf2f(X[off]);
                } else {
                    outv = v * (1.f / (1.f + __expf(-v)));
                }
                ((unsigned short*)Cout)[off] = f2bf(outv);
            }
        }
    }
}

// ---------------------------------------------------------------------------
// Fused QKV GEMM: W is (3H x H) fused [q;k;v] for one layer. N=3072.
// col block (64-aligned) selects destination: 0 -> Q, 1 -> K, 2 -> V^T store.
// ---------------------------------------------------------------------------
__global__ __launch_bounds__(256) void gemm_qkv(
    const unsigned short* __restrict__ A, const unsigned short* __restrict__ W,
    const float* __restrict__ qb, const float* __restrict__ kb,
    const float* __restrict__ vbb, unsigned short* __restrict__ Qo,
    unsigned short* __restrict__ Ko, unsigned short* __restrict__ Vt) {
    __shared__ unsigned short As[128 * 32];
    __shared__ unsigned short Bs[128 * 32];
    const int K = H_;
    int tid = threadIdx.x;
    int wave = tid >> 6, lane = tid & 63;
    int quad = lane >> 4, l16 = lane & 15;
    int bm = blockIdx.x * 128;
    int bn = blockIdx.y * 128;
    int mw = (wave >> 1) * 64, nw = (wave & 1) * 64;

    const unsigned short* Ag = A + (size_t)(bm + wave * 16 + (lane >> 2)) * K + (lane & 3) * 8;
    const unsigned short* Wg = W + (size_t)(bn + wave * 16 + (lane >> 2)) * K + (lane & 3) * 8;
    unsigned short* ldsA = As + wave * 512;
    unsigned short* ldsB = Bs + wave * 512;
    size_t rowskip = (size_t)64 * K;

    f32x4 acc[4][4];
#pragma unroll
    for (int i = 0; i < 4; i++)
#pragma unroll
        for (int j = 0; j < 4; j++)
#pragma unroll
            for (int r = 0; r < 4; r++) acc[i][j][r] = 0.f;

    for (int kk = 0; kk < K; kk += 32) {
        __syncthreads();
        gl_lds16(Ag + kk, ldsA);
        gl_lds16(Ag + rowskip + kk, ldsA + 2048);
        gl_lds16(Wg + kk, ldsB);
        gl_lds16(Wg + rowskip + kk, ldsB + 2048);
        __syncthreads();

        short8 af[4], bfr[4];
#pragma unroll
        for (int i = 0; i < 4; i++)
            af[i] = *(const short8*)&As[(mw + i * 16 + l16) * 32 + quad * 8];
#pragma unroll
        for (int j = 0; j < 4; j++)
            bfr[j] = *(const short8*)&Bs[(nw + j * 16 + l16) * 32 + quad * 8];
#pragma unroll
        for (int i = 0; i < 4; i++)
#pragma unroll
            for (int j = 0; j < 4; j++)
                acc[i][j] = __builtin_amdgcn_mfma_f32_16x16x32_bf16(af[i], bfr[j], acc[i][j], 0, 0, 0);
    }

    int sel = (bn + nw) >> 10;   // uniform per block-half
    if (sel == 2) {
#pragma unroll
        for (int i = 0; i < 4; i++) {
#pragma unroll
            for (int j = 0; j < 4; j++) {
                int c2 = ((bn + nw) & 1023) + j * 16 + l16;
                float bv = vbb[c2];
                int n = c2 >> 8, d = c2 & 255;
                int row0 = bm + mw + i * 16 + quad * 4;
                int b = row0 >> 11, s0 = row0 & 2047;
                union { unsigned short u[4]; uint2 v; } pk;
#pragma unroll
                for (int r = 0; r < 4; r++) pk.u[r] = f2bf(acc[i][j][r] + bv);
                *(uint2*)(Vt + ((size_t)(b * N_ + n) * D_ + d) * S_ + s0) = pk.v;
            }
        }
    } else {
        unsigned short* Co = (sel == 0) ? Qo : Ko;
        const float* bias = (sel == 0) ? qb : kb;
#pragma unroll
        for (int i = 0; i < 4; i++) {
#pragma unroll
            for (int j = 0; j < 4; j++) {
                int c2 = ((bn + nw) & 1023) + j * 16 + l16;
                float bv = bias[c2];
#pragma unroll
                for (int r = 0; r < 4; r++) {
                    int row = bm + mw + i * 16 + quad * 4 + r;
                    Co[(size_t)row * H_ + c2] = f2bf(acc[i][j][r] + bv);
                }
            }
        }
    }
}

// ---------------------------------------------------------------------------
// Flash attention, round-4 (round-3 k-split with the merge-spill fix).
// 512 thr = 8 waves; wave w owns 32 q-rows (pair = w>>1) and HALF the
// k-range of each 64-wide tile (even wave k 0..31, odd 32..63). Independent
// online softmax per half; merged once at the end via flash merge.
// End-merge spill: pair p's 32x256 fp32 O tile (8192 floats) goes through
// Kb (pairs 0-1) / Vb (pairs 2-3); m/l through Pl. All dead at merge time.
// Per-wave LDS reads/iter: 16 kf + 16 vf + 2 pf + 1 ones = 35 b128 (was 68).
// Staging: double-buffered K/V via global_load_lds, both-sides XOR swizzle
// (slot ^= row&7), one vmcnt(0)+barrier per tile. Defer-max THR=8.
// LDS: 64K K-dbuf + 64K V-dbuf + 1.25K Vones + 20K Pl = 149.3 KiB.
// ---------------------------------------------------------------------------
__global__ __launch_bounds__(512) void flash_attn(
    const unsigned short* __restrict__ Q, const unsigned short* __restrict__ Kg,
    const unsigned short* __restrict__ VT, const float* __restrict__ qscale,
    unsigned short* __restrict__ O) {
    __shared__ unsigned short Kb[2][64 * 256];   // [buf][row*256 + col], swizzled slots
    __shared__ unsigned short Vb[2][256 * 64];   // [buf][d*64 + col], swizzled slots
    __shared__ unsigned short Vones[16][40];     // ones "column" tile for row-sum
    __shared__ unsigned short Pl[8][32][40];     // per-wave P (32 rows x 32 k)

    int tid = threadIdx.x;
    int wave = tid >> 6, lane = tid & 63;
    int quad = lane >> 4, l16 = lane & 15;
    int rx = l16 & 7;                            // read-side swizzle mask
    int pair = wave >> 1;
    int khalf = wave & 1;
    int koff = khalf * 32;                       // k-col offset within tile
    int kv0 = khalf * 4;                         // V^T slot offset (16B slots)
    int bnh = blockIdx.y;
    size_t base = ((size_t)(bnh >> 2) * S_) * H_ + (size_t)(bnh & 3) * D_;
    size_t vtbase = (size_t)bnh * D_ * S_;
    int qw = blockIdx.x * 128 + pair * 32;
    float scale = qscale[bnh];

    for (int c = tid; c < 16 * 40; c += 512) {
        int rr = c / 40, cc = c - rr * 40;
        Vones[rr][cc] = (rr == 0) ? (unsigned short)0x3F80 : (unsigned short)0;
    }

    // staging source-side swizzle lane constants
    int l5 = lane >> 5;                 // K: which of 2 rows in a 1KB chunk
    int ks = lane & 31;                 // K: lds slot within row (16B units)
    int vrow = lane >> 3;               // V: which of 8 rows in a 1KB chunk
    int vs = lane & 7;                  // V: lds slot within row
    int vmask = vrow & 7;

    short8 qf[2][8];
#pragma unroll
    for (int rt = 0; rt < 2; rt++)
#pragma unroll
        for (int kk = 0; kk < 8; kk++)
            qf[rt][kk] = *(const short8*)(Q + base +
                (size_t)(qw + rt * 16 + l16) * H_ + kk * 32 + quad * 8);

    f32x4 o[2][16], osum[2];
#pragma unroll
    for (int rt = 0; rt < 2; rt++) {
#pragma unroll
        for (int c = 0; c < 16; c++)
#pragma unroll
            for (int r = 0; r < 4; r++) o[rt][c][r] = 0.f;
#pragma unroll
        for (int r = 0; r < 4; r++) osum[rt][r] = 0.f;
    }
    float mrow[2][4];
#pragma unroll
    for (int rt = 0; rt < 2; rt++)
#pragma unroll
        for (int r = 0; r < 4; r++) mrow[rt][r] = -1e30f;

    // prologue: stage tile 0 into buffer 0
    {
#pragma unroll
        for (int k = 0; k < 4; k++) {
            int chunk = 4 * wave + k;
            int kmask = (2 * k + l5) & 7;
            int grow = 2 * chunk + l5;
            int gcol = (ks ^ kmask) * 8;
            gl_lds16(Kg + base + (size_t)grow * H_ + gcol, &Kb[0][chunk * 512]);
        }
#pragma unroll
        for (int k = 0; k < 4; k++) {
            int chunk = 4 * wave + k;
            int d = 8 * chunk + vrow;
            int gcol = (vs ^ vmask) * 8;
            gl_lds16(VT + vtbase + (size_t)d * S_ + gcol, &Vb[0][chunk * 512]);
        }
    }
    asm volatile("s_waitcnt vmcnt(0)" ::: "memory");
    __syncthreads();

    int cur = 0;
    for (int t0 = 0; t0 < S_; t0 += 64) {
        // issue next tile's loads into the other buffer (fly under compute)
        if (t0 + 64 < S_) {
            int nb = cur ^ 1;
#pragma unroll
            for (int k = 0; k < 4; k++) {
                int chunk = 4 * wave + k;
                int kmask = (2 * k + l5) & 7;
                int grow = t0 + 64 + 2 * chunk + l5;
                int gcol = (ks ^ kmask) * 8;
                gl_lds16(Kg + base + (size_t)grow * H_ + gcol, &Kb[nb][chunk * 512]);
            }
#pragma unroll
            for (int k = 0; k < 4; k++) {
                int chunk = 4 * wave + k;
                int d = 8 * chunk + vrow;
                int gcol = (vs ^ vmask) * 8;
                gl_lds16(VT + vtbase + (size_t)d * S_ + t0 + 64 + gcol, &Vb[nb][chunk * 512]);
            }
        }

        const unsigned short* Kc = Kb[cur];
        const unsigned short* Vc = Vb[cur];

        // QK^T: 32 q-rows x 32 k-cols (this wave's half), kf shared across rt
        f32x4 s[2][2];
#pragma unroll
        for (int rt = 0; rt < 2; rt++)
#pragma unroll
            for (int j = 0; j < 2; j++)
#pragma unroll
                for (int r = 0; r < 4; r++) s[rt][j][r] = 0.f;
#pragma unroll
        for (int j = 0; j < 2; j++)
#pragma unroll
            for (int kk = 0; kk < 8; kk++) {
                short8 kf = *(const short8*)&Kc[(koff + j * 16 + l16) * 256 +
                                                ((4 * kk + quad) ^ rx) * 8];
                s[0][j] = __builtin_amdgcn_mfma_f32_16x16x32_bf16(qf[0][kk], kf, s[0][j], 0, 0, 0);
                s[1][j] = __builtin_amdgcn_mfma_f32_16x16x32_bf16(qf[1][kk], kf, s[1][j], 0, 0, 0);
            }

        // online softmax (independent per k-half) with defer-max (THR=8)
        float sv[2][4][2], mx[2][4];
        bool ok = true;
#pragma unroll
        for (int rt = 0; rt < 2; rt++)
#pragma unroll
            for (int r = 0; r < 4; r++) {
                sv[rt][r][0] = s[rt][0][r] * scale;
                sv[rt][r][1] = s[rt][1][r] * scale;
                float m0 = fmaxf(sv[rt][r][0], sv[rt][r][1]);
                for (int m = 8; m >= 1; m >>= 1) m0 = fmaxf(m0, __shfl_xor(m0, m, 64));
                mx[rt][r] = m0;
                ok = ok && (m0 <= mrow[rt][r] + 8.f);
            }
        if (__all(ok)) {
#pragma unroll
            for (int rt = 0; rt < 2; rt++)
#pragma unroll
                for (int r = 0; r < 4; r++) {
                    Pl[wave][rt * 16 + quad * 4 + r][l16] =
                        f2bf(__expf(sv[rt][r][0] - mrow[rt][r]));
                    Pl[wave][rt * 16 + quad * 4 + r][16 + l16] =
                        f2bf(__expf(sv[rt][r][1] - mrow[rt][r]));
                }
        } else {
            float alpha[2][4];
#pragma unroll
            for (int rt = 0; rt < 2; rt++)
#pragma unroll
                for (int r = 0; r < 4; r++) {
                    float mnew = fmaxf(mrow[rt][r], mx[rt][r]);
                    alpha[rt][r] = __expf(mrow[rt][r] - mnew);
                    mrow[rt][r] = mnew;
                    Pl[wave][rt * 16 + quad * 4 + r][l16] =
                        f2bf(__expf(sv[rt][r][0] - mnew));
                    Pl[wave][rt * 16 + quad * 4 + r][16 + l16] =
                        f2bf(__expf(sv[rt][r][1] - mnew));
                }
#pragma unroll
            for (int rt = 0; rt < 2; rt++) {
#pragma unroll
                for (int c = 0; c < 16; c++)
#pragma unroll
                    for (int r = 0; r < 4; r++) o[rt][c][r] *= alpha[rt][r];
#pragma unroll
                for (int r = 0; r < 4; r++) osum[rt][r] *= alpha[rt][r];
            }
        }

        // PV: vf shared across both row-tiles
        short8 pf0 = *(const short8*)&Pl[wave][l16][quad * 8];
        short8 pf1 = *(const short8*)&Pl[wave][16 + l16][quad * 8];
#pragma unroll
        for (int c = 0; c < 16; c++) {
            short8 vf = *(const short8*)&Vc[(c * 16 + l16) * 64 + ((kv0 + quad) ^ rx) * 8];
            o[0][c] = __builtin_amdgcn_mfma_f32_16x16x32_bf16(pf0, vf, o[0][c], 0, 0, 0);
            o[1][c] = __builtin_amdgcn_mfma_f32_16x16x32_bf16(pf1, vf, o[1][c], 0, 0, 0);
        }
        {
            short8 vsf = *(const short8*)&Vones[l16][quad * 8];
            osum[0] = __builtin_amdgcn_mfma_f32_16x16x32_bf16(pf0, vsf, osum[0], 0, 0, 0);
            osum[1] = __builtin_amdgcn_mfma_f32_16x16x32_bf16(pf1, vsf, osum[1], 0, 0, 0);
        }

        // next tile must have landed; all waves done reading current buffers
        asm volatile("s_waitcnt vmcnt(0)" ::: "memory");
        __syncthreads();
        cur ^= 1;
    }

    // ---- end merge: odd half publishes (O, m, l); even half merges+writes.
    // Spill space: pair 0-1 -> Kb (2 x 8192 floats), pair 2-3 -> Vb.
    // m/l -> Pl (needs 256 floats; Pl is 20 KB). All LDS dead at this point.
    float* Of = (pair < 2) ? ((float*)&Kb[0][0] + pair * 8192)
                           : ((float*)&Vb[0][0] + (pair - 2) * 8192);
    float* Ml = (float*)&Pl[0][0][0];
    if (khalf) {
#pragma unroll
        for (int rt = 0; rt < 2; rt++)
#pragma unroll
            for (int c = 0; c < 16; c++) {
                int idx = ((((rt * 16 + c) * 4 + quad) * 16) + l16) * 4;
                *(f32x4*)&Of[idx] = o[rt][c];
            }
        if (l16 == 0) {
#pragma unroll
            for (int rt = 0; rt < 2; rt++)
#pragma unroll
                for (int r = 0; r < 4; r++) {
                    int row = rt * 16 + quad * 4 + r;
                    Ml[pair * 64 + row]      = mrow[rt][r];
                    Ml[pair * 64 + 32 + row] = osum[rt][r];
                }
        }
    }
    __syncthreads();
    if (!khalf) {
        float sca[2][4], scb[2][4];
#pragma unroll
        for (int rt = 0; rt < 2; rt++)
#pragma unroll
            for (int r = 0; r < 4; r++) {
                int row = rt * 16 + quad * 4 + r;
                float mb = Ml[pair * 64 + row];
                float lb = Ml[pair * 64 + 32 + row];
                float la = __shfl(osum[rt][r], (lane & 48), 64);
                float mm = fmaxf(mrow[rt][r], mb);
                float ea = __expf(mrow[rt][r] - mm);
                float eb = __expf(mb - mm);
                float inv = 1.f / (ea * la + eb * lb);
                sca[rt][r] = ea * inv;
                scb[rt][r] = eb * inv;
            }
#pragma unroll
        for (int rt = 0; rt < 2; rt++)
#pragma unroll
            for (int c = 0; c < 16; c++) {
                int idx = ((((rt * 16 + c) * 4 + quad) * 16) + l16) * 4;
                f32x4 ob = *(const f32x4*)&Of[idx];
#pragma unroll
                for (int r = 0; r < 4; r++) {
                    int row = qw + rt * 16 + quad * 4 + r;
                    int d = c * 16 + l16;
                    O[base + (size_t)row * H_ + d] =
                        f2bf(o[rt][c][r] * sca[rt][r] + ob[r] * scb[rt][r]);
                }
            }
    }
}

// ---------------------------------------------------------------------------
__global__ __launch_bounds__(256) void ln_kernel(
    const unsigned short* __restrict__ y, const float* __restrict__ g,
    const float* __restrict__ bta, unsigned short* __restrict__ out) {
    int row = blockIdx.x;
    size_t ro = (size_t)row * H_;
    int tid = threadIdx.x;
    float t[4]; float s = 0.f, s2 = 0.f;
#pragma unroll
    for (int i = 0; i < 4; i++) {
        int h = i * 256 + tid;
        float v = bf2f(y[ro + h]);
        t[i] = v; s += v; s2 += v * v;
    }
    s = wave64_sum(s); s2 = wave64_sum(s2);
    __shared__ float sh[8];
    int wave = tid >> 6, lane = tid & 63;
    if (lane == 0) { sh[wave] = s; sh[4 + wave] = s2; }
    __syncthreads();
    s  = sh[0] + sh[1] + sh[2] + sh[3];
    s2 = sh[4] + sh[5] + sh[6] + sh[7];
    float mu = s * (1.f / H_);
    float var = s2 * (1.f / H_) - mu * mu;
    float inv = rsqrtf(var + EPSF);
#pragma unroll
    for (int i = 0; i < 4; i++) {
        int h = i * 256 + tid;
        out[ro + h] = f2bf((t[i] - mu) * inv * g[h] + bta[h]);
    }
}

// ---------------------------------------------------------------------------
extern "C" void kernel_launch(void* const* d_in, const int* in_sizes, int n_in,
                              void* d_out, int out_size, void* d_ws, size_t ws_size,
                              hipStream_t stream) {
    const int*   ids          = (const int*)d_in[0];
    const float* embed        = (const float*)d_in[1];
    const float* nm_gate_w    = (const float*)d_in[2];
    const float* nm_gate_b    = (const float*)d_in[3];
    const float* nm_filter_w  = (const float*)d_in[4];
    const float* nm_filter_b  = (const float*)d_in[5];
    const float* nm_ctx_w     = (const float*)d_in[6];
    const float* nm_ctx_b     = (const float*)d_in[7];
    const float* q_w          = (const float*)d_in[8];
    const float* q_b          = (const float*)d_in[9];
    const float* k_w          = (const float*)d_in[10];
    const float* k_b          = (const float*)d_in[11];
    const float* v_w          = (const float*)d_in[12];
    const float* v_b          = (const float*)d_in[13];
    const float* gain_w       = (const float*)d_in[14];
    const float* gain_b       = (const float*)d_in[15];
    const float* attn_ow      = (const float*)d_in[16];
    const float* attn_ob      = (const float*)d_in[17];
    const float* en_w         = (const float*)d_in[18];
    const float* en_b         = (const float*)d_in[19];
    const float* plastic_w    = (const float*)d_in[20];
    const float* fix_w        = (const float*)d_in[21];
    const float* fix_b        = (const float*)d_in[22];
    const float* ln_g         = (const float*)d_in[23];
    const float* ln_b         = (const float*)d_in[24];
    const float* out_w        = (const float*)d_in[25];
    const float* out_b        = (const float*)d_in[26];

    size_t T  = (size_t)B_ * S_ * H_;
    size_t smallBytes = ((size_t)B_ * H_ + 2 * B_ + B_ * N_ + 8) * sizeof(float);
    size_t megaElems  = 26 * WH_ + WH_ / 4;
    size_t need_base  = 4 * T * 2 + smallBytes + 2 * WH_;
    size_t need_mega  = 4 * T * 2 + smallBytes + 2 * megaElems;
    if (ws_size < need_base) return;
    bool mega = ws_size >= need_mega;

    unsigned short* X   = (unsigned short*)d_ws;
    unsigned short* Qb  = X + T;
    unsigned short* Kb  = Qb + T;
    unsigned short* Vb  = Kb + T;
    float* xmean  = (float*)(Vb + T);
    float* dopnor = xmean + (size_t)B_ * H_;
    float* qscale = dopnor + 2 * B_;
    unsigned short* Wbase = (unsigned short*)(qscale + B_ * N_ + 8);
#define WOFF(k) (Wbase + (size_t)(k) * WH_)

    const int M   = B_ * S_;
    const int W8  = (int)(WH_ / 8);
    const int WG  = (W8 + 255) / 256;
    const int W84 = (int)(4 * WH_ / 8);
    const int WG4 = (W84 + 255) / 256;
    const int W8o = V_ * H_ / 8;
    const int WGo = (W8o + 255) / 256;

    if (mega) {
        wcvt_kernel<<<WG,  256, 0, stream>>>(nm_gate_w,   WOFF(0), W8);
        wcvt_kernel<<<WG,  256, 0, stream>>>(nm_filter_w, WOFF(1), W8);
        wcvt_qkv<<<WG4, 256, 0, stream>>>(q_w, WOFF(2), W84, 0);
        wcvt_qkv<<<WG4, 256, 0, stream>>>(k_w, WOFF(2), W84, 1);
        wcvt_qkv<<<WG4, 256, 0, stream>>>(v_w, WOFF(2), W84, 2);
        wcvt_kernel<<<WG4, 256, 0, stream>>>(attn_ow, WOFF(14), W84);
        wcvt_kernel<<<WG4, 256, 0, stream>>>(en_w,    WOFF(18), W84);
        wadd_kernel<<<WG4, 256, 0, stream>>>(fix_w, plastic_w, WOFF(22), W84);
        wcvt_kernel<<<WGo, 256, 0, stream>>>(out_w, WOFF(26), W8o);
    }

    gather_kernel<<<dim3((int)(T / 256)), 256, 0, stream>>>(ids, embed, X);

    hipMemsetAsync(xmean, 0, (size_t)B_ * H_ * sizeof(float), stream);
    mean_kernel<<<dim3(B_ * H_ / 256, 16), 256, 0, stream>>>(X, xmean);
    nm_kernel<<<1, 256, 0, stream>>>(xmean, nm_ctx_w, nm_ctx_b, dopnor);

    const unsigned short* Wp;
    if (mega) Wp = WOFF(0);
    else { wcvt_kernel<<<WG, 256, 0, stream>>>(nm_gate_w, Wbase, W8); Wp = Wbase; }
    gemm_bt<<<dim3(M / 128, H_ / 128), 256, 0, stream>>>(
        X, Wp, nm_gate_b, Qb, X, dopnor, H_, H_, 1);
    if (mega) Wp = WOFF(1);
    else { wcvt_kernel<<<WG, 256, 0, stream>>>(nm_filter_w, Wbase, W8); Wp = Wbase; }
    gemm_bt<<<dim3(M / 128, H_ / 128), 256, 0, stream>>>(
        Qb, Wp, nm_filter_b, X, Qb, dopnor, H_, H_, 2);

    for (int l = 0; l < L_; l++) {
        size_t wo = (size_t)l * WH_;
        size_t bo = (size_t)l * H_;
        hipMemsetAsync(xmean, 0, (size_t)B_ * H_ * sizeof(float), stream);
        mean_kernel<<<dim3(B_ * H_ / 256, 16), 256, 0, stream>>>(X, xmean);
        gain_kernel<<<1, 256, 0, stream>>>(xmean, gain_w + (size_t)l * N_ * H_,
                                           gain_b + (size_t)l * N_, qscale);

        if (mega) {
            gemm_qkv<<<dim3(M / 128, 3 * H_ / 128), 256, 0, stream>>>(
                X, WOFF(2) + (size_t)l * 3 * WH_, q_b + bo, k_b + bo, v_b + bo,
                Qb, Kb, Vb);
        } else {
            wcvt_kernel<<<WG, 256, 0, stream>>>(q_w + wo, Wbase, W8);
            gemm_bt<<<dim3(M / 128, H_ / 128), 256, 0, stream>>>(
                X, Wbase, q_b + bo, Qb, nullptr, nullptr, H_, H_, 0);
            wcvt_kernel<<<WG, 256, 0, stream>>>(k_w + wo, Wbase, W8);
            gemm_bt<<<dim3(M / 128, H_ / 128), 256, 0, stream>>>(
                X, Wbase, k_b + bo, Kb, nullptr, nullptr, H_, H_, 0);
            wcvt_kernel<<<WG, 256, 0, stream>>>(v_w + wo, Wbase, W8);
            gemm_bt<<<dim3(M / 128, H_ / 128), 256, 0, stream>>>(
                X, Wbase, v_b + bo, Vb, nullptr, nullptr, H_, H_, 6);
        }

        flash_attn<<<dim3(S_ / 128, B_ * N_), 512, 0, stream>>>(
            Qb, Kb, Vb, qscale, Qb);

        if (mega) Wp = WOFF(14) + wo;
        else { wcvt_kernel<<<WG, 256, 0, stream>>>(attn_ow + wo, Wbase, W8); Wp = Wbase; }
        gemm_bt<<<dim3(M / 128, H_ / 128), 256, 0, stream>>>(
            Qb, Wp, attn_ob + bo, Kb, X, nullptr, H_, H_, 3);
        if (mega) Wp = WOFF(18) + wo;
        else { wcvt_kernel<<<WG, 256, 0, stream>>>(en_w + wo, Wbase, W8); Wp = Wbase; }
        gemm_bt<<<dim3(M / 128, H_ / 128), 256, 0, stream>>>(
            Kb, Wp, en_b + bo, Vb, nullptr, nullptr, H_, H_, 4);
        if (mega) Wp = WOFF(22) + wo;
        else { wadd_kernel<<<WG, 256, 0, stream>>>(fix_w + wo, plastic_w + wo, Wbase, W8); Wp = Wbase; }
        gemm_bt<<<dim3(M / 128, H_ / 128), 256, 0, stream>>>(
            Vb, Wp, fix_b + bo, Qb, nullptr, nullptr, H_, H_, 0);
        ln_kernel<<<dim3(M), 256, 0, stream>>>(Qb, ln_g + bo, ln_b + bo, X);
    }

    if (mega) Wp = WOFF(26);
    else { wcvt_kernel<<<WGo, 256, 0, stream>>>(out_w, Wbase, W8o); Wp = Wbase; }
    gemm_bt<<<dim3(M / 128, V_ / 128), 256, 0, stream>>>(
        X, Wp, out_b, (float*)d_out, nullptr, nullptr, H_, V_, 5);
#undef WOFF
}

// Round 5
// 4250.454 us; speedup vs baseline: 1.0350x; 1.0350x over previous
//
#include <hip/hip_runtime.h>

#define B_ 4
#define S_ 2048
#define H_ 1024
#define L_ 4
#define N_ 4
#define D_ 256
#define V_ 256
#define EPSF 1e-5f
#define WH_ ((size_t)H_ * H_)   // 1<<20

typedef __attribute__((ext_vector_type(8))) short short8;
typedef __attribute__((ext_vector_type(4))) float f32x4;

__device__ inline float bf2f(unsigned short u) {
    union { unsigned int ui; float f; } c; c.ui = ((unsigned int)u) << 16; return c.f;
}
__device__ inline unsigned short f2bf(float f) {
    union { float f; unsigned int ui; } c; c.f = f;
    unsigned int u = c.ui;
    unsigned int r = (u + 0x7FFFu + ((u >> 16) & 1u)) >> 16;
    return (unsigned short)r;
}
__device__ inline float wave64_sum(float v) {
    for (int m = 32; m >= 1; m >>= 1) v += __shfl_xor(v, m, 64);
    return v;
}
__device__ inline void gl_lds16(const unsigned short* g, unsigned short* l) {
    __builtin_amdgcn_global_load_lds(
        (const __attribute__((address_space(1))) unsigned int*)g,
        (__attribute__((address_space(3))) unsigned int*)l, 16, 0, 0);
}

// ---------------------------------------------------------------------------
__global__ void wcvt_kernel(const float* __restrict__ W,
                            unsigned short* __restrict__ Wb, int n8) {
    int idx = blockIdx.x * 256 + threadIdx.x;
    if (idx >= n8) return;
    size_t base = (size_t)idx * 8;
    float4 a0 = *(const float4*)(W + base);
    float4 a1 = *(const float4*)(W + base + 4);
    short8 t;
    t[0] = f2bf(a0.x); t[1] = f2bf(a0.y); t[2] = f2bf(a0.z); t[3] = f2bf(a0.w);
    t[4] = f2bf(a1.x); t[5] = f2bf(a1.y); t[6] = f2bf(a1.z); t[7] = f2bf(a1.w);
    *(short8*)(Wb + base) = t;
}

// fp32 -> bf16 into QKV-fused layout: src (L,WH) -> dst layer*3WH + sel*WH
__global__ void wcvt_qkv(const float* __restrict__ W,
                         unsigned short* __restrict__ Wb, int n8, int sel) {
    int idx = blockIdx.x * 256 + threadIdx.x;
    if (idx >= n8) return;
    size_t p = (size_t)idx * 8;
    size_t layer = p >> 20;
    size_t within = p & (WH_ - 1);
    size_t dst = layer * 3 * WH_ + (size_t)sel * WH_ + within;
    float4 a0 = *(const float4*)(W + p);
    float4 a1 = *(const float4*)(W + p + 4);
    short8 t;
    t[0] = f2bf(a0.x); t[1] = f2bf(a0.y); t[2] = f2bf(a0.z); t[3] = f2bf(a0.w);
    t[4] = f2bf(a1.x); t[5] = f2bf(a1.y); t[6] = f2bf(a1.z); t[7] = f2bf(a1.w);
    *(short8*)(Wb + dst) = t;
}

// combined weight: Wo = bf16(Wa + Wb2 + I) per HxH layer (layers contiguous)
__global__ void wadd_kernel(const float* __restrict__ Wa, const float* __restrict__ Wb2,
                            unsigned short* __restrict__ Wo, int n8) {
    int idx = blockIdx.x * 256 + threadIdx.x;
    if (idx >= n8) return;
    size_t base = (size_t)idx * 8;
    short8 t;
#pragma unroll
    for (int e = 0; e < 8; e++) {
        size_t p = base + e;
        int pos = (int)(p & (WH_ - 1));
        float v = Wa[p] + Wb2[p] + (((pos >> 10) == (pos & (H_ - 1))) ? 1.f : 0.f);
        t[e] = f2bf(v);
    }
    *(short8*)(Wo + base) = t;
}

// ---------------------------------------------------------------------------
__global__ void gather_kernel(const int* __restrict__ ids,
                              const float* __restrict__ embed,
                              unsigned short* __restrict__ x) {
    size_t idx = (size_t)blockIdx.x * 256 + threadIdx.x;
    int bs = (int)(idx >> 10);
    int h  = (int)(idx & 1023);
    x[idx] = f2bf(embed[(size_t)ids[bs] * H_ + h]);
}

__global__ void mean_kernel(const unsigned short* __restrict__ Xin,
                            float* __restrict__ xmean) {
    int idx = blockIdx.x * 256 + threadIdx.x;
    int b = idx >> 10, h = idx & 1023;
    int s0 = blockIdx.y * 128;
    const unsigned short* p = Xin + ((size_t)b * S_ + s0) * H_ + h;
    float s = 0.f;
    for (int i = 0; i < 128; i++) s += bf2f(p[(size_t)i * H_]);
    atomicAdd(&xmean[idx], s);
}

__global__ void nm_kernel(const float* __restrict__ xmean,
                          const float* __restrict__ w,
                          const float* __restrict__ bias,
                          float* __restrict__ dopnor) {
    int wave = threadIdx.x >> 6, lane = threadIdx.x & 63;
    for (int p = wave; p < 2 * B_; p += 4) {
        int b = p >> 1, j = p & 1;
        float s = 0.f;
        for (int h = lane; h < H_; h += 64) s += xmean[b * H_ + h] * w[j * H_ + h];
        s = wave64_sum(s);
        if (lane == 0) dopnor[p] = s / (float)S_ + bias[j];
    }
}

__global__ void gain_kernel(const float* __restrict__ xmean,
                            const float* __restrict__ gw,
                            const float* __restrict__ gb,
                            float* __restrict__ qscale) {
    int wave = threadIdx.x >> 6, lane = threadIdx.x & 63;
    for (int p = wave; p < B_ * N_; p += 4) {
        int b = p >> 2, n = p & 3;
        float s = 0.f;
        for (int h = lane; h < H_; h += 64) s += xmean[b * H_ + h] * gw[n * H_ + h];
        s = wave64_sum(s);
        if (lane == 0) qscale[p] = (1.f + s / (float)S_ + gb[n]) * 0.0625f;
    }
}

// ---------------------------------------------------------------------------
// GEMM (m97 structure): C(MxN) = epilogue( A(MxK) @ W(NxK)^T + bias )
// modes: 0 plain->bf16; 1 gate; 2 noise; 3 residual; 4 silu; 5 plain->fp32;
//        6 V^T store
// ---------------------------------------------------------------------------
__global__ __launch_bounds__(256) void gemm_bt(
    const unsigned short* __restrict__ A, const unsigned short* __restrict__ W,
    const float* __restrict__ bias, void* __restrict__ Cout,
    const unsigned short* __restrict__ X, const float* __restrict__ scal,
    int K, int Nout, int mode) {
    __shared__ unsigned short As[128 * 32];
    __shared__ unsigned short Bs[128 * 32];
    int tid = threadIdx.x;
    int wave = tid >> 6, lane = tid & 63;
    int quad = lane >> 4, l16 = lane & 15;
    int bm = blockIdx.x * 128;
    int bn = blockIdx.y * 128;
    int mw = (wave >> 1) * 64, nw = (wave & 1) * 64;

    const unsigned short* Ag = A + (size_t)(bm + wave * 16 + (lane >> 2)) * K + (lane & 3) * 8;
    const unsigned short* Wg = W + (size_t)(bn + wave * 16 + (lane >> 2)) * K + (lane & 3) * 8;
    unsigned short* ldsA = As + wave * 512;
    unsigned short* ldsB = Bs + wave * 512;
    size_t rowskip = (size_t)64 * K;

    f32x4 acc[4][4];
#pragma unroll
    for (int i = 0; i < 4; i++)
#pragma unroll
        for (int j = 0; j < 4; j++)
#pragma unroll
            for (int r = 0; r < 4; r++) acc[i][j][r] = 0.f;

    for (int kk = 0; kk < K; kk += 32) {
        __syncthreads();
        gl_lds16(Ag + kk, ldsA);
        gl_lds16(Ag + rowskip + kk, ldsA + 2048);
        gl_lds16(Wg + kk, ldsB);
        gl_lds16(Wg + rowskip + kk, ldsB + 2048);
        __syncthreads();

        short8 af[4], bfr[4];
#pragma unroll
        for (int i = 0; i < 4; i++)
            af[i] = *(const short8*)&As[(mw + i * 16 + l16) * 32 + quad * 8];
#pragma unroll
        for (int j = 0; j < 4; j++)
            bfr[j] = *(const short8*)&Bs[(nw + j * 16 + l16) * 32 + quad * 8];
#pragma unroll
        for (int i = 0; i < 4; i++)
#pragma unroll
            for (int j = 0; j < 4; j++)
                acc[i][j] = __builtin_amdgcn_mfma_f32_16x16x32_bf16(af[i], bfr[j], acc[i][j], 0, 0, 0);
    }

    if (mode == 6) {
#pragma unroll
        for (int i = 0; i < 4; i++) {
#pragma unroll
            for (int j = 0; j < 4; j++) {
                int col = bn + nw + j * 16 + l16;
                float bv = bias ? bias[col] : 0.f;
                int n = col >> 8, d = col & 255;
                int row0 = bm + mw + i * 16 + quad * 4;
                int b = row0 >> 11, s0 = row0 & 2047;
                union { unsigned short u[4]; uint2 v; } pk;
#pragma unroll
                for (int r = 0; r < 4; r++) pk.u[r] = f2bf(acc[i][j][r] + bv);
                *(uint2*)((unsigned short*)Cout +
                          ((size_t)(b * N_ + n) * D_ + d) * S_ + s0) = pk.v;
            }
        }
        return;
    }

#pragma unroll
    for (int i = 0; i < 4; i++) {
#pragma unroll
        for (int j = 0; j < 4; j++) {
            int col = bn + nw + j * 16 + l16;
            float bv = bias ? bias[col] : 0.f;
#pragma unroll
            for (int r = 0; r < 4; r++) {
                int row = bm + mw + i * 16 + quad * 4 + r;
                float v = acc[i][j][r] + bv;
                size_t off = (size_t)row * Nout + col;
                if (mode == 5) {
                    ((float*)Cout)[off] = v;
                    continue;
                }
                float outv;
                if (mode == 0) {
                    outv = v;
                } else if (mode == 1) {
                    float sig = 1.f / (1.f + __expf(-v));
                    float dop = scal[(row >> 11) * 2];
                    outv = bf2f(X[off]) * (1.f + dop * sig);
                } else if (mode == 2) {
                    float nor = scal[(row >> 11) * 2 + 1];
                    outv = bf2f(X[off]) + nor * tanhf(v);
                } else if (mode == 3) {
                    outv = v + bf2f(X[off]);
                } else {
                    outv = v * (1.f / (1.f + __expf(-v)));
                }
                ((unsigned short*)Cout)[off] = f2bf(outv);
            }
        }
    }
}

// ---------------------------------------------------------------------------
// Fused QKV GEMM: W is (3H x H) fused [q;k;v] for one layer. N=3072.
// col block (64-aligned) selects destination: 0 -> Q, 1 -> K, 2 -> V^T store.
// ---------------------------------------------------------------------------
__global__ __launch_bounds__(256) void gemm_qkv(
    const unsigned short* __restrict__ A, const unsigned short* __restrict__ W,
    const float* __restrict__ qb, const float* __restrict__ kb,
    const float* __restrict__ vbb, unsigned short* __restrict__ Qo,
    unsigned short* __restrict__ Ko, unsigned short* __restrict__ Vt) {
    __shared__ unsigned short As[128 * 32];
    __shared__ unsigned short Bs[128 * 32];
    const int K = H_;
    int tid = threadIdx.x;
    int wave = tid >> 6, lane = tid & 63;
    int quad = lane >> 4, l16 = lane & 15;
    int bm = blockIdx.x * 128;
    int bn = blockIdx.y * 128;
    int mw = (wave >> 1) * 64, nw = (wave & 1) * 64;

    const unsigned short* Ag = A + (size_t)(bm + wave * 16 + (lane >> 2)) * K + (lane & 3) * 8;
    const unsigned short* Wg = W + (size_t)(bn + wave * 16 + (lane >> 2)) * K + (lane & 3) * 8;
    unsigned short* ldsA = As + wave * 512;
    unsigned short* ldsB = Bs + wave * 512;
    size_t rowskip = (size_t)64 * K;

    f32x4 acc[4][4];
#pragma unroll
    for (int i = 0; i < 4; i++)
#pragma unroll
        for (int j = 0; j < 4; j++)
#pragma unroll
            for (int r = 0; r < 4; r++) acc[i][j][r] = 0.f;

    for (int kk = 0; kk < K; kk += 32) {
        __syncthreads();
        gl_lds16(Ag + kk, ldsA);
        gl_lds16(Ag + rowskip + kk, ldsA + 2048);
        gl_lds16(Wg + kk, ldsB);
        gl_lds16(Wg + rowskip + kk, ldsB + 2048);
        __syncthreads();

        short8 af[4], bfr[4];
#pragma unroll
        for (int i = 0; i < 4; i++)
            af[i] = *(const short8*)&As[(mw + i * 16 + l16) * 32 + quad * 8];
#pragma unroll
        for (int j = 0; j < 4; j++)
            bfr[j] = *(const short8*)&Bs[(nw + j * 16 + l16) * 32 + quad * 8];
#pragma unroll
        for (int i = 0; i < 4; i++)
#pragma unroll
            for (int j = 0; j < 4; j++)
                acc[i][j] = __builtin_amdgcn_mfma_f32_16x16x32_bf16(af[i], bfr[j], acc[i][j], 0, 0, 0);
    }

    int sel = (bn + nw) >> 10;   // uniform per block-half
    if (sel == 2) {
#pragma unroll
        for (int i = 0; i < 4; i++) {
#pragma unroll
            for (int j = 0; j < 4; j++) {
                int c2 = ((bn + nw) & 1023) + j * 16 + l16;
                float bv = vbb[c2];
                int n = c2 >> 8, d = c2 & 255;
                int row0 = bm + mw + i * 16 + quad * 4;
                int b = row0 >> 11, s0 = row0 & 2047;
                union { unsigned short u[4]; uint2 v; } pk;
#pragma unroll
                for (int r = 0; r < 4; r++) pk.u[r] = f2bf(acc[i][j][r] + bv);
                *(uint2*)(Vt + ((size_t)(b * N_ + n) * D_ + d) * S_ + s0) = pk.v;
            }
        }
    } else {
        unsigned short* Co = (sel == 0) ? Qo : Ko;
        const float* bias = (sel == 0) ? qb : kb;
#pragma unroll
        for (int i = 0; i < 4; i++) {
#pragma unroll
            for (int j = 0; j < 4; j++) {
                int c2 = ((bn + nw) & 1023) + j * 16 + l16;
                float bv = bias[c2];
#pragma unroll
                for (int r = 0; r < 4; r++) {
                    int row = bm + mw + i * 16 + quad * 4 + r;
                    Co[(size_t)row * H_ + c2] = f2bf(acc[i][j][r] + bv);
                }
            }
        }
    }
}

// ---------------------------------------------------------------------------
// Flash attention, round-5: round-4 k-split + __launch_bounds__(512, 2).
// Round-4 failure: default launch_bounds target capped VGPR at 128 while the
// per-thread state (o[2][16] fp32 + qf[2][8] bf16 ~ 230 VGPR) needs ~230 ->
// ~100 VGPRs spilled to scratch -> 2.6 GB/dispatch HBM scratch traffic
// (FETCH 1.49 GB, WRITE 1.22 GB), 780 us. The (512,2) bound = 2 waves/EU
// gives the 256-VGPR budget; one 8-wave block/CU is all LDS admits anyway.
// Design (validated correct in round 4): wave w owns 32 q-rows (pair=w>>1)
// and HALF the k-range (even wave k 0..31, odd 32..63); independent online
// softmax per half, merged once at the end through dead LDS buffers.
// Per-wave LDS reads/iter: 16 kf + 16 vf + 2 pf + 1 ones = 35 b128 (was 68).
// Staging: double-buffered K/V via global_load_lds, both-sides XOR swizzle
// (slot ^= row&7), one vmcnt(0)+barrier per tile. Defer-max THR=8.
// LDS: 64K K-dbuf + 64K V-dbuf + 1.25K Vones + 20K Pl = 149.3 KiB.
// ---------------------------------------------------------------------------
__global__ __launch_bounds__(512, 2) void flash_attn(
    const unsigned short* __restrict__ Q, const unsigned short* __restrict__ Kg,
    const unsigned short* __restrict__ VT, const float* __restrict__ qscale,
    unsigned short* __restrict__ O) {
    __shared__ unsigned short Kb[2][64 * 256];   // [buf][row*256 + col], swizzled slots
    __shared__ unsigned short Vb[2][256 * 64];   // [buf][d*64 + col], swizzled slots
    __shared__ unsigned short Vones[16][40];     // ones "column" tile for row-sum
    __shared__ unsigned short Pl[8][32][40];     // per-wave P (32 rows x 32 k)

    int tid = threadIdx.x;
    int wave = tid >> 6, lane = tid & 63;
    int quad = lane >> 4, l16 = lane & 15;
    int rx = l16 & 7;                            // read-side swizzle mask
    int pair = wave >> 1;
    int khalf = wave & 1;
    int koff = khalf * 32;                       // k-col offset within tile
    int kv0 = khalf * 4;                         // V^T slot offset (16B slots)
    int bnh = blockIdx.y;
    size_t base = ((size_t)(bnh >> 2) * S_) * H_ + (size_t)(bnh & 3) * D_;
    size_t vtbase = (size_t)bnh * D_ * S_;
    int qw = blockIdx.x * 128 + pair * 32;
    float scale = qscale[bnh];

    for (int c = tid; c < 16 * 40; c += 512) {
        int rr = c / 40, cc = c - rr * 40;
        Vones[rr][cc] = (rr == 0) ? (unsigned short)0x3F80 : (unsigned short)0;
    }

    // staging source-side swizzle lane constants
    int l5 = lane >> 5;                 // K: which of 2 rows in a 1KB chunk
    int ks = lane & 31;                 // K: lds slot within row (16B units)
    int vrow = lane >> 3;               // V: which of 8 rows in a 1KB chunk
    int vs = lane & 7;                  // V: lds slot within row
    int vmask = vrow & 7;

    short8 qf[2][8];
#pragma unroll
    for (int rt = 0; rt < 2; rt++)
#pragma unroll
        for (int kk = 0; kk < 8; kk++)
            qf[rt][kk] = *(const short8*)(Q + base +
                (size_t)(qw + rt * 16 + l16) * H_ + kk * 32 + quad * 8);

    f32x4 o[2][16], osum[2];
#pragma unroll
    for (int rt = 0; rt < 2; rt++) {
#pragma unroll
        for (int c = 0; c < 16; c++)
#pragma unroll
            for (int r = 0; r < 4; r++) o[rt][c][r] = 0.f;
#pragma unroll
        for (int r = 0; r < 4; r++) osum[rt][r] = 0.f;
    }
    float mrow[2][4];
#pragma unroll
    for (int rt = 0; rt < 2; rt++)
#pragma unroll
        for (int r = 0; r < 4; r++) mrow[rt][r] = -1e30f;

    // prologue: stage tile 0 into buffer 0
    {
#pragma unroll
        for (int k = 0; k < 4; k++) {
            int chunk = 4 * wave + k;
            int kmask = (2 * k + l5) & 7;
            int grow = 2 * chunk + l5;
            int gcol = (ks ^ kmask) * 8;
            gl_lds16(Kg + base + (size_t)grow * H_ + gcol, &Kb[0][chunk * 512]);
        }
#pragma unroll
        for (int k = 0; k < 4; k++) {
            int chunk = 4 * wave + k;
            int d = 8 * chunk + vrow;
            int gcol = (vs ^ vmask) * 8;
            gl_lds16(VT + vtbase + (size_t)d * S_ + gcol, &Vb[0][chunk * 512]);
        }
    }
    asm volatile("s_waitcnt vmcnt(0)" ::: "memory");
    __syncthreads();

    int cur = 0;
    for (int t0 = 0; t0 < S_; t0 += 64) {
        // issue next tile's loads into the other buffer (fly under compute)
        if (t0 + 64 < S_) {
            int nb = cur ^ 1;
#pragma unroll
            for (int k = 0; k < 4; k++) {
                int chunk = 4 * wave + k;
                int kmask = (2 * k + l5) & 7;
                int grow = t0 + 64 + 2 * chunk + l5;
                int gcol = (ks ^ kmask) * 8;
                gl_lds16(Kg + base + (size_t)grow * H_ + gcol, &Kb[nb][chunk * 512]);
            }
#pragma unroll
            for (int k = 0; k < 4; k++) {
                int chunk = 4 * wave + k;
                int d = 8 * chunk + vrow;
                int gcol = (vs ^ vmask) * 8;
                gl_lds16(VT + vtbase + (size_t)d * S_ + t0 + 64 + gcol, &Vb[nb][chunk * 512]);
            }
        }

        const unsigned short* Kc = Kb[cur];
        const unsigned short* Vc = Vb[cur];

        // QK^T: 32 q-rows x 32 k-cols (this wave's half), kf shared across rt
        f32x4 s[2][2];
#pragma unroll
        for (int rt = 0; rt < 2; rt++)
#pragma unroll
            for (int j = 0; j < 2; j++)
#pragma unroll
                for (int r = 0; r < 4; r++) s[rt][j][r] = 0.f;
#pragma unroll
        for (int j = 0; j < 2; j++)
#pragma unroll
            for (int kk = 0; kk < 8; kk++) {
                short8 kf = *(const short8*)&Kc[(koff + j * 16 + l16) * 256 +
                                                ((4 * kk + quad) ^ rx) * 8];
                s[0][j] = __builtin_amdgcn_mfma_f32_16x16x32_bf16(qf[0][kk], kf, s[0][j], 0, 0, 0);
                s[1][j] = __builtin_amdgcn_mfma_f32_16x16x32_bf16(qf[1][kk], kf, s[1][j], 0, 0, 0);
            }

        // online softmax (independent per k-half) with defer-max (THR=8)
        float sv[2][4][2], mx[2][4];
        bool ok = true;
#pragma unroll
        for (int rt = 0; rt < 2; rt++)
#pragma unroll
            for (int r = 0; r < 4; r++) {
                sv[rt][r][0] = s[rt][0][r] * scale;
                sv[rt][r][1] = s[rt][1][r] * scale;
                float m0 = fmaxf(sv[rt][r][0], sv[rt][r][1]);
                for (int m = 8; m >= 1; m >>= 1) m0 = fmaxf(m0, __shfl_xor(m0, m, 64));
                mx[rt][r] = m0;
                ok = ok && (m0 <= mrow[rt][r] + 8.f);
            }
        if (__all(ok)) {
#pragma unroll
            for (int rt = 0; rt < 2; rt++)
#pragma unroll
                for (int r = 0; r < 4; r++) {
                    Pl[wave][rt * 16 + quad * 4 + r][l16] =
                        f2bf(__expf(sv[rt][r][0] - mrow[rt][r]));
                    Pl[wave][rt * 16 + quad * 4 + r][16 + l16] =
                        f2bf(__expf(sv[rt][r][1] - mrow[rt][r]));
                }
        } else {
            float alpha[2][4];
#pragma unroll
            for (int rt = 0; rt < 2; rt++)
#pragma unroll
                for (int r = 0; r < 4; r++) {
                    float mnew = fmaxf(mrow[rt][r], mx[rt][r]);
                    alpha[rt][r] = __expf(mrow[rt][r] - mnew);
                    mrow[rt][r] = mnew;
                    Pl[wave][rt * 16 + quad * 4 + r][l16] =
                        f2bf(__expf(sv[rt][r][0] - mnew));
                    Pl[wave][rt * 16 + quad * 4 + r][16 + l16] =
                        f2bf(__expf(sv[rt][r][1] - mnew));
                }
#pragma unroll
            for (int rt = 0; rt < 2; rt++) {
#pragma unroll
                for (int c = 0; c < 16; c++)
#pragma unroll
                    for (int r = 0; r < 4; r++) o[rt][c][r] *= alpha[rt][r];
#pragma unroll
                for (int r = 0; r < 4; r++) osum[rt][r] *= alpha[rt][r];
            }
        }

        // PV: vf shared across both row-tiles
        short8 pf0 = *(const short8*)&Pl[wave][l16][quad * 8];
        short8 pf1 = *(const short8*)&Pl[wave][16 + l16][quad * 8];
#pragma unroll
        for (int c = 0; c < 16; c++) {
            short8 vf = *(const short8*)&Vc[(c * 16 + l16) * 64 + ((kv0 + quad) ^ rx) * 8];
            o[0][c] = __builtin_amdgcn_mfma_f32_16x16x32_bf16(pf0, vf, o[0][c], 0, 0, 0);
            o[1][c] = __builtin_amdgcn_mfma_f32_16x16x32_bf16(pf1, vf, o[1][c], 0, 0, 0);
        }
        {
            short8 vsf = *(const short8*)&Vones[l16][quad * 8];
            osum[0] = __builtin_amdgcn_mfma_f32_16x16x32_bf16(pf0, vsf, osum[0], 0, 0, 0);
            osum[1] = __builtin_amdgcn_mfma_f32_16x16x32_bf16(pf1, vsf, osum[1], 0, 0, 0);
        }

        // next tile must have landed; all waves done reading current buffers
        asm volatile("s_waitcnt vmcnt(0)" ::: "memory");
        __syncthreads();
        cur ^= 1;
    }

    // ---- end merge: odd half publishes (O, m, l); even half merges+writes.
    // Spill space: pair 0-1 -> Kb (2 x 8192 floats), pair 2-3 -> Vb.
    // m/l -> Pl (needs 256 floats; Pl is 20 KB). All LDS dead at this point.
    float* Of = (pair < 2) ? ((float*)&Kb[0][0] + pair * 8192)
                           : ((float*)&Vb[0][0] + (pair - 2) * 8192);
    float* Ml = (float*)&Pl[0][0][0];
    if (khalf) {
#pragma unroll
        for (int rt = 0; rt < 2; rt++)
#pragma unroll
            for (int c = 0; c < 16; c++) {
                int idx = ((((rt * 16 + c) * 4 + quad) * 16) + l16) * 4;
                *(f32x4*)&Of[idx] = o[rt][c];
            }
        if (l16 == 0) {
#pragma unroll
            for (int rt = 0; rt < 2; rt++)
#pragma unroll
                for (int r = 0; r < 4; r++) {
                    int row = rt * 16 + quad * 4 + r;
                    Ml[pair * 64 + row]      = mrow[rt][r];
                    Ml[pair * 64 + 32 + row] = osum[rt][r];
                }
        }
    }
    __syncthreads();
    if (!khalf) {
        float sca[2][4], scb[2][4];
#pragma unroll
        for (int rt = 0; rt < 2; rt++)
#pragma unroll
            for (int r = 0; r < 4; r++) {
                int row = rt * 16 + quad * 4 + r;
                float mb = Ml[pair * 64 + row];
                float lb = Ml[pair * 64 + 32 + row];
                float la = __shfl(osum[rt][r], (lane & 48), 64);
                float mm = fmaxf(mrow[rt][r], mb);
                float ea = __expf(mrow[rt][r] - mm);
                float eb = __expf(mb - mm);
                float inv = 1.f / (ea * la + eb * lb);
                sca[rt][r] = ea * inv;
                scb[rt][r] = eb * inv;
            }
#pragma unroll
        for (int rt = 0; rt < 2; rt++)
#pragma unroll
            for (int c = 0; c < 16; c++) {
                int idx = ((((rt * 16 + c) * 4 + quad) * 16) + l16) * 4;
                f32x4 ob = *(const f32x4*)&Of[idx];
#pragma unroll
                for (int r = 0; r < 4; r++) {
                    int row = qw + rt * 16 + quad * 4 + r;
                    int d = c * 16 + l16;
                    O[base + (size_t)row * H_ + d] =
                        f2bf(o[rt][c][r] * sca[rt][r] + ob[r] * scb[rt][r]);
                }
            }
    }
}

// ---------------------------------------------------------------------------
__global__ __launch_bounds__(256) void ln_kernel(
    const unsigned short* __restrict__ y, const float* __restrict__ g,
    const float* __restrict__ bta, unsigned short* __restrict__ out) {
    int row = blockIdx.x;
    size_t ro = (size_t)row * H_;
    int tid = threadIdx.x;
    float t[4]; float s = 0.f, s2 = 0.f;
#pragma unroll
    for (int i = 0; i < 4; i++) {
        int h = i * 256 + tid;
        float v = bf2f(y[ro + h]);
        t[i] = v; s += v; s2 += v * v;
    }
    s = wave64_sum(s); s2 = wave64_sum(s2);
    __shared__ float sh[8];
    int wave = tid >> 6, lane = tid & 63;
    if (lane == 0) { sh[wave] = s; sh[4 + wave] = s2; }
    __syncthreads();
    s  = sh[0] + sh[1] + sh[2] + sh[3];
    s2 = sh[4] + sh[5] + sh[6] + sh[7];
    float mu = s * (1.f / H_);
    float var = s2 * (1.f / H_) - mu * mu;
    float inv = rsqrtf(var + EPSF);
#pragma unroll
    for (int i = 0; i < 4; i++) {
        int h = i * 256 + tid;
        out[ro + h] = f2bf((t[i] - mu) * inv * g[h] + bta[h]);
    }
}

// ---------------------------------------------------------------------------
extern "C" void kernel_launch(void* const* d_in, const int* in_sizes, int n_in,
                              void* d_out, int out_size, void* d_ws, size_t ws_size,
                              hipStream_t stream) {
    const int*   ids          = (const int*)d_in[0];
    const float* embed        = (const float*)d_in[1];
    const float* nm_gate_w    = (const float*)d_in[2];
    const float* nm_gate_b    = (const float*)d_in[3];
    const float* nm_filter_w  = (const float*)d_in[4];
    const float* nm_filter_b  = (const float*)d_in[5];
    const float* nm_ctx_w     = (const float*)d_in[6];
    const float* nm_ctx_b     = (const float*)d_in[7];
    const float* q_w          = (const float*)d_in[8];
    const float* q_b          = (const float*)d_in[9];
    const float* k_w          = (const float*)d_in[10];
    const float* k_b          = (const float*)d_in[11];
    const float* v_w          = (const float*)d_in[12];
    const float* v_b          = (const float*)d_in[13];
    const float* gain_w       = (const float*)d_in[14];
    const float* gain_b       = (const float*)d_in[15];
    const float* attn_ow      = (const float*)d_in[16];
    const float* attn_ob      = (const float*)d_in[17];
    const float* en_w         = (const float*)d_in[18];
    const float* en_b         = (const float*)d_in[19];
    const float* plastic_w    = (const float*)d_in[20];
    const float* fix_w        = (const float*)d_in[21];
    const float* fix_b        = (const float*)d_in[22];
    const float* ln_g         = (const float*)d_in[23];
    const float* ln_b         = (const float*)d_in[24];
    const float* out_w        = (const float*)d_in[25];
    const float* out_b        = (const float*)d_in[26];

    size_t T  = (size_t)B_ * S_ * H_;
    size_t smallBytes = ((size_t)B_ * H_ + 2 * B_ + B_ * N_ + 8) * sizeof(float);
    size_t megaElems  = 26 * WH_ + WH_ / 4;
    size_t need_base  = 4 * T * 2 + smallBytes + 2 * WH_;
    size_t need_mega  = 4 * T * 2 + smallBytes + 2 * megaElems;
    if (ws_size < need_base) return;
    bool mega = ws_size >= need_mega;

    unsigned short* X   = (unsigned short*)d_ws;
    unsigned short* Qb  = X + T;
    unsigned short* Kb  = Qb + T;
    unsigned short* Vb  = Kb + T;
    float* xmean  = (float*)(Vb + T);
    float* dopnor = xmean + (size_t)B_ * H_;
    float* qscale = dopnor + 2 * B_;
    unsigned short* Wbase = (unsigned short*)(qscale + B_ * N_ + 8);
#define WOFF(k) (Wbase + (size_t)(k) * WH_)

    const int M   = B_ * S_;
    const int W8  = (int)(WH_ / 8);
    const int WG  = (W8 + 255) / 256;
    const int W84 = (int)(4 * WH_ / 8);
    const int WG4 = (W84 + 255) / 256;
    const int W8o = V_ * H_ / 8;
    const int WGo = (W8o + 255) / 256;

    if (mega) {
        wcvt_kernel<<<WG,  256, 0, stream>>>(nm_gate_w,   WOFF(0), W8);
        wcvt_kernel<<<WG,  256, 0, stream>>>(nm_filter_w, WOFF(1), W8);
        wcvt_qkv<<<WG4, 256, 0, stream>>>(q_w, WOFF(2), W84, 0);
        wcvt_qkv<<<WG4, 256, 0, stream>>>(k_w, WOFF(2), W84, 1);
        wcvt_qkv<<<WG4, 256, 0, stream>>>(v_w, WOFF(2), W84, 2);
        wcvt_kernel<<<WG4, 256, 0, stream>>>(attn_ow, WOFF(14), W84);
        wcvt_kernel<<<WG4, 256, 0, stream>>>(en_w,    WOFF(18), W84);
        wadd_kernel<<<WG4, 256, 0, stream>>>(fix_w, plastic_w, WOFF(22), W84);
        wcvt_kernel<<<WGo, 256, 0, stream>>>(out_w, WOFF(26), W8o);
    }

    gather_kernel<<<dim3((int)(T / 256)), 256, 0, stream>>>(ids, embed, X);

    hipMemsetAsync(xmean, 0, (size_t)B_ * H_ * sizeof(float), stream);
    mean_kernel<<<dim3(B_ * H_ / 256, 16), 256, 0, stream>>>(X, xmean);
    nm_kernel<<<1, 256, 0, stream>>>(xmean, nm_ctx_w, nm_ctx_b, dopnor);

    const unsigned short* Wp;
    if (mega) Wp = WOFF(0);
    else { wcvt_kernel<<<WG, 256, 0, stream>>>(nm_gate_w, Wbase, W8); Wp = Wbase; }
    gemm_bt<<<dim3(M / 128, H_ / 128), 256, 0, stream>>>(
        X, Wp, nm_gate_b, Qb, X, dopnor, H_, H_, 1);
    if (mega) Wp = WOFF(1);
    else { wcvt_kernel<<<WG, 256, 0, stream>>>(nm_filter_w, Wbase, W8); Wp = Wbase; }
    gemm_bt<<<dim3(M / 128, H_ / 128), 256, 0, stream>>>(
        Qb, Wp, nm_filter_b, X, Qb, dopnor, H_, H_, 2);

    for (int l = 0; l < L_; l++) {
        size_t wo = (size_t)l * WH_;
        size_t bo = (size_t)l * H_;
        hipMemsetAsync(xmean, 0, (size_t)B_ * H_ * sizeof(float), stream);
        mean_kernel<<<dim3(B_ * H_ / 256, 16), 256, 0, stream>>>(X, xmean);
        gain_kernel<<<1, 256, 0, stream>>>(xmean, gain_w + (size_t)l * N_ * H_,
                                           gain_b + (size_t)l * N_, qscale);

        if (mega) {
            gemm_qkv<<<dim3(M / 128, 3 * H_ / 128), 256, 0, stream>>>(
                X, WOFF(2) + (size_t)l * 3 * WH_, q_b + bo, k_b + bo, v_b + bo,
                Qb, Kb, Vb);
        } else {
            wcvt_kernel<<<WG, 256, 0, stream>>>(q_w + wo, Wbase, W8);
            gemm_bt<<<dim3(M / 128, H_ / 128), 256, 0, stream>>>(
                X, Wbase, q_b + bo, Qb, nullptr, nullptr, H_, H_, 0);
            wcvt_kernel<<<WG, 256, 0, stream>>>(k_w + wo, Wbase, W8);
            gemm_bt<<<dim3(M / 128, H_ / 128), 256, 0, stream>>>(
                X, Wbase, k_b + bo, Kb, nullptr, nullptr, H_, H_, 0);
            wcvt_kernel<<<WG, 256, 0, stream>>>(v_w + wo, Wbase, W8);
            gemm_bt<<<dim3(M / 128, H_ / 128), 256, 0, stream>>>(
                X, Wbase, v_b + bo, Vb, nullptr, nullptr, H_, H_, 6);
        }

        flash_attn<<<dim3(S_ / 128, B_ * N_), 512, 0, stream>>>(
            Qb, Kb, Vb, qscale, Qb);

        if (mega) Wp = WOFF(14) + wo;
        else { wcvt_kernel<<<WG, 256, 0, stream>>>(attn_ow + wo, Wbase, W8); Wp = Wbase; }
        gemm_bt<<<dim3(M / 128, H_ / 128), 256, 0, stream>>>(
            Qb, Wp, attn_ob + bo, Kb, X, nullptr, H_, H_, 3);
        if (mega) Wp = WOFF(18) + wo;
        else { wcvt_kernel<<<WG, 256, 0, stream>>>(en_w + wo, Wbase, W8); Wp = Wbase; }
        gemm_bt<<<dim3(M / 128, H_ / 128), 256, 0, stream>>>(
            Kb, Wp, en_b + bo, Vb, nullptr, nullptr, H_, H_, 4);
        if (mega) Wp = WOFF(22) + wo;
        else { wadd_kernel<<<WG, 256, 0, stream>>>(fix_w + wo, plastic_w + wo, Wbase, W8); Wp = Wbase; }
        gemm_bt<<<dim3(M / 128, H_ / 128), 256, 0, stream>>>(
            Vb, Wp, fix_b + bo, Qb, nullptr, nullptr, H_, H_, 0);
        ln_kernel<<<dim3(M), 256, 0, stream>>>(Qb, ln_g + bo, ln_b + bo, X);
    }

    if (mega) Wp = WOFF(26);
    else { wcvt_kernel<<<WGo, 256, 0, stream>>>(out_w, Wbase, W8o); Wp = Wbase; }
    gemm_bt<<<dim3(M / 128, V_ / 128), 256, 0, stream>>>(
        X, Wp, out_b, (float*)d_out, nullptr, nullptr, H_, V_, 5);
#undef WOFF
}

// Round 7
// 3516.557 us; speedup vs baseline: 1.2511x; 1.2087x over previous
//
#include <hip/hip_runtime.h>

#define B_ 4
#define S_ 2048
#define H_ 1024
#define L_ 4
#define N_ 4
#define D_ 256
#define V_ 256
#define EPSF 1e-5f
#define WH_ ((size_t)H_ * H_)   // 1<<20

typedef __attribute__((ext_vector_type(8))) short short8;
typedef __attribute__((ext_vector_type(4))) float f32x4;

__device__ inline float bf2f(unsigned short u) {
    union { unsigned int ui; float f; } c; c.ui = ((unsigned int)u) << 16; return c.f;
}
__device__ inline unsigned short f2bf(float f) {
    union { float f; unsigned int ui; } c; c.f = f;
    unsigned int u = c.ui;
    unsigned int r = (u + 0x7FFFu + ((u >> 16) & 1u)) >> 16;
    return (unsigned short)r;
}
__device__ inline float wave64_sum(float v) {
    for (int m = 32; m >= 1; m >>= 1) v += __shfl_xor(v, m, 64);
    return v;
}
__device__ inline void gl_lds16(const unsigned short* g, unsigned short* l) {
    __builtin_amdgcn_global_load_lds(
        (const __attribute__((address_space(1))) unsigned int*)g,
        (__attribute__((address_space(3))) unsigned int*)l, 16, 0, 0);
}

// ---------------------------------------------------------------------------
__global__ void wcvt_kernel(const float* __restrict__ W,
                            unsigned short* __restrict__ Wb, int n8) {
    int idx = blockIdx.x * 256 + threadIdx.x;
    if (idx >= n8) return;
    size_t base = (size_t)idx * 8;
    float4 a0 = *(const float4*)(W + base);
    float4 a1 = *(const float4*)(W + base + 4);
    short8 t;
    t[0] = f2bf(a0.x); t[1] = f2bf(a0.y); t[2] = f2bf(a0.z); t[3] = f2bf(a0.w);
    t[4] = f2bf(a1.x); t[5] = f2bf(a1.y); t[6] = f2bf(a1.z); t[7] = f2bf(a1.w);
    *(short8*)(Wb + base) = t;
}

// fp32 -> bf16 into QKV-fused layout: src (L,WH) -> dst layer*3WH + sel*WH
__global__ void wcvt_qkv(const float* __restrict__ W,
                         unsigned short* __restrict__ Wb, int n8, int sel) {
    int idx = blockIdx.x * 256 + threadIdx.x;
    if (idx >= n8) return;
    size_t p = (size_t)idx * 8;
    size_t layer = p >> 20;
    size_t within = p & (WH_ - 1);
    size_t dst = layer * 3 * WH_ + (size_t)sel * WH_ + within;
    float4 a0 = *(const float4*)(W + p);
    float4 a1 = *(const float4*)(W + p + 4);
    short8 t;
    t[0] = f2bf(a0.x); t[1] = f2bf(a0.y); t[2] = f2bf(a0.z); t[3] = f2bf(a0.w);
    t[4] = f2bf(a1.x); t[5] = f2bf(a1.y); t[6] = f2bf(a1.z); t[7] = f2bf(a1.w);
    *(short8*)(Wb + dst) = t;
}

// combined weight: Wo = bf16(Wa + Wb2 + I) per HxH layer (layers contiguous)
__global__ void wadd_kernel(const float* __restrict__ Wa, const float* __restrict__ Wb2,
                            unsigned short* __restrict__ Wo, int n8) {
    int idx = blockIdx.x * 256 + threadIdx.x;
    if (idx >= n8) return;
    size_t base = (size_t)idx * 8;
    short8 t;
#pragma unroll
    for (int e = 0; e < 8; e++) {
        size_t p = base + e;
        int pos = (int)(p & (WH_ - 1));
        float v = Wa[p] + Wb2[p] + (((pos >> 10) == (pos & (H_ - 1))) ? 1.f : 0.f);
        t[e] = f2bf(v);
    }
    *(short8*)(Wo + base) = t;
}

// ---------------------------------------------------------------------------
__global__ void gather_kernel(const int* __restrict__ ids,
                              const float* __restrict__ embed,
                              unsigned short* __restrict__ x) {
    size_t idx = (size_t)blockIdx.x * 256 + threadIdx.x;
    int bs = (int)(idx >> 10);
    int h  = (int)(idx & 1023);
    x[idx] = f2bf(embed[(size_t)ids[bs] * H_ + h]);
}

__global__ void mean_kernel(const unsigned short* __restrict__ Xin,
                            float* __restrict__ xmean) {
    int idx = blockIdx.x * 256 + threadIdx.x;
    int b = idx >> 10, h = idx & 1023;
    int s0 = blockIdx.y * 128;
    const unsigned short* p = Xin + ((size_t)b * S_ + s0) * H_ + h;
    float s = 0.f;
    for (int i = 0; i < 128; i++) s += bf2f(p[(size_t)i * H_]);
    atomicAdd(&xmean[idx], s);
}

__global__ void nm_kernel(const float* __restrict__ xmean,
                          const float* __restrict__ w,
                          const float* __restrict__ bias,
                          float* __restrict__ dopnor) {
    int wave = threadIdx.x >> 6, lane = threadIdx.x & 63;
    for (int p = wave; p < 2 * B_; p += 4) {
        int b = p >> 1, j = p & 1;
        float s = 0.f;
        for (int h = lane; h < H_; h += 64) s += xmean[b * H_ + h] * w[j * H_ + h];
        s = wave64_sum(s);
        if (lane == 0) dopnor[p] = s / (float)S_ + bias[j];
    }
}

__global__ void gain_kernel(const float* __restrict__ xmean,
                            const float* __restrict__ gw,
                            const float* __restrict__ gb,
                            float* __restrict__ qscale) {
    int wave = threadIdx.x >> 6, lane = threadIdx.x & 63;
    for (int p = wave; p < B_ * N_; p += 4) {
        int b = p >> 2, n = p & 3;
        float s = 0.f;
        for (int h = lane; h < H_; h += 64) s += xmean[b * H_ + h] * gw[n * H_ + h];
        s = wave64_sum(s);
        if (lane == 0) qscale[p] = (1.f + s / (float)S_ + gb[n]) * 0.0625f;
    }
}

// ---------------------------------------------------------------------------
// GEMM (m97 structure): C(MxN) = epilogue( A(MxK) @ W(NxK)^T + bias )
// modes: 0 plain->bf16; 1 gate; 2 noise; 3 residual; 4 silu; 5 plain->fp32;
//        6 V^T store
// ---------------------------------------------------------------------------
__global__ __launch_bounds__(256) void gemm_bt(
    const unsigned short* __restrict__ A, const unsigned short* __restrict__ W,
    const float* __restrict__ bias, void* __restrict__ Cout,
    const unsigned short* __restrict__ X, const float* __restrict__ scal,
    int K, int Nout, int mode) {
    __shared__ unsigned short As[128 * 32];
    __shared__ unsigned short Bs[128 * 32];
    int tid = threadIdx.x;
    int wave = tid >> 6, lane = tid & 63;
    int quad = lane >> 4, l16 = lane & 15;
    int bm = blockIdx.x * 128;
    int bn = blockIdx.y * 128;
    int mw = (wave >> 1) * 64, nw = (wave & 1) * 64;

    const unsigned short* Ag = A + (size_t)(bm + wave * 16 + (lane >> 2)) * K + (lane & 3) * 8;
    const unsigned short* Wg = W + (size_t)(bn + wave * 16 + (lane >> 2)) * K + (lane & 3) * 8;
    unsigned short* ldsA = As + wave * 512;
    unsigned short* ldsB = Bs + wave * 512;
    size_t rowskip = (size_t)64 * K;

    f32x4 acc[4][4];
#pragma unroll
    for (int i = 0; i < 4; i++)
#pragma unroll
        for (int j = 0; j < 4; j++)
#pragma unroll
            for (int r = 0; r < 4; r++) acc[i][j][r] = 0.f;

    for (int kk = 0; kk < K; kk += 32) {
        __syncthreads();
        gl_lds16(Ag + kk, ldsA);
        gl_lds16(Ag + rowskip + kk, ldsA + 2048);
        gl_lds16(Wg + kk, ldsB);
        gl_lds16(Wg + rowskip + kk, ldsB + 2048);
        __syncthreads();

        short8 af[4], bfr[4];
#pragma unroll
        for (int i = 0; i < 4; i++)
            af[i] = *(const short8*)&As[(mw + i * 16 + l16) * 32 + quad * 8];
#pragma unroll
        for (int j = 0; j < 4; j++)
            bfr[j] = *(const short8*)&Bs[(nw + j * 16 + l16) * 32 + quad * 8];
#pragma unroll
        for (int i = 0; i < 4; i++)
#pragma unroll
            for (int j = 0; j < 4; j++)
                acc[i][j] = __builtin_amdgcn_mfma_f32_16x16x32_bf16(af[i], bfr[j], acc[i][j], 0, 0, 0);
    }

    if (mode == 6) {
#pragma unroll
        for (int i = 0; i < 4; i++) {
#pragma unroll
            for (int j = 0; j < 4; j++) {
                int col = bn + nw + j * 16 + l16;
                float bv = bias ? bias[col] : 0.f;
                int n = col >> 8, d = col & 255;
                int row0 = bm + mw + i * 16 + quad * 4;
                int b = row0 >> 11, s0 = row0 & 2047;
                union { unsigned short u[4]; uint2 v; } pk;
#pragma unroll
                for (int r = 0; r < 4; r++) pk.u[r] = f2bf(acc[i][j][r] + bv);
                *(uint2*)((unsigned short*)Cout +
                          ((size_t)(b * N_ + n) * D_ + d) * S_ + s0) = pk.v;
            }
        }
        return;
    }

#pragma unroll
    for (int i = 0; i < 4; i++) {
#pragma unroll
        for (int j = 0; j < 4; j++) {
            int col = bn + nw + j * 16 + l16;
            float bv = bias ? bias[col] : 0.f;
#pragma unroll
            for (int r = 0; r < 4; r++) {
                int row = bm + mw + i * 16 + quad * 4 + r;
                float v = acc[i][j][r] + bv;
                size_t off = (size_t)row * Nout + col;
                if (mode == 5) {
                    ((float*)Cout)[off] = v;
                    continue;
                }
                float outv;
                if (mode == 0) {
                    outv = v;
                } else if (mode == 1) {
                    float sig = 1.f / (1.f + __expf(-v));
                    float dop = scal[(row >> 11) * 2];
                    outv = bf2f(X[off]) * (1.f + dop * sig);
                } else if (mode == 2) {
                    float nor = scal[(row >> 11) * 2 + 1];
                    outv = bf2f(X[off]) + nor * tanhf(v);
                } else if (mode == 3) {
                    outv = v + bf2f(X[off]);
                } else {
                    outv = v * (1.f / (1.f + __expf(-v)));
                }
                ((unsigned short*)Cout)[off] = f2bf(outv);
            }
        }
    }
}

// ---------------------------------------------------------------------------
// Fused QKV GEMM: W is (3H x H) fused [q;k;v] for one layer. N=3072.
// col block (64-aligned) selects destination: 0 -> Q, 1 -> K, 2 -> V^T store.
// ---------------------------------------------------------------------------
__global__ __launch_bounds__(256) void gemm_qkv(
    const unsigned short* __restrict__ A, const unsigned short* __restrict__ W,
    const float* __restrict__ qb, const float* __restrict__ kb,
    const float* __restrict__ vbb, unsigned short* __restrict__ Qo,
    unsigned short* __restrict__ Ko, unsigned short* __restrict__ Vt) {
    __shared__ unsigned short As[128 * 32];
    __shared__ unsigned short Bs[128 * 32];
    const int K = H_;
    int tid = threadIdx.x;
    int wave = tid >> 6, lane = tid & 63;
    int quad = lane >> 4, l16 = lane & 15;
    int bm = blockIdx.x * 128;
    int bn = blockIdx.y * 128;
    int mw = (wave >> 1) * 64, nw = (wave & 1) * 64;

    const unsigned short* Ag = A + (size_t)(bm + wave * 16 + (lane >> 2)) * K + (lane & 3) * 8;
    const unsigned short* Wg = W + (size_t)(bn + wave * 16 + (lane >> 2)) * K + (lane & 3) * 8;
    unsigned short* ldsA = As + wave * 512;
    unsigned short* ldsB = Bs + wave * 512;
    size_t rowskip = (size_t)64 * K;

    f32x4 acc[4][4];
#pragma unroll
    for (int i = 0; i < 4; i++)
#pragma unroll
        for (int j = 0; j < 4; j++)
#pragma unroll
            for (int r = 0; r < 4; r++) acc[i][j][r] = 0.f;

    for (int kk = 0; kk < K; kk += 32) {
        __syncthreads();
        gl_lds16(Ag + kk, ldsA);
        gl_lds16(Ag + rowskip + kk, ldsA + 2048);
        gl_lds16(Wg + kk, ldsB);
        gl_lds16(Wg + rowskip + kk, ldsB + 2048);
        __syncthreads();

        short8 af[4], bfr[4];
#pragma unroll
        for (int i = 0; i < 4; i++)
            af[i] = *(const short8*)&As[(mw + i * 16 + l16) * 32 + quad * 8];
#pragma unroll
        for (int j = 0; j < 4; j++)
            bfr[j] = *(const short8*)&Bs[(nw + j * 16 + l16) * 32 + quad * 8];
#pragma unroll
        for (int i = 0; i < 4; i++)
#pragma unroll
            for (int j = 0; j < 4; j++)
                acc[i][j] = __builtin_amdgcn_mfma_f32_16x16x32_bf16(af[i], bfr[j], acc[i][j], 0, 0, 0);
    }

    int sel = (bn + nw) >> 10;   // uniform per block-half
    if (sel == 2) {
#pragma unroll
        for (int i = 0; i < 4; i++) {
#pragma unroll
            for (int j = 0; j < 4; j++) {
                int c2 = ((bn + nw) & 1023) + j * 16 + l16;
                float bv = vbb[c2];
                int n = c2 >> 8, d = c2 & 255;
                int row0 = bm + mw + i * 16 + quad * 4;
                int b = row0 >> 11, s0 = row0 & 2047;
                union { unsigned short u[4]; uint2 v; } pk;
#pragma unroll
                for (int r = 0; r < 4; r++) pk.u[r] = f2bf(acc[i][j][r] + bv);
                *(uint2*)(Vt + ((size_t)(b * N_ + n) * D_ + d) * S_ + s0) = pk.v;
            }
        }
    } else {
        unsigned short* Co = (sel == 0) ? Qo : Ko;
        const float* bias = (sel == 0) ? qb : kb;
#pragma unroll
        for (int i = 0; i < 4; i++) {
#pragma unroll
            for (int j = 0; j < 4; j++) {
                int c2 = ((bn + nw) & 1023) + j * 16 + l16;
                float bv = bias[c2];
#pragma unroll
                for (int r = 0; r < 4; r++) {
                    int row = bm + mw + i * 16 + quad * 4 + r;
                    Co[(size_t)row * H_ + c2] = f2bf(acc[i][j][r] + bv);
                }
            }
        }
    }
}

// ---------------------------------------------------------------------------
// Flash attention, round-7 = round-6 resubmission (audit clean; round-6 bench
// failure attributed to harness/container flake, not the kernel).
// k-split at 256 threads / 4 waves = 2 pairs x {32 q-rows, half-k}. Evidence
// base: 512-thread builds always cap at 128 VGPR (rounds 1/2/4/5) and spill
// ~2.6 GB scratch; the 256-thread round-0 build with the SAME per-thread
// state got 228 VGPR, no spill. Block covers 64 q-rows; grid (S/64, B*N) =
// 512 blocks, 2 per CU in series. Per-wave LDS reads/iter: 16 kf + 16 vf +
// 2 pf + 1 ones = 35 b128 (vs 68 in round-2 structure) -> CU DS traffic
// halved. Staging: double-buffered K/V via global_load_lds, both-sides XOR
// swizzle (slot ^= row&7), one vmcnt(0)+barrier per tile. Defer-max THR=8.
// End merge: odd half publishes (O,m,l) via dead LDS (pair p -> Kb[p], m/l
// -> Pl); even half merges + writes.
// LDS: 64K K-dbuf + 64K V-dbuf + 1.25K Vones + 10K Pl = 139.3 KiB.
// ---------------------------------------------------------------------------
__global__ __launch_bounds__(256) void flash_attn(
    const unsigned short* __restrict__ Q, const unsigned short* __restrict__ Kg,
    const unsigned short* __restrict__ VT, const float* __restrict__ qscale,
    unsigned short* __restrict__ O) {
    __shared__ unsigned short Kb[2][64 * 256];   // [buf][row*256 + col], swizzled slots
    __shared__ unsigned short Vb[2][256 * 64];   // [buf][d*64 + col], swizzled slots
    __shared__ unsigned short Vones[16][40];     // ones "column" tile for row-sum
    __shared__ unsigned short Pl[4][32][40];     // per-wave P (32 rows x 32 k)

    int tid = threadIdx.x;
    int wave = tid >> 6, lane = tid & 63;
    int quad = lane >> 4, l16 = lane & 15;
    int rx = l16 & 7;                            // read-side swizzle mask
    int pair = wave >> 1;                        // 0..1
    int khalf = wave & 1;
    int koff = khalf * 32;                       // k-col offset within tile
    int kv0 = khalf * 4;                         // V^T slot offset (16B slots)
    int bnh = blockIdx.y;
    size_t base = ((size_t)(bnh >> 2) * S_) * H_ + (size_t)(bnh & 3) * D_;
    size_t vtbase = (size_t)bnh * D_ * S_;
    int qw = blockIdx.x * 64 + pair * 32;
    float scale = qscale[bnh];

    for (int c = tid; c < 16 * 40; c += 256) {
        int rr = c / 40, cc = c - rr * 40;
        Vones[rr][cc] = (rr == 0) ? (unsigned short)0x3F80 : (unsigned short)0;
    }

    // staging source-side swizzle lane constants
    int l5 = lane >> 5;                 // K: which of 2 rows in a 1KB chunk
    int ks = lane & 31;                 // K: lds slot within row (16B units)
    int vrow = lane >> 3;               // V: which of 8 rows in a 1KB chunk
    int vs = lane & 7;                  // V: lds slot within row
    int vmask = vrow & 7;

    short8 qf[2][8];
#pragma unroll
    for (int rt = 0; rt < 2; rt++)
#pragma unroll
        for (int kk = 0; kk < 8; kk++)
            qf[rt][kk] = *(const short8*)(Q + base +
                (size_t)(qw + rt * 16 + l16) * H_ + kk * 32 + quad * 8);

    f32x4 o[2][16], osum[2];
#pragma unroll
    for (int rt = 0; rt < 2; rt++) {
#pragma unroll
        for (int c = 0; c < 16; c++)
#pragma unroll
            for (int r = 0; r < 4; r++) o[rt][c][r] = 0.f;
#pragma unroll
        for (int r = 0; r < 4; r++) osum[rt][r] = 0.f;
    }
    float mrow[2][4];
#pragma unroll
    for (int rt = 0; rt < 2; rt++)
#pragma unroll
        for (int r = 0; r < 4; r++) mrow[rt][r] = -1e30f;

    // prologue: stage tile 0 into buffer 0 (32 chunks of 1KB, 8 per wave)
    {
#pragma unroll
        for (int k = 0; k < 8; k++) {
            int chunk = 8 * wave + k;
            int kmask = (2 * k + l5) & 7;       // == (2*chunk+l5)&7, 16*wave = 0 mod 8
            int grow = 2 * chunk + l5;
            int gcol = (ks ^ kmask) * 8;
            gl_lds16(Kg + base + (size_t)grow * H_ + gcol, &Kb[0][chunk * 512]);
        }
#pragma unroll
        for (int k = 0; k < 8; k++) {
            int chunk = 8 * wave + k;
            int d = 8 * chunk + vrow;
            int gcol = (vs ^ vmask) * 8;
            gl_lds16(VT + vtbase + (size_t)d * S_ + gcol, &Vb[0][chunk * 512]);
        }
    }
    asm volatile("s_waitcnt vmcnt(0)" ::: "memory");
    __syncthreads();

    int cur = 0;
    for (int t0 = 0; t0 < S_; t0 += 64) {
        // issue next tile's loads into the other buffer (fly under compute)
        if (t0 + 64 < S_) {
            int nb = cur ^ 1;
#pragma unroll
            for (int k = 0; k < 8; k++) {
                int chunk = 8 * wave + k;
                int kmask = (2 * k + l5) & 7;
                int grow = t0 + 64 + 2 * chunk + l5;
                int gcol = (ks ^ kmask) * 8;
                gl_lds16(Kg + base + (size_t)grow * H_ + gcol, &Kb[nb][chunk * 512]);
            }
#pragma unroll
            for (int k = 0; k < 8; k++) {
                int chunk = 8 * wave + k;
                int d = 8 * chunk + vrow;
                int gcol = (vs ^ vmask) * 8;
                gl_lds16(VT + vtbase + (size_t)d * S_ + t0 + 64 + gcol, &Vb[nb][chunk * 512]);
            }
        }

        const unsigned short* Kc = Kb[cur];
        const unsigned short* Vc = Vb[cur];

        // QK^T: 32 q-rows x 32 k-cols (this wave's half), kf shared across rt
        f32x4 s[2][2];
#pragma unroll
        for (int rt = 0; rt < 2; rt++)
#pragma unroll
            for (int j = 0; j < 2; j++)
#pragma unroll
                for (int r = 0; r < 4; r++) s[rt][j][r] = 0.f;
#pragma unroll
        for (int j = 0; j < 2; j++)
#pragma unroll
            for (int kk = 0; kk < 8; kk++) {
                short8 kf = *(const short8*)&Kc[(koff + j * 16 + l16) * 256 +
                                                ((4 * kk + quad) ^ rx) * 8];
                s[0][j] = __builtin_amdgcn_mfma_f32_16x16x32_bf16(qf[0][kk], kf, s[0][j], 0, 0, 0);
                s[1][j] = __builtin_amdgcn_mfma_f32_16x16x32_bf16(qf[1][kk], kf, s[1][j], 0, 0, 0);
            }

        // online softmax (independent per k-half) with defer-max (THR=8)
        float sv[2][4][2], mx[2][4];
        bool ok = true;
#pragma unroll
        for (int rt = 0; rt < 2; rt++)
#pragma unroll
            for (int r = 0; r < 4; r++) {
                sv[rt][r][0] = s[rt][0][r] * scale;
                sv[rt][r][1] = s[rt][1][r] * scale;
                float m0 = fmaxf(sv[rt][r][0], sv[rt][r][1]);
                for (int m = 8; m >= 1; m >>= 1) m0 = fmaxf(m0, __shfl_xor(m0, m, 64));
                mx[rt][r] = m0;
                ok = ok && (m0 <= mrow[rt][r] + 8.f);
            }
        if (__all(ok)) {
#pragma unroll
            for (int rt = 0; rt < 2; rt++)
#pragma unroll
                for (int r = 0; r < 4; r++) {
                    Pl[wave][rt * 16 + quad * 4 + r][l16] =
                        f2bf(__expf(sv[rt][r][0] - mrow[rt][r]));
                    Pl[wave][rt * 16 + quad * 4 + r][16 + l16] =
                        f2bf(__expf(sv[rt][r][1] - mrow[rt][r]));
                }
        } else {
            float alpha[2][4];
#pragma unroll
            for (int rt = 0; rt < 2; rt++)
#pragma unroll
                for (int r = 0; r < 4; r++) {
                    float mnew = fmaxf(mrow[rt][r], mx[rt][r]);
                    alpha[rt][r] = __expf(mrow[rt][r] - mnew);
                    mrow[rt][r] = mnew;
                    Pl[wave][rt * 16 + quad * 4 + r][l16] =
                        f2bf(__expf(sv[rt][r][0] - mnew));
                    Pl[wave][rt * 16 + quad * 4 + r][16 + l16] =
                        f2bf(__expf(sv[rt][r][1] - mnew));
                }
#pragma unroll
            for (int rt = 0; rt < 2; rt++) {
#pragma unroll
                for (int c = 0; c < 16; c++)
#pragma unroll
                    for (int r = 0; r < 4; r++) o[rt][c][r] *= alpha[rt][r];
#pragma unroll
                for (int r = 0; r < 4; r++) osum[rt][r] *= alpha[rt][r];
            }
        }

        // PV: vf shared across both row-tiles
        short8 pf0 = *(const short8*)&Pl[wave][l16][quad * 8];
        short8 pf1 = *(const short8*)&Pl[wave][16 + l16][quad * 8];
#pragma unroll
        for (int c = 0; c < 16; c++) {
            short8 vf = *(const short8*)&Vc[(c * 16 + l16) * 64 + ((kv0 + quad) ^ rx) * 8];
            o[0][c] = __builtin_amdgcn_mfma_f32_16x16x32_bf16(pf0, vf, o[0][c], 0, 0, 0);
            o[1][c] = __builtin_amdgcn_mfma_f32_16x16x32_bf16(pf1, vf, o[1][c], 0, 0, 0);
        }
        {
            short8 vsf = *(const short8*)&Vones[l16][quad * 8];
            osum[0] = __builtin_amdgcn_mfma_f32_16x16x32_bf16(pf0, vsf, osum[0], 0, 0, 0);
            osum[1] = __builtin_amdgcn_mfma_f32_16x16x32_bf16(pf1, vsf, osum[1], 0, 0, 0);
        }

        // next tile must have landed; all waves done reading current buffers
        asm volatile("s_waitcnt vmcnt(0)" ::: "memory");
        __syncthreads();
        cur ^= 1;
    }

    // ---- end merge: odd half publishes (O, m, l); even half merges+writes.
    // Spill space: pair p -> Kb[p] (8192 floats each); m/l -> Pl (128 floats
    // needed, Pl is 10 KB). All LDS dead at this point.
    float* Of = (float*)&Kb[pair][0];
    float* Ml = (float*)&Pl[0][0][0];
    if (khalf) {
#pragma unroll
        for (int rt = 0; rt < 2; rt++)
#pragma unroll
            for (int c = 0; c < 16; c++) {
                int idx = ((((rt * 16 + c) * 4 + quad) * 16) + l16) * 4;
                *(f32x4*)&Of[idx] = o[rt][c];
            }
        if (l16 == 0) {
#pragma unroll
            for (int rt = 0; rt < 2; rt++)
#pragma unroll
                for (int r = 0; r < 4; r++) {
                    int row = rt * 16 + quad * 4 + r;
                    Ml[pair * 64 + row]      = mrow[rt][r];
                    Ml[pair * 64 + 32 + row] = osum[rt][r];
                }
        }
    }
    __syncthreads();
    if (!khalf) {
        float sca[2][4], scb[2][4];
#pragma unroll
        for (int rt = 0; rt < 2; rt++)
#pragma unroll
            for (int r = 0; r < 4; r++) {
                int row = rt * 16 + quad * 4 + r;
                float mb = Ml[pair * 64 + row];
                float lb = Ml[pair * 64 + 32 + row];
                float la = __shfl(osum[rt][r], (lane & 48), 64);
                float mm = fmaxf(mrow[rt][r], mb);
                float ea = __expf(mrow[rt][r] - mm);
                float eb = __expf(mb - mm);
                float inv = 1.f / (ea * la + eb * lb);
                sca[rt][r] = ea * inv;
                scb[rt][r] = eb * inv;
            }
#pragma unroll
        for (int rt = 0; rt < 2; rt++)
#pragma unroll
            for (int c = 0; c < 16; c++) {
                int idx = ((((rt * 16 + c) * 4 + quad) * 16) + l16) * 4;
                f32x4 ob = *(const f32x4*)&Of[idx];
#pragma unroll
                for (int r = 0; r < 4; r++) {
                    int row = qw + rt * 16 + quad * 4 + r;
                    int d = c * 16 + l16;
                    O[base + (size_t)row * H_ + d] =
                        f2bf(o[rt][c][r] * sca[rt][r] + ob[r] * scb[rt][r]);
                }
            }
    }
}

// ---------------------------------------------------------------------------
__global__ __launch_bounds__(256) void ln_kernel(
    const unsigned short* __restrict__ y, const float* __restrict__ g,
    const float* __restrict__ bta, unsigned short* __restrict__ out) {
    int row = blockIdx.x;
    size_t ro = (size_t)row * H_;
    int tid = threadIdx.x;
    float t[4]; float s = 0.f, s2 = 0.f;
#pragma unroll
    for (int i = 0; i < 4; i++) {
        int h = i * 256 + tid;
        float v = bf2f(y[ro + h]);
        t[i] = v; s += v; s2 += v * v;
    }
    s = wave64_sum(s); s2 = wave64_sum(s2);
    __shared__ float sh[8];
    int wave = tid >> 6, lane = tid & 63;
    if (lane == 0) { sh[wave] = s; sh[4 + wave] = s2; }
    __syncthreads();
    s  = sh[0] + sh[1] + sh[2] + sh[3];
    s2 = sh[4] + sh[5] + sh[6] + sh[7];
    float mu = s * (1.f / H_);
    float var = s2 * (1.f / H_) - mu * mu;
    float inv = rsqrtf(var + EPSF);
#pragma unroll
    for (int i = 0; i < 4; i++) {
        int h = i * 256 + tid;
        out[ro + h] = f2bf((t[i] - mu) * inv * g[h] + bta[h]);
    }
}

// ---------------------------------------------------------------------------
extern "C" void kernel_launch(void* const* d_in, const int* in_sizes, int n_in,
                              void* d_out, int out_size, void* d_ws, size_t ws_size,
                              hipStream_t stream) {
    const int*   ids          = (const int*)d_in[0];
    const float* embed        = (const float*)d_in[1];
    const float* nm_gate_w    = (const float*)d_in[2];
    const float* nm_gate_b    = (const float*)d_in[3];
    const float* nm_filter_w  = (const float*)d_in[4];
    const float* nm_filter_b  = (const float*)d_in[5];
    const float* nm_ctx_w     = (const float*)d_in[6];
    const float* nm_ctx_b     = (const float*)d_in[7];
    const float* q_w          = (const float*)d_in[8];
    const float* q_b          = (const float*)d_in[9];
    const float* k_w          = (const float*)d_in[10];
    const float* k_b          = (const float*)d_in[11];
    const float* v_w          = (const float*)d_in[12];
    const float* v_b          = (const float*)d_in[13];
    const float* gain_w       = (const float*)d_in[14];
    const float* gain_b       = (const float*)d_in[15];
    const float* attn_ow      = (const float*)d_in[16];
    const float* attn_ob      = (const float*)d_in[17];
    const float* en_w         = (const float*)d_in[18];
    const float* en_b         = (const float*)d_in[19];
    const float* plastic_w    = (const float*)d_in[20];
    const float* fix_w        = (const float*)d_in[21];
    const float* fix_b        = (const float*)d_in[22];
    const float* ln_g         = (const float*)d_in[23];
    const float* ln_b         = (const float*)d_in[24];
    const float* out_w        = (const float*)d_in[25];
    const float* out_b        = (const float*)d_in[26];

    size_t T  = (size_t)B_ * S_ * H_;
    size_t smallBytes = ((size_t)B_ * H_ + 2 * B_ + B_ * N_ + 8) * sizeof(float);
    size_t megaElems  = 26 * WH_ + WH_ / 4;
    size_t need_base  = 4 * T * 2 + smallBytes + 2 * WH_;
    size_t need_mega  = 4 * T * 2 + smallBytes + 2 * megaElems;
    if (ws_size < need_base) return;
    bool mega = ws_size >= need_mega;

    unsigned short* X   = (unsigned short*)d_ws;
    unsigned short* Qb  = X + T;
    unsigned short* Kb  = Qb + T;
    unsigned short* Vb  = Kb + T;
    float* xmean  = (float*)(Vb + T);
    float* dopnor = xmean + (size_t)B_ * H_;
    float* qscale = dopnor + 2 * B_;
    unsigned short* Wbase = (unsigned short*)(qscale + B_ * N_ + 8);
#define WOFF(k) (Wbase + (size_t)(k) * WH_)

    const int M   = B_ * S_;
    const int W8  = (int)(WH_ / 8);
    const int WG  = (W8 + 255) / 256;
    const int W84 = (int)(4 * WH_ / 8);
    const int WG4 = (W84 + 255) / 256;
    const int W8o = V_ * H_ / 8;
    const int WGo = (W8o + 255) / 256;

    if (mega) {
        wcvt_kernel<<<WG,  256, 0, stream>>>(nm_gate_w,   WOFF(0), W8);
        wcvt_kernel<<<WG,  256, 0, stream>>>(nm_filter_w, WOFF(1), W8);
        wcvt_qkv<<<WG4, 256, 0, stream>>>(q_w, WOFF(2), W84, 0);
        wcvt_qkv<<<WG4, 256, 0, stream>>>(k_w, WOFF(2), W84, 1);
        wcvt_qkv<<<WG4, 256, 0, stream>>>(v_w, WOFF(2), W84, 2);
        wcvt_kernel<<<WG4, 256, 0, stream>>>(attn_ow, WOFF(14), W84);
        wcvt_kernel<<<WG4, 256, 0, stream>>>(en_w,    WOFF(18), W84);
        wadd_kernel<<<WG4, 256, 0, stream>>>(fix_w, plastic_w, WOFF(22), W84);
        wcvt_kernel<<<WGo, 256, 0, stream>>>(out_w, WOFF(26), W8o);
    }

    gather_kernel<<<dim3((int)(T / 256)), 256, 0, stream>>>(ids, embed, X);

    hipMemsetAsync(xmean, 0, (size_t)B_ * H_ * sizeof(float), stream);
    mean_kernel<<<dim3(B_ * H_ / 256, 16), 256, 0, stream>>>(X, xmean);
    nm_kernel<<<1, 256, 0, stream>>>(xmean, nm_ctx_w, nm_ctx_b, dopnor);

    const unsigned short* Wp;
    if (mega) Wp = WOFF(0);
    else { wcvt_kernel<<<WG, 256, 0, stream>>>(nm_gate_w, Wbase, W8); Wp = Wbase; }
    gemm_bt<<<dim3(M / 128, H_ / 128), 256, 0, stream>>>(
        X, Wp, nm_gate_b, Qb, X, dopnor, H_, H_, 1);
    if (mega) Wp = WOFF(1);
    else { wcvt_kernel<<<WG, 256, 0, stream>>>(nm_filter_w, Wbase, W8); Wp = Wbase; }
    gemm_bt<<<dim3(M / 128, H_ / 128), 256, 0, stream>>>(
        Qb, Wp, nm_filter_b, X, Qb, dopnor, H_, H_, 2);

    for (int l = 0; l < L_; l++) {
        size_t wo = (size_t)l * WH_;
        size_t bo = (size_t)l * H_;
        hipMemsetAsync(xmean, 0, (size_t)B_ * H_ * sizeof(float), stream);
        mean_kernel<<<dim3(B_ * H_ / 256, 16), 256, 0, stream>>>(X, xmean);
        gain_kernel<<<1, 256, 0, stream>>>(xmean, gain_w + (size_t)l * N_ * H_,
                                           gain_b + (size_t)l * N_, qscale);

        if (mega) {
            gemm_qkv<<<dim3(M / 128, 3 * H_ / 128), 256, 0, stream>>>(
                X, WOFF(2) + (size_t)l * 3 * WH_, q_b + bo, k_b + bo, v_b + bo,
                Qb, Kb, Vb);
        } else {
            wcvt_kernel<<<WG, 256, 0, stream>>>(q_w + wo, Wbase, W8);
            gemm_bt<<<dim3(M / 128, H_ / 128), 256, 0, stream>>>(
                X, Wbase, q_b + bo, Qb, nullptr, nullptr, H_, H_, 0);
            wcvt_kernel<<<WG, 256, 0, stream>>>(k_w + wo, Wbase, W8);
            gemm_bt<<<dim3(M / 128, H_ / 128), 256, 0, stream>>>(
                X, Wbase, k_b + bo, Kb, nullptr, nullptr, H_, H_, 0);
            wcvt_kernel<<<WG, 256, 0, stream>>>(v_w + wo, Wbase, W8);
            gemm_bt<<<dim3(M / 128, H_ / 128), 256, 0, stream>>>(
                X, Wbase, v_b + bo, Vb, nullptr, nullptr, H_, H_, 6);
        }

        flash_attn<<<dim3(S_ / 64, B_ * N_), 256, 0, stream>>>(
            Qb, Kb, Vb, qscale, Qb);

        if (mega) Wp = WOFF(14) + wo;
        else { wcvt_kernel<<<WG, 256, 0, stream>>>(attn_ow + wo, Wbase, W8); Wp = Wbase; }
        gemm_bt<<<dim3(M / 128, H_ / 128), 256, 0, stream>>>(
            Qb, Wp, attn_ob + bo, Kb, X, nullptr, H_, H_, 3);
        if (mega) Wp = WOFF(18) + wo;
        else { wcvt_kernel<<<WG, 256, 0, stream>>>(en_w + wo, Wbase, W8); Wp = Wbase; }
        gemm_bt<<<dim3(M / 128, H_ / 128), 256, 0, stream>>>(
            Kb, Wp, en_b + bo, Vb, nullptr, nullptr, H_, H_, 4);
        if (mega) Wp = WOFF(22) + wo;
        else { wadd_kernel<<<WG, 256, 0, stream>>>(fix_w + wo, plastic_w + wo, Wbase, W8); Wp = Wbase; }
        gemm_bt<<<dim3(M / 128, H_ / 128), 256, 0, stream>>>(
            Vb, Wp, fix_b + bo, Qb, nullptr, nullptr, H_, H_, 0);
        ln_kernel<<<dim3(M), 256, 0, stream>>>(Qb, ln_g + bo, ln_b + bo, X);
    }

    if (mega) Wp = WOFF(26);
    else { wcvt_kernel<<<WGo, 256, 0, stream>>>(out_w, Wbase, W8o); Wp = Wbase; }
    gemm_bt<<<dim3(M / 128, V_ / 128), 256, 0, stream>>>(
        X, Wp, out_b, (float*)d_out, nullptr, nullptr, H_, V_, 5);
#undef WOFF
}

// Round 8
// 2078.462 us; speedup vs baseline: 2.1167x; 1.6919x over previous
//
#include <hip/hip_runtime.h>

#define B_ 4
#define S_ 2048
#define H_ 1024
#define L_ 4
#define N_ 4
#define D_ 256
#define V_ 256
#define EPSF 1e-5f
#define WH_ ((size_t)H_ * H_)   // 1<<20

typedef __attribute__((ext_vector_type(8))) short short8;
typedef __attribute__((ext_vector_type(4))) float f32x4;

__device__ inline float bf2f(unsigned short u) {
    union { unsigned int ui; float f; } c; c.ui = ((unsigned int)u) << 16; return c.f;
}
__device__ inline unsigned short f2bf(float f) {
    union { float f; unsigned int ui; } c; c.f = f;
    unsigned int u = c.ui;
    unsigned int r = (u + 0x7FFFu + ((u >> 16) & 1u)) >> 16;
    return (unsigned short)r;
}
__device__ inline float wave64_sum(float v) {
    for (int m = 32; m >= 1; m >>= 1) v += __shfl_xor(v, m, 64);
    return v;
}
__device__ inline void gl_lds16(const unsigned short* g, unsigned short* l) {
    __builtin_amdgcn_global_load_lds(
        (const __attribute__((address_space(1))) unsigned int*)g,
        (__attribute__((address_space(3))) unsigned int*)l, 16, 0, 0);
}

// ---------------------------------------------------------------------------
__global__ void wcvt_kernel(const float* __restrict__ W,
                            unsigned short* __restrict__ Wb, int n8) {
    int idx = blockIdx.x * 256 + threadIdx.x;
    if (idx >= n8) return;
    size_t base = (size_t)idx * 8;
    float4 a0 = *(const float4*)(W + base);
    float4 a1 = *(const float4*)(W + base + 4);
    short8 t;
    t[0] = f2bf(a0.x); t[1] = f2bf(a0.y); t[2] = f2bf(a0.z); t[3] = f2bf(a0.w);
    t[4] = f2bf(a1.x); t[5] = f2bf(a1.y); t[6] = f2bf(a1.z); t[7] = f2bf(a1.w);
    *(short8*)(Wb + base) = t;
}

// fp32 -> bf16 into QKV-fused layout: src (L,WH) -> dst layer*3WH + sel*WH
__global__ void wcvt_qkv(const float* __restrict__ W,
                         unsigned short* __restrict__ Wb, int n8, int sel) {
    int idx = blockIdx.x * 256 + threadIdx.x;
    if (idx >= n8) return;
    size_t p = (size_t)idx * 8;
    size_t layer = p >> 20;
    size_t within = p & (WH_ - 1);
    size_t dst = layer * 3 * WH_ + (size_t)sel * WH_ + within;
    float4 a0 = *(const float4*)(W + p);
    float4 a1 = *(const float4*)(W + p + 4);
    short8 t;
    t[0] = f2bf(a0.x); t[1] = f2bf(a0.y); t[2] = f2bf(a0.z); t[3] = f2bf(a0.w);
    t[4] = f2bf(a1.x); t[5] = f2bf(a1.y); t[6] = f2bf(a1.z); t[7] = f2bf(a1.w);
    *(short8*)(Wb + dst) = t;
}

// combined weight: Wo = bf16(Wa + Wb2 + I) per HxH layer (layers contiguous)
__global__ void wadd_kernel(const float* __restrict__ Wa, const float* __restrict__ Wb2,
                            unsigned short* __restrict__ Wo, int n8) {
    int idx = blockIdx.x * 256 + threadIdx.x;
    if (idx >= n8) return;
    size_t base = (size_t)idx * 8;
    short8 t;
#pragma unroll
    for (int e = 0; e < 8; e++) {
        size_t p = base + e;
        int pos = (int)(p & (WH_ - 1));
        float v = Wa[p] + Wb2[p] + (((pos >> 10) == (pos & (H_ - 1))) ? 1.f : 0.f);
        t[e] = f2bf(v);
    }
    *(short8*)(Wo + base) = t;
}

// ---------------------------------------------------------------------------
__global__ void gather_kernel(const int* __restrict__ ids,
                              const float* __restrict__ embed,
                              unsigned short* __restrict__ x) {
    size_t idx = (size_t)blockIdx.x * 256 + threadIdx.x;
    int bs = (int)(idx >> 10);
    int h  = (int)(idx & 1023);
    x[idx] = f2bf(embed[(size_t)ids[bs] * H_ + h]);
}

__global__ void mean_kernel(const unsigned short* __restrict__ Xin,
                            float* __restrict__ xmean) {
    int idx = blockIdx.x * 256 + threadIdx.x;
    int b = idx >> 10, h = idx & 1023;
    int s0 = blockIdx.y * 128;
    const unsigned short* p = Xin + ((size_t)b * S_ + s0) * H_ + h;
    float s = 0.f;
    for (int i = 0; i < 128; i++) s += bf2f(p[(size_t)i * H_]);
    atomicAdd(&xmean[idx], s);
}

__global__ void nm_kernel(const float* __restrict__ xmean,
                          const float* __restrict__ w,
                          const float* __restrict__ bias,
                          float* __restrict__ dopnor) {
    int wave = threadIdx.x >> 6, lane = threadIdx.x & 63;
    for (int p = wave; p < 2 * B_; p += 4) {
        int b = p >> 1, j = p & 1;
        float s = 0.f;
        for (int h = lane; h < H_; h += 64) s += xmean[b * H_ + h] * w[j * H_ + h];
        s = wave64_sum(s);
        if (lane == 0) dopnor[p] = s / (float)S_ + bias[j];
    }
}

__global__ void gain_kernel(const float* __restrict__ xmean,
                            const float* __restrict__ gw,
                            const float* __restrict__ gb,
                            float* __restrict__ qscale) {
    int wave = threadIdx.x >> 6, lane = threadIdx.x & 63;
    for (int p = wave; p < B_ * N_; p += 4) {
        int b = p >> 2, n = p & 3;
        float s = 0.f;
        for (int h = lane; h < H_; h += 64) s += xmean[b * H_ + h] * gw[n * H_ + h];
        s = wave64_sum(s);
        if (lane == 0) qscale[p] = (1.f + s / (float)S_ + gb[n]) * 0.0625f;
    }
}

// ---------------------------------------------------------------------------
// GEMM (m97 structure): C(MxN) = epilogue( A(MxK) @ W(NxK)^T + bias )
// modes: 0 plain->bf16; 1 gate; 2 noise; 3 residual; 4 silu; 5 plain->fp32;
//        6 V^T store
// ---------------------------------------------------------------------------
__global__ __launch_bounds__(256) void gemm_bt(
    const unsigned short* __restrict__ A, const unsigned short* __restrict__ W,
    const float* __restrict__ bias, void* __restrict__ Cout,
    const unsigned short* __restrict__ X, const float* __restrict__ scal,
    int K, int Nout, int mode) {
    __shared__ unsigned short As[128 * 32];
    __shared__ unsigned short Bs[128 * 32];
    int tid = threadIdx.x;
    int wave = tid >> 6, lane = tid & 63;
    int quad = lane >> 4, l16 = lane & 15;
    int bm = blockIdx.x * 128;
    int bn = blockIdx.y * 128;
    int mw = (wave >> 1) * 64, nw = (wave & 1) * 64;

    const unsigned short* Ag = A + (size_t)(bm + wave * 16 + (lane >> 2)) * K + (lane & 3) * 8;
    const unsigned short* Wg = W + (size_t)(bn + wave * 16 + (lane >> 2)) * K + (lane & 3) * 8;
    unsigned short* ldsA = As + wave * 512;
    unsigned short* ldsB = Bs + wave * 512;
    size_t rowskip = (size_t)64 * K;

    f32x4 acc[4][4];
#pragma unroll
    for (int i = 0; i < 4; i++)
#pragma unroll
        for (int j = 0; j < 4; j++)
#pragma unroll
            for (int r = 0; r < 4; r++) acc[i][j][r] = 0.f;

    for (int kk = 0; kk < K; kk += 32) {
        __syncthreads();
        gl_lds16(Ag + kk, ldsA);
        gl_lds16(Ag + rowskip + kk, ldsA + 2048);
        gl_lds16(Wg + kk, ldsB);
        gl_lds16(Wg + rowskip + kk, ldsB + 2048);
        __syncthreads();

        short8 af[4], bfr[4];
#pragma unroll
        for (int i = 0; i < 4; i++)
            af[i] = *(const short8*)&As[(mw + i * 16 + l16) * 32 + quad * 8];
#pragma unroll
        for (int j = 0; j < 4; j++)
            bfr[j] = *(const short8*)&Bs[(nw + j * 16 + l16) * 32 + quad * 8];
#pragma unroll
        for (int i = 0; i < 4; i++)
#pragma unroll
            for (int j = 0; j < 4; j++)
                acc[i][j] = __builtin_amdgcn_mfma_f32_16x16x32_bf16(af[i], bfr[j], acc[i][j], 0, 0, 0);
    }

    if (mode == 6) {
#pragma unroll
        for (int i = 0; i < 4; i++) {
#pragma unroll
            for (int j = 0; j < 4; j++) {
                int col = bn + nw + j * 16 + l16;
                float bv = bias ? bias[col] : 0.f;
                int n = col >> 8, d = col & 255;
                int row0 = bm + mw + i * 16 + quad * 4;
                int b = row0 >> 11, s0 = row0 & 2047;
                union { unsigned short u[4]; uint2 v; } pk;
#pragma unroll
                for (int r = 0; r < 4; r++) pk.u[r] = f2bf(acc[i][j][r] + bv);
                *(uint2*)((unsigned short*)Cout +
                          ((size_t)(b * N_ + n) * D_ + d) * S_ + s0) = pk.v;
            }
        }
        return;
    }

#pragma unroll
    for (int i = 0; i < 4; i++) {
#pragma unroll
        for (int j = 0; j < 4; j++) {
            int col = bn + nw + j * 16 + l16;
            float bv = bias ? bias[col] : 0.f;
#pragma unroll
            for (int r = 0; r < 4; r++) {
                int row = bm + mw + i * 16 + quad * 4 + r;
                float v = acc[i][j][r] + bv;
                size_t off = (size_t)row * Nout + col;
                if (mode == 5) {
                    ((float*)Cout)[off] = v;
                    continue;
                }
                float outv;
                if (mode == 0) {
                    outv = v;
                } else if (mode == 1) {
                    float sig = 1.f / (1.f + __expf(-v));
                    float dop = scal[(row >> 11) * 2];
                    outv = bf2f(X[off]) * (1.f + dop * sig);
                } else if (mode == 2) {
                    float nor = scal[(row >> 11) * 2 + 1];
                    outv = bf2f(X[off]) + nor * tanhf(v);
                } else if (mode == 3) {
                    outv = v + bf2f(X[off]);
                } else {
                    outv = v * (1.f / (1.f + __expf(-v)));
                }
                ((unsigned short*)Cout)[off] = f2bf(outv);
            }
        }
    }
}

// ---------------------------------------------------------------------------
// Fused QKV GEMM: W is (3H x H) fused [q;k;v] for one layer. N=3072.
// col block (64-aligned) selects destination: 0 -> Q, 1 -> K, 2 -> V^T store.
// ---------------------------------------------------------------------------
__global__ __launch_bounds__(256) void gemm_qkv(
    const unsigned short* __restrict__ A, const unsigned short* __restrict__ W,
    const float* __restrict__ qb, const float* __restrict__ kb,
    const float* __restrict__ vbb, unsigned short* __restrict__ Qo,
    unsigned short* __restrict__ Ko, unsigned short* __restrict__ Vt) {
    __shared__ unsigned short As[128 * 32];
    __shared__ unsigned short Bs[128 * 32];
    const int K = H_;
    int tid = threadIdx.x;
    int wave = tid >> 6, lane = tid & 63;
    int quad = lane >> 4, l16 = lane & 15;
    int bm = blockIdx.x * 128;
    int bn = blockIdx.y * 128;
    int mw = (wave >> 1) * 64, nw = (wave & 1) * 64;

    const unsigned short* Ag = A + (size_t)(bm + wave * 16 + (lane >> 2)) * K + (lane & 3) * 8;
    const unsigned short* Wg = W + (size_t)(bn + wave * 16 + (lane >> 2)) * K + (lane & 3) * 8;
    unsigned short* ldsA = As + wave * 512;
    unsigned short* ldsB = Bs + wave * 512;
    size_t rowskip = (size_t)64 * K;

    f32x4 acc[4][4];
#pragma unroll
    for (int i = 0; i < 4; i++)
#pragma unroll
        for (int j = 0; j < 4; j++)
#pragma unroll
            for (int r = 0; r < 4; r++) acc[i][j][r] = 0.f;

    for (int kk = 0; kk < K; kk += 32) {
        __syncthreads();
        gl_lds16(Ag + kk, ldsA);
        gl_lds16(Ag + rowskip + kk, ldsA + 2048);
        gl_lds16(Wg + kk, ldsB);
        gl_lds16(Wg + rowskip + kk, ldsB + 2048);
        __syncthreads();

        short8 af[4], bfr[4];
#pragma unroll
        for (int i = 0; i < 4; i++)
            af[i] = *(const short8*)&As[(mw + i * 16 + l16) * 32 + quad * 8];
#pragma unroll
        for (int j = 0; j < 4; j++)
            bfr[j] = *(const short8*)&Bs[(nw + j * 16 + l16) * 32 + quad * 8];
#pragma unroll
        for (int i = 0; i < 4; i++)
#pragma unroll
            for (int j = 0; j < 4; j++)
                acc[i][j] = __builtin_amdgcn_mfma_f32_16x16x32_bf16(af[i], bfr[j], acc[i][j], 0, 0, 0);
    }

    int sel = (bn + nw) >> 10;   // uniform per block-half
    if (sel == 2) {
#pragma unroll
        for (int i = 0; i < 4; i++) {
#pragma unroll
            for (int j = 0; j < 4; j++) {
                int c2 = ((bn + nw) & 1023) + j * 16 + l16;
                float bv = vbb[c2];
                int n = c2 >> 8, d = c2 & 255;
                int row0 = bm + mw + i * 16 + quad * 4;
                int b = row0 >> 11, s0 = row0 & 2047;
                union { unsigned short u[4]; uint2 v; } pk;
#pragma unroll
                for (int r = 0; r < 4; r++) pk.u[r] = f2bf(acc[i][j][r] + bv);
                *(uint2*)(Vt + ((size_t)(b * N_ + n) * D_ + d) * S_ + s0) = pk.v;
            }
        }
    } else {
        unsigned short* Co = (sel == 0) ? Qo : Ko;
        const float* bias = (sel == 0) ? qb : kb;
#pragma unroll
        for (int i = 0; i < 4; i++) {
#pragma unroll
            for (int j = 0; j < 4; j++) {
                int c2 = ((bn + nw) & 1023) + j * 16 + l16;
                float bv = bias[c2];
#pragma unroll
                for (int r = 0; r < 4; r++) {
                    int row = bm + mw + i * 16 + quad * 4 + r;
                    Co[(size_t)row * H_ + c2] = f2bf(acc[i][j][r] + bv);
                }
            }
        }
    }
}

// ---------------------------------------------------------------------------
// Flash attention, round-8: occupancy-first k-split.
// Lesson from r0/r2/r7: at 1 wave/SIMD the per-iteration latency floor
// (~10-13K cyc: staging latency + serialized softmax + barriers) dominates
// regardless of DS traffic; r7's 256-thr k-split doubled per-CU iterations
// at 1 wave/SIMD AND hit the 256-VGPR cap (spill). Fix both:
//   - 512 thr / 8 waves (the regime that compiles to 120-124 VGPR, no
//     spill: r1/r2 evidence), 16 q-rows/wave (o[16]+qf[8] ~ 96 regs);
//   - k-split across wave PAIRS: 4 pairs x {16 rows, half-k}; block = 64
//     q-rows; grid (S/64, B*N) = 512 blocks;
//   - LDS cut to 74 KiB (single-buffer K/V + Pl[8][16][40]; Vones dropped,
//     row-sum via 16-lane shfl reduce) -> 2 blocks/CU resident ->
//     16 waves/CU = 4 waves/SIMD. Cross-block TLP hides staging+softmax.
// Staging: global_load_lds with both-sides XOR swizzle (slot ^= row&7),
// 2 barriers/iter (single buffer). Defer-max THR=8 (mx recomputed on the
// rare rescale path to cut live VGPRs). End merge: odd half publishes
// (O,m,l) through dead LDS (pair 0-1 -> Kt, 2-3 -> Vt, m/l -> Pl); even
// half merges + writes. LDS: 32K K + 32K V + 10K Pl = 74 KiB.
// ---------------------------------------------------------------------------
__global__ __launch_bounds__(512) void flash_attn(
    const unsigned short* __restrict__ Q, const unsigned short* __restrict__ Kg,
    const unsigned short* __restrict__ VT, const float* __restrict__ qscale,
    unsigned short* __restrict__ O) {
    __shared__ unsigned short Kt[64 * 256];   // [row*256 + col], swizzled slots
    __shared__ unsigned short Vt[256 * 64];   // [d*64 + col], swizzled slots
    __shared__ unsigned short Pl[8][16][40];  // per-wave P (16 rows x 32 k)

    int tid = threadIdx.x;
    int wave = tid >> 6, lane = tid & 63;
    int quad = lane >> 4, l16 = lane & 15;
    int rx = l16 & 7;                         // read-side swizzle mask
    int pair = wave >> 1;                     // 0..3
    int khalf = wave & 1;
    int koff = khalf * 32;                    // k-col offset within tile
    int kv0 = khalf * 4;                      // V^T slot offset (16B slots)
    int bnh = blockIdx.y;
    size_t base = ((size_t)(bnh >> 2) * S_) * H_ + (size_t)(bnh & 3) * D_;
    size_t vtbase = (size_t)bnh * D_ * S_;
    int qw = blockIdx.x * 64 + pair * 16;
    float scale = qscale[bnh];

    // staging source-side swizzle lane constants
    int l5 = lane >> 5;                 // K: which of 2 rows in a 1KB chunk
    int ks = lane & 31;                 // K: lds slot within row (16B units)
    int vrow = lane >> 3;               // V: which of 8 rows in a 1KB chunk
    int vs = lane & 7;                  // V: lds slot within row
    int vmask = vrow & 7;

    short8 qf[8];
#pragma unroll
    for (int kk = 0; kk < 8; kk++)
        qf[kk] = *(const short8*)(Q + base +
            (size_t)(qw + l16) * H_ + kk * 32 + quad * 8);

    f32x4 o[16];
#pragma unroll
    for (int c = 0; c < 16; c++)
#pragma unroll
        for (int r = 0; r < 4; r++) o[c][r] = 0.f;
    float mrow[4], lsum[4];
#pragma unroll
    for (int r = 0; r < 4; r++) { mrow[r] = -1e30f; lsum[r] = 0.f; }

    for (int t0 = 0; t0 < S_; t0 += 64) {
        __syncthreads();   // previous iteration's reads done; safe to overwrite
        // stage K tile 64x256 + V^T tile 256x64 (32 chunks of 1KB each, 4/wave)
#pragma unroll
        for (int k = 0; k < 4; k++) {
            int chunk = 4 * wave + k;
            int kmask = (2 * k + l5) & 7;   // == (2*chunk+l5)&7 (8w = 0 mod 8)
            int grow = t0 + 2 * chunk + l5;
            int gcol = (ks ^ kmask) * 8;
            gl_lds16(Kg + base + (size_t)grow * H_ + gcol, &Kt[chunk * 512]);
        }
#pragma unroll
        for (int k = 0; k < 4; k++) {
            int chunk = 4 * wave + k;
            int d = 8 * chunk + vrow;
            int gcol = (vs ^ vmask) * 8;
            gl_lds16(VT + vtbase + (size_t)d * S_ + t0 + gcol, &Vt[chunk * 512]);
        }
        asm volatile("s_waitcnt vmcnt(0)" ::: "memory");
        __syncthreads();

        // QK^T: 16 q-rows x 32 k-cols (this wave's half)
        f32x4 s[2];
#pragma unroll
        for (int j = 0; j < 2; j++)
#pragma unroll
            for (int r = 0; r < 4; r++) s[j][r] = 0.f;
#pragma unroll
        for (int j = 0; j < 2; j++)
#pragma unroll
            for (int kk = 0; kk < 8; kk++) {
                short8 kf = *(const short8*)&Kt[(koff + j * 16 + l16) * 256 +
                                                ((4 * kk + quad) ^ rx) * 8];
                s[j] = __builtin_amdgcn_mfma_f32_16x16x32_bf16(qf[kk], kf, s[j], 0, 0, 0);
            }

        // online softmax (independent per k-half), defer-max THR=8.
        // Pass 1 computes the tile-max check only (no live mx array).
        float sv[4][2];
        bool ok = true;
#pragma unroll
        for (int r = 0; r < 4; r++) {
            sv[r][0] = s[0][r] * scale;
            sv[r][1] = s[1][r] * scale;
            float m0 = fmaxf(sv[r][0], sv[r][1]);
            for (int m = 8; m >= 1; m >>= 1) m0 = fmaxf(m0, __shfl_xor(m0, m, 64));
            ok = ok && (m0 <= mrow[r] + 8.f);
        }
        if (__all(ok)) {
#pragma unroll
            for (int r = 0; r < 4; r++) {
                float e0 = __expf(sv[r][0] - mrow[r]);
                float e1 = __expf(sv[r][1] - mrow[r]);
                Pl[wave][quad * 4 + r][l16]      = f2bf(e0);
                Pl[wave][quad * 4 + r][16 + l16] = f2bf(e1);
                float ps = e0 + e1;
                for (int m = 8; m >= 1; m >>= 1) ps += __shfl_xor(ps, m, 64);
                lsum[r] += ps;
            }
        } else {
#pragma unroll
            for (int r = 0; r < 4; r++) {
                float m0 = fmaxf(sv[r][0], sv[r][1]);   // recompute (rare path)
                for (int m = 8; m >= 1; m >>= 1) m0 = fmaxf(m0, __shfl_xor(m0, m, 64));
                float mnew = fmaxf(mrow[r], m0);
                float alpha = __expf(mrow[r] - mnew);
                mrow[r] = mnew;
                float e0 = __expf(sv[r][0] - mnew);
                float e1 = __expf(sv[r][1] - mnew);
                Pl[wave][quad * 4 + r][l16]      = f2bf(e0);
                Pl[wave][quad * 4 + r][16 + l16] = f2bf(e1);
                float ps = e0 + e1;
                for (int m = 8; m >= 1; m >>= 1) ps += __shfl_xor(ps, m, 64);
                lsum[r] = lsum[r] * alpha + ps;
#pragma unroll
                for (int c = 0; c < 16; c++) o[c][r] *= alpha;
            }
        }

        // PV over this wave's 32-k half
        short8 pf = *(const short8*)&Pl[wave][l16][quad * 8];
#pragma unroll
        for (int c = 0; c < 16; c++) {
            short8 vf = *(const short8*)&Vt[(c * 16 + l16) * 64 + ((kv0 + quad) ^ rx) * 8];
            o[c] = __builtin_amdgcn_mfma_f32_16x16x32_bf16(pf, vf, o[c], 0, 0, 0);
        }
    }

    // ---- end merge: odd half publishes (O, m, l); even half merges+writes.
    // Spill: pair 0-1 -> Kt (2 x 4096 floats of 8192 avail), pair 2-3 -> Vt;
    // m/l -> Pl (256 floats of 5120 avail). All LDS dead at this point.
    __syncthreads();
    float* Of = (pair < 2) ? ((float*)&Kt[0] + pair * 4096)
                           : ((float*)&Vt[0] + (pair - 2) * 4096);
    float* Ml = (float*)&Pl[0][0][0];
    if (khalf) {
#pragma unroll
        for (int c = 0; c < 16; c++)
            *(f32x4*)&Of[((c * 4 + quad) * 16 + l16) * 4] = o[c];
        if (l16 == 0) {
#pragma unroll
            for (int r = 0; r < 4; r++) {
                int row = quad * 4 + r;
                Ml[pair * 32 + row]      = mrow[r];
                Ml[pair * 32 + 16 + row] = lsum[r];
            }
        }
    }
    __syncthreads();
    if (!khalf) {
        float sca[4], scb[4];
#pragma unroll
        for (int r = 0; r < 4; r++) {
            int row = quad * 4 + r;
            float mb = Ml[pair * 32 + row];
            float lb = Ml[pair * 32 + 16 + row];
            float la = lsum[r];                 // already uniform in 16-group
            float mm = fmaxf(mrow[r], mb);
            float ea = __expf(mrow[r] - mm);
            float eb = __expf(mb - mm);
            float inv = 1.f / (ea * la + eb * lb);
            sca[r] = ea * inv;
            scb[r] = eb * inv;
        }
#pragma unroll
        for (int c = 0; c < 16; c++) {
            f32x4 ob = *(const f32x4*)&Of[((c * 4 + quad) * 16 + l16) * 4];
#pragma unroll
            for (int r = 0; r < 4; r++) {
                int row = qw + quad * 4 + r;
                int d = c * 16 + l16;
                O[base + (size_t)row * H_ + d] =
                    f2bf(o[c][r] * sca[r] + ob[r] * scb[r]);
            }
        }
    }
}

// ---------------------------------------------------------------------------
__global__ __launch_bounds__(256) void ln_kernel(
    const unsigned short* __restrict__ y, const float* __restrict__ g,
    const float* __restrict__ bta, unsigned short* __restrict__ out) {
    int row = blockIdx.x;
    size_t ro = (size_t)row * H_;
    int tid = threadIdx.x;
    float t[4]; float s = 0.f, s2 = 0.f;
#pragma unroll
    for (int i = 0; i < 4; i++) {
        int h = i * 256 + tid;
        float v = bf2f(y[ro + h]);
        t[i] = v; s += v; s2 += v * v;
    }
    s = wave64_sum(s); s2 = wave64_sum(s2);
    __shared__ float sh[8];
    int wave = tid >> 6, lane = tid & 63;
    if (lane == 0) { sh[wave] = s; sh[4 + wave] = s2; }
    __syncthreads();
    s  = sh[0] + sh[1] + sh[2] + sh[3];
    s2 = sh[4] + sh[5] + sh[6] + sh[7];
    float mu = s * (1.f / H_);
    float var = s2 * (1.f / H_) - mu * mu;
    float inv = rsqrtf(var + EPSF);
#pragma unroll
    for (int i = 0; i < 4; i++) {
        int h = i * 256 + tid;
        out[ro + h] = f2bf((t[i] - mu) * inv * g[h] + bta[h]);
    }
}

// ---------------------------------------------------------------------------
extern "C" void kernel_launch(void* const* d_in, const int* in_sizes, int n_in,
                              void* d_out, int out_size, void* d_ws, size_t ws_size,
                              hipStream_t stream) {
    const int*   ids          = (const int*)d_in[0];
    const float* embed        = (const float*)d_in[1];
    const float* nm_gate_w    = (const float*)d_in[2];
    const float* nm_gate_b    = (const float*)d_in[3];
    const float* nm_filter_w  = (const float*)d_in[4];
    const float* nm_filter_b  = (const float*)d_in[5];
    const float* nm_ctx_w     = (const float*)d_in[6];
    const float* nm_ctx_b     = (const float*)d_in[7];
    const float* q_w          = (const float*)d_in[8];
    const float* q_b          = (const float*)d_in[9];
    const float* k_w          = (const float*)d_in[10];
    const float* k_b          = (const float*)d_in[11];
    const float* v_w          = (const float*)d_in[12];
    const float* v_b          = (const float*)d_in[13];
    const float* gain_w       = (const float*)d_in[14];
    const float* gain_b       = (const float*)d_in[15];
    const float* attn_ow      = (const float*)d_in[16];
    const float* attn_ob      = (const float*)d_in[17];
    const float* en_w         = (const float*)d_in[18];
    const float* en_b         = (const float*)d_in[19];
    const float* plastic_w    = (const float*)d_in[20];
    const float* fix_w        = (const float*)d_in[21];
    const float* fix_b        = (const float*)d_in[22];
    const float* ln_g         = (const float*)d_in[23];
    const float* ln_b         = (const float*)d_in[24];
    const float* out_w        = (const float*)d_in[25];
    const float* out_b        = (const float*)d_in[26];

    size_t T  = (size_t)B_ * S_ * H_;
    size_t smallBytes = ((size_t)B_ * H_ + 2 * B_ + B_ * N_ + 8) * sizeof(float);
    size_t megaElems  = 26 * WH_ + WH_ / 4;
    size_t need_base  = 4 * T * 2 + smallBytes + 2 * WH_;
    size_t need_mega  = 4 * T * 2 + smallBytes + 2 * megaElems;
    if (ws_size < need_base) return;
    bool mega = ws_size >= need_mega;

    unsigned short* X   = (unsigned short*)d_ws;
    unsigned short* Qb  = X + T;
    unsigned short* Kb  = Qb + T;
    unsigned short* Vb  = Kb + T;
    float* xmean  = (float*)(Vb + T);
    float* dopnor = xmean + (size_t)B_ * H_;
    float* qscale = dopnor + 2 * B_;
    unsigned short* Wbase = (unsigned short*)(qscale + B_ * N_ + 8);
#define WOFF(k) (Wbase + (size_t)(k) * WH_)

    const int M   = B_ * S_;
    const int W8  = (int)(WH_ / 8);
    const int WG  = (W8 + 255) / 256;
    const int W84 = (int)(4 * WH_ / 8);
    const int WG4 = (W84 + 255) / 256;
    const int W8o = V_ * H_ / 8;
    const int WGo = (W8o + 255) / 256;

    if (mega) {
        wcvt_kernel<<<WG,  256, 0, stream>>>(nm_gate_w,   WOFF(0), W8);
        wcvt_kernel<<<WG,  256, 0, stream>>>(nm_filter_w, WOFF(1), W8);
        wcvt_qkv<<<WG4, 256, 0, stream>>>(q_w, WOFF(2), W84, 0);
        wcvt_qkv<<<WG4, 256, 0, stream>>>(k_w, WOFF(2), W84, 1);
        wcvt_qkv<<<WG4, 256, 0, stream>>>(v_w, WOFF(2), W84, 2);
        wcvt_kernel<<<WG4, 256, 0, stream>>>(attn_ow, WOFF(14), W84);
        wcvt_kernel<<<WG4, 256, 0, stream>>>(en_w,    WOFF(18), W84);
        wadd_kernel<<<WG4, 256, 0, stream>>>(fix_w, plastic_w, WOFF(22), W84);
        wcvt_kernel<<<WGo, 256, 0, stream>>>(out_w, WOFF(26), W8o);
    }

    gather_kernel<<<dim3((int)(T / 256)), 256, 0, stream>>>(ids, embed, X);

    hipMemsetAsync(xmean, 0, (size_t)B_ * H_ * sizeof(float), stream);
    mean_kernel<<<dim3(B_ * H_ / 256, 16), 256, 0, stream>>>(X, xmean);
    nm_kernel<<<1, 256, 0, stream>>>(xmean, nm_ctx_w, nm_ctx_b, dopnor);

    const unsigned short* Wp;
    if (mega) Wp = WOFF(0);
    else { wcvt_kernel<<<WG, 256, 0, stream>>>(nm_gate_w, Wbase, W8); Wp = Wbase; }
    gemm_bt<<<dim3(M / 128, H_ / 128), 256, 0, stream>>>(
        X, Wp, nm_gate_b, Qb, X, dopnor, H_, H_, 1);
    if (mega) Wp = WOFF(1);
    else { wcvt_kernel<<<WG, 256, 0, stream>>>(nm_filter_w, Wbase, W8); Wp = Wbase; }
    gemm_bt<<<dim3(M / 128, H_ / 128), 256, 0, stream>>>(
        Qb, Wp, nm_filter_b, X, Qb, dopnor, H_, H_, 2);

    for (int l = 0; l < L_; l++) {
        size_t wo = (size_t)l * WH_;
        size_t bo = (size_t)l * H_;
        hipMemsetAsync(xmean, 0, (size_t)B_ * H_ * sizeof(float), stream);
        mean_kernel<<<dim3(B_ * H_ / 256, 16), 256, 0, stream>>>(X, xmean);
        gain_kernel<<<1, 256, 0, stream>>>(xmean, gain_w + (size_t)l * N_ * H_,
                                           gain_b + (size_t)l * N_, qscale);

        if (mega) {
            gemm_qkv<<<dim3(M / 128, 3 * H_ / 128), 256, 0, stream>>>(
                X, WOFF(2) + (size_t)l * 3 * WH_, q_b + bo, k_b + bo, v_b + bo,
                Qb, Kb, Vb);
        } else {
            wcvt_kernel<<<WG, 256, 0, stream>>>(q_w + wo, Wbase, W8);
            gemm_bt<<<dim3(M / 128, H_ / 128), 256, 0, stream>>>(
                X, Wbase, q_b + bo, Qb, nullptr, nullptr, H_, H_, 0);
            wcvt_kernel<<<WG, 256, 0, stream>>>(k_w + wo, Wbase, W8);
            gemm_bt<<<dim3(M / 128, H_ / 128), 256, 0, stream>>>(
                X, Wbase, k_b + bo, Kb, nullptr, nullptr, H_, H_, 0);
            wcvt_kernel<<<WG, 256, 0, stream>>>(v_w + wo, Wbase, W8);
            gemm_bt<<<dim3(M / 128, H_ / 128), 256, 0, stream>>>(
                X, Wbase, v_b + bo, Vb, nullptr, nullptr, H_, H_, 6);
        }

        flash_attn<<<dim3(S_ / 64, B_ * N_), 512, 0, stream>>>(
            Qb, Kb, Vb, qscale, Qb);

        if (mega) Wp = WOFF(14) + wo;
        else { wcvt_kernel<<<WG, 256, 0, stream>>>(attn_ow + wo, Wbase, W8); Wp = Wbase; }
        gemm_bt<<<dim3(M / 128, H_ / 128), 256, 0, stream>>>(
            Qb, Wp, attn_ob + bo, Kb, X, nullptr, H_, H_, 3);
        if (mega) Wp = WOFF(18) + wo;
        else { wcvt_kernel<<<WG, 256, 0, stream>>>(en_w + wo, Wbase, W8); Wp = Wbase; }
        gemm_bt<<<dim3(M / 128, H_ / 128), 256, 0, stream>>>(
            Kb, Wp, en_b + bo, Vb, nullptr, nullptr, H_, H_, 4);
        if (mega) Wp = WOFF(22) + wo;
        else { wadd_kernel<<<WG, 256, 0, stream>>>(fix_w + wo, plastic_w + wo, Wbase, W8); Wp = Wbase; }
        gemm_bt<<<dim3(M / 128, H_ / 128), 256, 0, stream>>>(
            Vb, Wp, fix_b + bo, Qb, nullptr, nullptr, H_, H_, 0);
        ln_kernel<<<dim3(M), 256, 0, stream>>>(Qb, ln_g + bo, ln_b + bo, X);
    }

    if (mega) Wp = WOFF(26);
    else { wcvt_kernel<<<WGo, 256, 0, stream>>>(out_w, Wbase, W8o); Wp = Wbase; }
    gemm_bt<<<dim3(M / 128, V_ / 128), 256, 0, stream>>>(
        X, Wp, out_b, (float*)d_out, nullptr, nullptr, H_, V_, 5);
#undef WOFF
}

// Round 9
// 1626.430 us; speedup vs baseline: 2.7049x; 1.2779x over previous
//
#include <hip/hip_runtime.h>

#define B_ 4
#define S_ 2048
#define H_ 1024
#define L_ 4
#define N_ 4
#define D_ 256
#define V_ 256
#define EPSF 1e-5f
#define WH_ ((size_t)H_ * H_)   // 1<<20

typedef __attribute__((ext_vector_type(8))) short short8;
typedef __attribute__((ext_vector_type(4))) float f32x4;

__device__ inline float bf2f(unsigned short u) {
    union { unsigned int ui; float f; } c; c.ui = ((unsigned int)u) << 16; return c.f;
}
__device__ inline unsigned short f2bf(float f) {
    union { float f; unsigned int ui; } c; c.f = f;
    unsigned int u = c.ui;
    unsigned int r = (u + 0x7FFFu + ((u >> 16) & 1u)) >> 16;
    return (unsigned short)r;
}
__device__ inline float wave64_sum(float v) {
    for (int m = 32; m >= 1; m >>= 1) v += __shfl_xor(v, m, 64);
    return v;
}
__device__ inline void gl_lds16(const unsigned short* g, unsigned short* l) {
    __builtin_amdgcn_global_load_lds(
        (const __attribute__((address_space(1))) unsigned int*)g,
        (__attribute__((address_space(3))) unsigned int*)l, 16, 0, 0);
}

// ---------------------------------------------------------------------------
__global__ void wcvt_kernel(const float* __restrict__ W,
                            unsigned short* __restrict__ Wb, int n8) {
    int idx = blockIdx.x * 256 + threadIdx.x;
    if (idx >= n8) return;
    size_t base = (size_t)idx * 8;
    float4 a0 = *(const float4*)(W + base);
    float4 a1 = *(const float4*)(W + base + 4);
    short8 t;
    t[0] = f2bf(a0.x); t[1] = f2bf(a0.y); t[2] = f2bf(a0.z); t[3] = f2bf(a0.w);
    t[4] = f2bf(a1.x); t[5] = f2bf(a1.y); t[6] = f2bf(a1.z); t[7] = f2bf(a1.w);
    *(short8*)(Wb + base) = t;
}

// fp32 -> bf16 into QKV-fused layout: src (L,WH) -> dst layer*3WH + sel*WH
__global__ void wcvt_qkv(const float* __restrict__ W,
                         unsigned short* __restrict__ Wb, int n8, int sel) {
    int idx = blockIdx.x * 256 + threadIdx.x;
    if (idx >= n8) return;
    size_t p = (size_t)idx * 8;
    size_t layer = p >> 20;
    size_t within = p & (WH_ - 1);
    size_t dst = layer * 3 * WH_ + (size_t)sel * WH_ + within;
    float4 a0 = *(const float4*)(W + p);
    float4 a1 = *(const float4*)(W + p + 4);
    short8 t;
    t[0] = f2bf(a0.x); t[1] = f2bf(a0.y); t[2] = f2bf(a0.z); t[3] = f2bf(a0.w);
    t[4] = f2bf(a1.x); t[5] = f2bf(a1.y); t[6] = f2bf(a1.z); t[7] = f2bf(a1.w);
    *(short8*)(Wb + dst) = t;
}

// combined weight: Wo = bf16(Wa + Wb2 + I) per HxH layer (layers contiguous)
__global__ void wadd_kernel(const float* __restrict__ Wa, const float* __restrict__ Wb2,
                            unsigned short* __restrict__ Wo, int n8) {
    int idx = blockIdx.x * 256 + threadIdx.x;
    if (idx >= n8) return;
    size_t base = (size_t)idx * 8;
    short8 t;
#pragma unroll
    for (int e = 0; e < 8; e++) {
        size_t p = base + e;
        int pos = (int)(p & (WH_ - 1));
        float v = Wa[p] + Wb2[p] + (((pos >> 10) == (pos & (H_ - 1))) ? 1.f : 0.f);
        t[e] = f2bf(v);
    }
    *(short8*)(Wo + base) = t;
}

// ---------------------------------------------------------------------------
__global__ void gather_kernel(const int* __restrict__ ids,
                              const float* __restrict__ embed,
                              unsigned short* __restrict__ x) {
    size_t idx = (size_t)blockIdx.x * 256 + threadIdx.x;
    int bs = (int)(idx >> 10);
    int h  = (int)(idx & 1023);
    x[idx] = f2bf(embed[(size_t)ids[bs] * H_ + h]);
}

__global__ void mean_kernel(const unsigned short* __restrict__ Xin,
                            float* __restrict__ xmean) {
    int idx = blockIdx.x * 256 + threadIdx.x;
    int b = idx >> 10, h = idx & 1023;
    int s0 = blockIdx.y * 128;
    const unsigned short* p = Xin + ((size_t)b * S_ + s0) * H_ + h;
    float s = 0.f;
    for (int i = 0; i < 128; i++) s += bf2f(p[(size_t)i * H_]);
    atomicAdd(&xmean[idx], s);
}

__global__ void nm_kernel(const float* __restrict__ xmean,
                          const float* __restrict__ w,
                          const float* __restrict__ bias,
                          float* __restrict__ dopnor) {
    int wave = threadIdx.x >> 6, lane = threadIdx.x & 63;
    for (int p = wave; p < 2 * B_; p += 4) {
        int b = p >> 1, j = p & 1;
        float s = 0.f;
        for (int h = lane; h < H_; h += 64) s += xmean[b * H_ + h] * w[j * H_ + h];
        s = wave64_sum(s);
        if (lane == 0) dopnor[p] = s / (float)S_ + bias[j];
    }
}

__global__ void gain_kernel(const float* __restrict__ xmean,
                            const float* __restrict__ gw,
                            const float* __restrict__ gb,
                            float* __restrict__ qscale) {
    int wave = threadIdx.x >> 6, lane = threadIdx.x & 63;
    for (int p = wave; p < B_ * N_; p += 4) {
        int b = p >> 2, n = p & 3;
        float s = 0.f;
        for (int h = lane; h < H_; h += 64) s += xmean[b * H_ + h] * gw[n * H_ + h];
        s = wave64_sum(s);
        if (lane == 0) qscale[p] = (1.f + s / (float)S_ + gb[n]) * 0.0625f;
    }
}

// ---------------------------------------------------------------------------
// GEMM: C(MxN) = epilogue( A(MxK) @ W(NxK)^T + bias )
// Round-9: BK 32->64 (halves barrier-pair count 32->16 at K=1024 — m233:
// stage+vmcnt+barrier dominates 2-phase loops) + both-sides XOR swizzle
// (slot ^= row&7; pre-swizzled global source for global_load_lds, XOR on
// frag reads) to keep 8-way conflict parity (plain 128B rows would be
// 16-way). Same staged bytes, same MFMA count, bit-identical FP order.
// LDS 32 KB. modes: 0 plain->bf16; 1 gate; 2 noise; 3 residual; 4 silu;
// 5 plain->fp32; 6 V^T store
// ---------------------------------------------------------------------------
__global__ __launch_bounds__(256) void gemm_bt(
    const unsigned short* __restrict__ A, const unsigned short* __restrict__ W,
    const float* __restrict__ bias, void* __restrict__ Cout,
    const unsigned short* __restrict__ X, const float* __restrict__ scal,
    int K, int Nout, int mode) {
    __shared__ unsigned short As[128 * 64];
    __shared__ unsigned short Bs[128 * 64];
    int tid = threadIdx.x;
    int wave = tid >> 6, lane = tid & 63;
    int quad = lane >> 4, l16 = lane & 15;
    int rx = l16 & 7;
    int bm = blockIdx.x * 128;
    int bn = blockIdx.y * 128;
    int mw = (wave >> 1) * 64, nw = (wave & 1) * 64;

    int srow = lane >> 3;                // 0..7: row within 8-row chunk
    int scol = ((lane & 7) ^ srow) * 8;  // pre-swizzled source col (shorts)

    f32x4 acc[4][4];
#pragma unroll
    for (int i = 0; i < 4; i++)
#pragma unroll
        for (int j = 0; j < 4; j++)
#pragma unroll
            for (int r = 0; r < 4; r++) acc[i][j][r] = 0.f;

    for (int kk = 0; kk < K; kk += 64) {
        __syncthreads();
        // chunk c covers tile rows 8c..8c+7; LDS [row][slot^(row&7)] layout
#pragma unroll
        for (int k = 0; k < 4; k++) {
            int c = 4 * wave + k;
            gl_lds16(A + (size_t)(bm + 8 * c + srow) * K + kk + scol, As + c * 512);
            gl_lds16(W + (size_t)(bn + 8 * c + srow) * K + kk + scol, Bs + c * 512);
        }
        __syncthreads();

#pragma unroll
        for (int ks = 0; ks < 2; ks++) {
            short8 af[4], bfr[4];
#pragma unroll
            for (int i = 0; i < 4; i++)
                af[i] = *(const short8*)&As[(mw + i * 16 + l16) * 64 +
                                            (((ks * 4 + quad) ^ rx) * 8)];
#pragma unroll
            for (int j = 0; j < 4; j++)
                bfr[j] = *(const short8*)&Bs[(nw + j * 16 + l16) * 64 +
                                             (((ks * 4 + quad) ^ rx) * 8)];
#pragma unroll
            for (int i = 0; i < 4; i++)
#pragma unroll
                for (int j = 0; j < 4; j++)
                    acc[i][j] = __builtin_amdgcn_mfma_f32_16x16x32_bf16(af[i], bfr[j], acc[i][j], 0, 0, 0);
        }
    }

    if (mode == 6) {
#pragma unroll
        for (int i = 0; i < 4; i++) {
#pragma unroll
            for (int j = 0; j < 4; j++) {
                int col = bn + nw + j * 16 + l16;
                float bv = bias ? bias[col] : 0.f;
                int n = col >> 8, d = col & 255;
                int row0 = bm + mw + i * 16 + quad * 4;
                int b = row0 >> 11, s0 = row0 & 2047;
                union { unsigned short u[4]; uint2 v; } pk;
#pragma unroll
                for (int r = 0; r < 4; r++) pk.u[r] = f2bf(acc[i][j][r] + bv);
                *(uint2*)((unsigned short*)Cout +
                          ((size_t)(b * N_ + n) * D_ + d) * S_ + s0) = pk.v;
            }
        }
        return;
    }

#pragma unroll
    for (int i = 0; i < 4; i++) {
#pragma unroll
        for (int j = 0; j < 4; j++) {
            int col = bn + nw + j * 16 + l16;
            float bv = bias ? bias[col] : 0.f;
#pragma unroll
            for (int r = 0; r < 4; r++) {
                int row = bm + mw + i * 16 + quad * 4 + r;
                float v = acc[i][j][r] + bv;
                size_t off = (size_t)row * Nout + col;
                if (mode == 5) {
                    ((float*)Cout)[off] = v;
                    continue;
                }
                float outv;
                if (mode == 0) {
                    outv = v;
                } else if (mode == 1) {
                    float sig = 1.f / (1.f + __expf(-v));
                    float dop = scal[(row >> 11) * 2];
                    outv = bf2f(X[off]) * (1.f + dop * sig);
                } else if (mode == 2) {
                    float nor = scal[(row >> 11) * 2 + 1];
                    outv = bf2f(X[off]) + nor * tanhf(v);
                } else if (mode == 3) {
                    outv = v + bf2f(X[off]);
                } else {
                    outv = v * (1.f / (1.f + __expf(-v)));
                }
                ((unsigned short*)Cout)[off] = f2bf(outv);
            }
        }
    }
}

// ---------------------------------------------------------------------------
// Fused QKV GEMM: W is (3H x H) fused [q;k;v] for one layer. N=3072.
// Same BK=64 + swizzle structure as gemm_bt.
// col block (64-aligned) selects destination: 0 -> Q, 1 -> K, 2 -> V^T store.
// ---------------------------------------------------------------------------
__global__ __launch_bounds__(256) void gemm_qkv(
    const unsigned short* __restrict__ A, const unsigned short* __restrict__ W,
    const float* __restrict__ qb, const float* __restrict__ kb,
    const float* __restrict__ vbb, unsigned short* __restrict__ Qo,
    unsigned short* __restrict__ Ko, unsigned short* __restrict__ Vt) {
    __shared__ unsigned short As[128 * 64];
    __shared__ unsigned short Bs[128 * 64];
    const int K = H_;
    int tid = threadIdx.x;
    int wave = tid >> 6, lane = tid & 63;
    int quad = lane >> 4, l16 = lane & 15;
    int rx = l16 & 7;
    int bm = blockIdx.x * 128;
    int bn = blockIdx.y * 128;
    int mw = (wave >> 1) * 64, nw = (wave & 1) * 64;

    int srow = lane >> 3;
    int scol = ((lane & 7) ^ srow) * 8;

    f32x4 acc[4][4];
#pragma unroll
    for (int i = 0; i < 4; i++)
#pragma unroll
        for (int j = 0; j < 4; j++)
#pragma unroll
            for (int r = 0; r < 4; r++) acc[i][j][r] = 0.f;

    for (int kk = 0; kk < K; kk += 64) {
        __syncthreads();
#pragma unroll
        for (int k = 0; k < 4; k++) {
            int c = 4 * wave + k;
            gl_lds16(A + (size_t)(bm + 8 * c + srow) * K + kk + scol, As + c * 512);
            gl_lds16(W + (size_t)(bn + 8 * c + srow) * K + kk + scol, Bs + c * 512);
        }
        __syncthreads();

#pragma unroll
        for (int ks = 0; ks < 2; ks++) {
            short8 af[4], bfr[4];
#pragma unroll
            for (int i = 0; i < 4; i++)
                af[i] = *(const short8*)&As[(mw + i * 16 + l16) * 64 +
                                            (((ks * 4 + quad) ^ rx) * 8)];
#pragma unroll
            for (int j = 0; j < 4; j++)
                bfr[j] = *(const short8*)&Bs[(nw + j * 16 + l16) * 64 +
                                             (((ks * 4 + quad) ^ rx) * 8)];
#pragma unroll
            for (int i = 0; i < 4; i++)
#pragma unroll
                for (int j = 0; j < 4; j++)
                    acc[i][j] = __builtin_amdgcn_mfma_f32_16x16x32_bf16(af[i], bfr[j], acc[i][j], 0, 0, 0);
        }
    }

    int sel = (bn + nw) >> 10;   // uniform per block-half
    if (sel == 2) {
#pragma unroll
        for (int i = 0; i < 4; i++) {
#pragma unroll
            for (int j = 0; j < 4; j++) {
                int c2 = ((bn + nw) & 1023) + j * 16 + l16;
                float bv = vbb[c2];
                int n = c2 >> 8, d = c2 & 255;
                int row0 = bm + mw + i * 16 + quad * 4;
                int b = row0 >> 11, s0 = row0 & 2047;
                union { unsigned short u[4]; uint2 v; } pk;
#pragma unroll
                for (int r = 0; r < 4; r++) pk.u[r] = f2bf(acc[i][j][r] + bv);
                *(uint2*)(Vt + ((size_t)(b * N_ + n) * D_ + d) * S_ + s0) = pk.v;
            }
        }
    } else {
        unsigned short* Co = (sel == 0) ? Qo : Ko;
        const float* bias = (sel == 0) ? qb : kb;
#pragma unroll
        for (int i = 0; i < 4; i++) {
#pragma unroll
            for (int j = 0; j < 4; j++) {
                int c2 = ((bn + nw) & 1023) + j * 16 + l16;
                float bv = bias[c2];
#pragma unroll
                for (int r = 0; r < 4; r++) {
                    int row = bm + mw + i * 16 + quad * 4 + r;
                    Co[(size_t)row * H_ + c2] = f2bf(acc[i][j][r] + bv);
                }
            }
        }
    }
}

// ---------------------------------------------------------------------------
// Flash attention (round-2 kernel, measured 131 us — restored verbatim).
// 512 thr = 8 waves x 16 q-rows, full t-range. Grid (S/128, B*N) = 256
// blocks, 1 block/CU, 2 waves/SIMD. Double-buffered K/V via global_load_lds
// (linear LDS dest), both-sides XOR swizzle (slot ^= row&7), one
// vmcnt(0)+barrier per tile. Ones-tile row-sum in Vones. Defer-max THR=8.
// LDS: 2*32K (K) + 2*32K (V) + 2.25K + 18K (Pl) = 148 KiB.
// ---------------------------------------------------------------------------
__global__ __launch_bounds__(512) void flash_attn(
    const unsigned short* __restrict__ Q, const unsigned short* __restrict__ Kg,
    const unsigned short* __restrict__ VT, const float* __restrict__ qscale,
    unsigned short* __restrict__ O) {
    __shared__ unsigned short Kb[2][64 * 256];   // [buf][row*256 + col], swizzled slots
    __shared__ unsigned short Vb[2][256 * 64];   // [buf][d*64 + col], swizzled slots
    __shared__ unsigned short Vones[16][72];     // ones tile for row-sum (padded)
    __shared__ unsigned short Pl[8][16][72];

    int tid = threadIdx.x;
    int wave = tid >> 6, lane = tid & 63;
    int quad = lane >> 4, l16 = lane & 15;
    int rx = l16 & 7;                            // read-side swizzle mask
    int bnh = blockIdx.y;
    size_t base = ((size_t)(bnh >> 2) * S_) * H_ + (size_t)(bnh & 3) * D_;
    size_t vtbase = (size_t)bnh * D_ * S_;
    int qw = blockIdx.x * 128 + wave * 16;
    float scale = qscale[bnh];

    for (int c = tid; c < 16 * 72; c += 512) {
        int rr = c / 72, cc = c - rr * 72;
        Vones[rr][cc] = (rr == 0) ? (unsigned short)0x3F80 : (unsigned short)0;
    }

    // staging source-side swizzle masks (per-lane constants)
    int l5 = lane >> 5;                 // K: which of 2 rows in a 1KB chunk
    int ks = lane & 31;                 // K: lds slot within row (16B units)
    int vrow = lane >> 3;               // V: which of 8 rows in a 1KB chunk
    int vs = lane & 7;                  // V: lds slot within row
    int vmask = vrow & 7;

    short8 qf[8];
#pragma unroll
    for (int kk = 0; kk < 8; kk++)
        qf[kk] = *(const short8*)(Q + base +
            (size_t)(qw + l16) * H_ + kk * 32 + quad * 8);

    f32x4 o[16], osum;
#pragma unroll
    for (int c = 0; c < 16; c++)
#pragma unroll
        for (int r = 0; r < 4; r++) o[c][r] = 0.f;
#pragma unroll
    for (int r = 0; r < 4; r++) osum[r] = 0.f;
    float mrow[4];
#pragma unroll
    for (int r = 0; r < 4; r++) mrow[r] = -1e30f;

    // prologue: stage tile 0 into buffer 0
    {
#pragma unroll
        for (int k = 0; k < 4; k++) {
            int chunk = 4 * wave + k;
            int kmask = (2 * k + l5) & 7;       // row&7 of the LDS row written
            int grow = 2 * chunk + l5;
            int gcol = ((ks ^ kmask)) * 8;
            gl_lds16(Kg + base + (size_t)grow * H_ + gcol, &Kb[0][chunk * 512]);
        }
#pragma unroll
        for (int k = 0; k < 4; k++) {
            int chunk = 4 * wave + k;
            int d = 8 * chunk + vrow;
            int gcol = ((vs ^ vmask)) * 8;
            gl_lds16(VT + vtbase + (size_t)d * S_ + gcol, &Vb[0][chunk * 512]);
        }
    }
    asm volatile("s_waitcnt vmcnt(0)" ::: "memory");
    __syncthreads();

    int cur = 0;
    for (int t0 = 0; t0 < S_; t0 += 64) {
        // issue next tile's loads into the other buffer (fly under compute)
        if (t0 + 64 < S_) {
            int nb = cur ^ 1;
#pragma unroll
            for (int k = 0; k < 4; k++) {
                int chunk = 4 * wave + k;
                int kmask = (2 * k + l5) & 7;
                int grow = t0 + 64 + 2 * chunk + l5;
                int gcol = ((ks ^ kmask)) * 8;
                gl_lds16(Kg + base + (size_t)grow * H_ + gcol, &Kb[nb][chunk * 512]);
            }
#pragma unroll
            for (int k = 0; k < 4; k++) {
                int chunk = 4 * wave + k;
                int d = 8 * chunk + vrow;
                int gcol = ((vs ^ vmask)) * 8;
                gl_lds16(VT + vtbase + (size_t)d * S_ + t0 + 64 + gcol, &Vb[nb][chunk * 512]);
            }
        }

        const unsigned short* Kc = Kb[cur];
        const unsigned short* Vc = Vb[cur];

        // QK^T for this wave's 16 rows (swizzled K reads)
        f32x4 s[4];
#pragma unroll
        for (int j = 0; j < 4; j++)
#pragma unroll
            for (int r = 0; r < 4; r++) s[j][r] = 0.f;
#pragma unroll
        for (int j = 0; j < 4; j++)
#pragma unroll
            for (int kk = 0; kk < 8; kk++) {
                short8 kf = *(const short8*)&Kc[(j * 16 + l16) * 256 +
                                                ((4 * kk + quad) ^ rx) * 8];
                s[j] = __builtin_amdgcn_mfma_f32_16x16x32_bf16(qf[kk], kf, s[j], 0, 0, 0);
            }

        // online softmax with defer-max (THR=8)
        float sv[4][4], mx[4];
        bool ok = true;
#pragma unroll
        for (int r = 0; r < 4; r++) {
#pragma unroll
            for (int j = 0; j < 4; j++) sv[r][j] = s[j][r] * scale;
            float m0 = fmaxf(fmaxf(sv[r][0], sv[r][1]), fmaxf(sv[r][2], sv[r][3]));
            for (int m = 8; m >= 1; m >>= 1) m0 = fmaxf(m0, __shfl_xor(m0, m, 64));
            mx[r] = m0;
            ok = ok && (m0 <= mrow[r] + 8.f);
        }
        if (__all(ok)) {
#pragma unroll
            for (int r = 0; r < 4; r++)
#pragma unroll
                for (int j = 0; j < 4; j++)
                    Pl[wave][quad * 4 + r][j * 16 + l16] =
                        f2bf(__expf(sv[r][j] - mrow[r]));
        } else {
            float alpha[4];
#pragma unroll
            for (int r = 0; r < 4; r++) {
                float mnew = fmaxf(mrow[r], mx[r]);
                alpha[r] = __expf(mrow[r] - mnew);
                mrow[r] = mnew;
#pragma unroll
                for (int j = 0; j < 4; j++)
                    Pl[wave][quad * 4 + r][j * 16 + l16] =
                        f2bf(__expf(sv[r][j] - mnew));
            }
#pragma unroll
            for (int c = 0; c < 16; c++)
#pragma unroll
                for (int r = 0; r < 4; r++) o[c][r] *= alpha[r];
#pragma unroll
            for (int r = 0; r < 4; r++) osum[r] *= alpha[r];
        }

        // PV (swizzled V reads)
        short8 pf0 = *(const short8*)&Pl[wave][l16][quad * 8];
        short8 pf1 = *(const short8*)&Pl[wave][l16][32 + quad * 8];
#pragma unroll
        for (int c = 0; c < 16; c++) {
            short8 vf0 = *(const short8*)&Vc[(c * 16 + l16) * 64 + (quad ^ rx) * 8];
            o[c] = __builtin_amdgcn_mfma_f32_16x16x32_bf16(pf0, vf0, o[c], 0, 0, 0);
            short8 vf1 = *(const short8*)&Vc[(c * 16 + l16) * 64 + ((4 | quad) ^ rx) * 8];
            o[c] = __builtin_amdgcn_mfma_f32_16x16x32_bf16(pf1, vf1, o[c], 0, 0, 0);
        }
        {
            short8 vs0 = *(const short8*)&Vones[l16][quad * 8];
            short8 vs1 = *(const short8*)&Vones[l16][32 + quad * 8];
            osum = __builtin_amdgcn_mfma_f32_16x16x32_bf16(pf0, vs0, osum, 0, 0, 0);
            osum = __builtin_amdgcn_mfma_f32_16x16x32_bf16(pf1, vs1, osum, 0, 0, 0);
        }

        // next tile must have landed; all waves done reading current buffers
        asm volatile("s_waitcnt vmcnt(0)" ::: "memory");
        __syncthreads();
        cur ^= 1;
    }

    float invl[4];
#pragma unroll
    for (int r = 0; r < 4; r++)
        invl[r] = 1.f / __shfl(osum[r], (lane & 48), 64);
#pragma unroll
    for (int c = 0; c < 16; c++)
#pragma unroll
        for (int r = 0; r < 4; r++) {
            int row = qw + quad * 4 + r;
            int d = c * 16 + l16;
            O[base + (size_t)row * H_ + d] = f2bf(o[c][r] * invl[r]);
        }
}

// ---------------------------------------------------------------------------
__global__ __launch_bounds__(256) void ln_kernel(
    const unsigned short* __restrict__ y, const float* __restrict__ g,
    const float* __restrict__ bta, unsigned short* __restrict__ out) {
    int row = blockIdx.x;
    size_t ro = (size_t)row * H_;
    int tid = threadIdx.x;
    float t[4]; float s = 0.f, s2 = 0.f;
#pragma unroll
    for (int i = 0; i < 4; i++) {
        int h = i * 256 + tid;
        float v = bf2f(y[ro + h]);
        t[i] = v; s += v; s2 += v * v;
    }
    s = wave64_sum(s); s2 = wave64_sum(s2);
    __shared__ float sh[8];
    int wave = tid >> 6, lane = tid & 63;
    if (lane == 0) { sh[wave] = s; sh[4 + wave] = s2; }
    __syncthreads();
    s  = sh[0] + sh[1] + sh[2] + sh[3];
    s2 = sh[4] + sh[5] + sh[6] + sh[7];
    float mu = s * (1.f / H_);
    float var = s2 * (1.f / H_) - mu * mu;
    float inv = rsqrtf(var + EPSF);
#pragma unroll
    for (int i = 0; i < 4; i++) {
        int h = i * 256 + tid;
        out[ro + h] = f2bf((t[i] - mu) * inv * g[h] + bta[h]);
    }
}

// ---------------------------------------------------------------------------
extern "C" void kernel_launch(void* const* d_in, const int* in_sizes, int n_in,
                              void* d_out, int out_size, void* d_ws, size_t ws_size,
                              hipStream_t stream) {
    const int*   ids          = (const int*)d_in[0];
    const float* embed        = (const float*)d_in[1];
    const float* nm_gate_w    = (const float*)d_in[2];
    const float* nm_gate_b    = (const float*)d_in[3];
    const float* nm_filter_w  = (const float*)d_in[4];
    const float* nm_filter_b  = (const float*)d_in[5];
    const float* nm_ctx_w     = (const float*)d_in[6];
    const float* nm_ctx_b     = (const float*)d_in[7];
    const float* q_w          = (const float*)d_in[8];
    const float* q_b          = (const float*)d_in[9];
    const float* k_w          = (const float*)d_in[10];
    const float* k_b          = (const float*)d_in[11];
    const float* v_w          = (const float*)d_in[12];
    const float* v_b          = (const float*)d_in[13];
    const float* gain_w       = (const float*)d_in[14];
    const float* gain_b       = (const float*)d_in[15];
    const float* attn_ow      = (const float*)d_in[16];
    const float* attn_ob      = (const float*)d_in[17];
    const float* en_w         = (const float*)d_in[18];
    const float* en_b         = (const float*)d_in[19];
    const float* plastic_w    = (const float*)d_in[20];
    const float* fix_w        = (const float*)d_in[21];
    const float* fix_b        = (const float*)d_in[22];
    const float* ln_g         = (const float*)d_in[23];
    const float* ln_b         = (const float*)d_in[24];
    const float* out_w        = (const float*)d_in[25];
    const float* out_b        = (const float*)d_in[26];

    size_t T  = (size_t)B_ * S_ * H_;
    size_t smallBytes = ((size_t)B_ * H_ + 2 * B_ + B_ * N_ + 8) * sizeof(float);
    size_t megaElems  = 26 * WH_ + WH_ / 4;
    size_t need_base  = 4 * T * 2 + smallBytes + 2 * WH_;
    size_t need_mega  = 4 * T * 2 + smallBytes + 2 * megaElems;
    if (ws_size < need_base) return;
    bool mega = ws_size >= need_mega;

    unsigned short* X   = (unsigned short*)d_ws;
    unsigned short* Qb  = X + T;
    unsigned short* Kb  = Qb + T;
    unsigned short* Vb  = Kb + T;
    float* xmean  = (float*)(Vb + T);
    float* dopnor = xmean + (size_t)B_ * H_;
    float* qscale = dopnor + 2 * B_;
    unsigned short* Wbase = (unsigned short*)(qscale + B_ * N_ + 8);
#define WOFF(k) (Wbase + (size_t)(k) * WH_)

    const int M   = B_ * S_;
    const int W8  = (int)(WH_ / 8);
    const int WG  = (W8 + 255) / 256;
    const int W84 = (int)(4 * WH_ / 8);
    const int WG4 = (W84 + 255) / 256;
    const int W8o = V_ * H_ / 8;
    const int WGo = (W8o + 255) / 256;

    if (mega) {
        wcvt_kernel<<<WG,  256, 0, stream>>>(nm_gate_w,   WOFF(0), W8);
        wcvt_kernel<<<WG,  256, 0, stream>>>(nm_filter_w, WOFF(1), W8);
        wcvt_qkv<<<WG4, 256, 0, stream>>>(q_w, WOFF(2), W84, 0);
        wcvt_qkv<<<WG4, 256, 0, stream>>>(k_w, WOFF(2), W84, 1);
        wcvt_qkv<<<WG4, 256, 0, stream>>>(v_w, WOFF(2), W84, 2);
        wcvt_kernel<<<WG4, 256, 0, stream>>>(attn_ow, WOFF(14), W84);
        wcvt_kernel<<<WG4, 256, 0, stream>>>(en_w,    WOFF(18), W84);
        wadd_kernel<<<WG4, 256, 0, stream>>>(fix_w, plastic_w, WOFF(22), W84);
        wcvt_kernel<<<WGo, 256, 0, stream>>>(out_w, WOFF(26), W8o);
    }

    gather_kernel<<<dim3((int)(T / 256)), 256, 0, stream>>>(ids, embed, X);

    hipMemsetAsync(xmean, 0, (size_t)B_ * H_ * sizeof(float), stream);
    mean_kernel<<<dim3(B_ * H_ / 256, 16), 256, 0, stream>>>(X, xmean);
    nm_kernel<<<1, 256, 0, stream>>>(xmean, nm_ctx_w, nm_ctx_b, dopnor);

    const unsigned short* Wp;
    if (mega) Wp = WOFF(0);
    else { wcvt_kernel<<<WG, 256, 0, stream>>>(nm_gate_w, Wbase, W8); Wp = Wbase; }
    gemm_bt<<<dim3(M / 128, H_ / 128), 256, 0, stream>>>(
        X, Wp, nm_gate_b, Qb, X, dopnor, H_, H_, 1);
    if (mega) Wp = WOFF(1);
    else { wcvt_kernel<<<WG, 256, 0, stream>>>(nm_filter_w, Wbase, W8); Wp = Wbase; }
    gemm_bt<<<dim3(M / 128, H_ / 128), 256, 0, stream>>>(
        Qb, Wp, nm_filter_b, X, Qb, dopnor, H_, H_, 2);

    for (int l = 0; l < L_; l++) {
        size_t wo = (size_t)l * WH_;
        size_t bo = (size_t)l * H_;
        hipMemsetAsync(xmean, 0, (size_t)B_ * H_ * sizeof(float), stream);
        mean_kernel<<<dim3(B_ * H_ / 256, 16), 256, 0, stream>>>(X, xmean);
        gain_kernel<<<1, 256, 0, stream>>>(xmean, gain_w + (size_t)l * N_ * H_,
                                           gain_b + (size_t)l * N_, qscale);

        if (mega) {
            gemm_qkv<<<dim3(M / 128, 3 * H_ / 128), 256, 0, stream>>>(
                X, WOFF(2) + (size_t)l * 3 * WH_, q_b + bo, k_b + bo, v_b + bo,
                Qb, Kb, Vb);
        } else {
            wcvt_kernel<<<WG, 256, 0, stream>>>(q_w + wo, Wbase, W8);
            gemm_bt<<<dim3(M / 128, H_ / 128), 256, 0, stream>>>(
                X, Wbase, q_b + bo, Qb, nullptr, nullptr, H_, H_, 0);
            wcvt_kernel<<<WG, 256, 0, stream>>>(k_w + wo, Wbase, W8);
            gemm_bt<<<dim3(M / 128, H_ / 128), 256, 0, stream>>>(
                X, Wbase, k_b + bo, Kb, nullptr, nullptr, H_, H_, 0);
            wcvt_kernel<<<WG, 256, 0, stream>>>(v_w + wo, Wbase, W8);
            gemm_bt<<<dim3(M / 128, H_ / 128), 256, 0, stream>>>(
                X, Wbase, v_b + bo, Vb, nullptr, nullptr, H_, H_, 6);
        }

        flash_attn<<<dim3(S_ / 128, B_ * N_), 512, 0, stream>>>(
            Qb, Kb, Vb, qscale, Qb);

        if (mega) Wp = WOFF(14) + wo;
        else { wcvt_kernel<<<WG, 256, 0, stream>>>(attn_ow + wo, Wbase, W8); Wp = Wbase; }
        gemm_bt<<<dim3(M / 128, H_ / 128), 256, 0, stream>>>(
            Qb, Wp, attn_ob + bo, Kb, X, nullptr, H_, H_, 3);
        if (mega) Wp = WOFF(18) + wo;
        else { wcvt_kernel<<<WG, 256, 0, stream>>>(en_w + wo, Wbase, W8); Wp = Wbase; }
        gemm_bt<<<dim3(M / 128, H_ / 128), 256, 0, stream>>>(
            Kb, Wp, en_b + bo, Vb, nullptr, nullptr, H_, H_, 4);
        if (mega) Wp = WOFF(22) + wo;
        else { wadd_kernel<<<WG, 256, 0, stream>>>(fix_w + wo, plastic_w + wo, Wbase, W8); Wp = Wbase; }
        gemm_bt<<<dim3(M / 128, H_ / 128), 256, 0, stream>>>(
            Vb, Wp, fix_b + bo, Qb, nullptr, nullptr, H_, H_, 0);
        ln_kernel<<<dim3(M), 256, 0, stream>>>(Qb, ln_g + bo, ln_b + bo, X);
    }

    if (mega) Wp = WOFF(26);
    else { wcvt_kernel<<<WGo, 256, 0, stream>>>(out_w, Wbase, W8o); Wp = Wbase; }
    gemm_bt<<<dim3(M / 128, V_ / 128), 256, 0, stream>>>(
        X, Wp, out_b, (float*)d_out, nullptr, nullptr, H_, V_, 5);
#undef WOFF
}

// Round 10
// 1606.244 us; speedup vs baseline: 2.7389x; 1.0126x over previous
//
#include <hip/hip_runtime.h>

#define B_ 4
#define S_ 2048
#define H_ 1024
#define L_ 4
#define N_ 4
#define D_ 256
#define V_ 256
#define EPSF 1e-5f
#define WH_ ((size_t)H_ * H_)   // 1<<20

typedef __attribute__((ext_vector_type(8))) short short8;
typedef __attribute__((ext_vector_type(4))) float f32x4;

__device__ inline float bf2f(unsigned short u) {
    union { unsigned int ui; float f; } c; c.ui = ((unsigned int)u) << 16; return c.f;
}
__device__ inline unsigned short f2bf(float f) {
    union { float f; unsigned int ui; } c; c.f = f;
    unsigned int u = c.ui;
    unsigned int r = (u + 0x7FFFu + ((u >> 16) & 1u)) >> 16;
    return (unsigned short)r;
}
__device__ inline float wave64_sum(float v) {
    for (int m = 32; m >= 1; m >>= 1) v += __shfl_xor(v, m, 64);
    return v;
}
__device__ inline void gl_lds16(const unsigned short* g, unsigned short* l) {
    __builtin_amdgcn_global_load_lds(
        (const __attribute__((address_space(1))) unsigned int*)g,
        (__attribute__((address_space(3))) unsigned int*)l, 16, 0, 0);
}

// ---------------------------------------------------------------------------
__global__ void wcvt_kernel(const float* __restrict__ W,
                            unsigned short* __restrict__ Wb, int n8) {
    int idx = blockIdx.x * 256 + threadIdx.x;
    if (idx >= n8) return;
    size_t base = (size_t)idx * 8;
    float4 a0 = *(const float4*)(W + base);
    float4 a1 = *(const float4*)(W + base + 4);
    short8 t;
    t[0] = f2bf(a0.x); t[1] = f2bf(a0.y); t[2] = f2bf(a0.z); t[3] = f2bf(a0.w);
    t[4] = f2bf(a1.x); t[5] = f2bf(a1.y); t[6] = f2bf(a1.z); t[7] = f2bf(a1.w);
    *(short8*)(Wb + base) = t;
}

// fp32 -> bf16 into QKV-fused layout: src (L,WH) -> dst layer*3WH + sel*WH
__global__ void wcvt_qkv(const float* __restrict__ W,
                         unsigned short* __restrict__ Wb, int n8, int sel) {
    int idx = blockIdx.x * 256 + threadIdx.x;
    if (idx >= n8) return;
    size_t p = (size_t)idx * 8;
    size_t layer = p >> 20;
    size_t within = p & (WH_ - 1);
    size_t dst = layer * 3 * WH_ + (size_t)sel * WH_ + within;
    float4 a0 = *(const float4*)(W + p);
    float4 a1 = *(const float4*)(W + p + 4);
    short8 t;
    t[0] = f2bf(a0.x); t[1] = f2bf(a0.y); t[2] = f2bf(a0.z); t[3] = f2bf(a0.w);
    t[4] = f2bf(a1.x); t[5] = f2bf(a1.y); t[6] = f2bf(a1.z); t[7] = f2bf(a1.w);
    *(short8*)(Wb + dst) = t;
}

// combined weight: Wo = bf16(Wa + Wb2 + I) per HxH layer (layers contiguous)
__global__ void wadd_kernel(const float* __restrict__ Wa, const float* __restrict__ Wb2,
                            unsigned short* __restrict__ Wo, int n8) {
    int idx = blockIdx.x * 256 + threadIdx.x;
    if (idx >= n8) return;
    size_t base = (size_t)idx * 8;
    short8 t;
#pragma unroll
    for (int e = 0; e < 8; e++) {
        size_t p = base + e;
        int pos = (int)(p & (WH_ - 1));
        float v = Wa[p] + Wb2[p] + (((pos >> 10) == (pos & (H_ - 1))) ? 1.f : 0.f);
        t[e] = f2bf(v);
    }
    *(short8*)(Wo + base) = t;
}

// ---------------------------------------------------------------------------
__global__ void gather_kernel(const int* __restrict__ ids,
                              const float* __restrict__ embed,
                              unsigned short* __restrict__ x) {
    size_t idx = (size_t)blockIdx.x * 256 + threadIdx.x;
    int bs = (int)(idx >> 10);
    int h  = (int)(idx & 1023);
    x[idx] = f2bf(embed[(size_t)ids[bs] * H_ + h]);
}

__global__ void mean_kernel(const unsigned short* __restrict__ Xin,
                            float* __restrict__ xmean) {
    int idx = blockIdx.x * 256 + threadIdx.x;
    int b = idx >> 10, h = idx & 1023;
    int s0 = blockIdx.y * 128;
    const unsigned short* p = Xin + ((size_t)b * S_ + s0) * H_ + h;
    float s = 0.f;
    for (int i = 0; i < 128; i++) s += bf2f(p[(size_t)i * H_]);
    atomicAdd(&xmean[idx], s);
}

__global__ void nm_kernel(const float* __restrict__ xmean,
                          const float* __restrict__ w,
                          const float* __restrict__ bias,
                          float* __restrict__ dopnor) {
    int wave = threadIdx.x >> 6, lane = threadIdx.x & 63;
    for (int p = wave; p < 2 * B_; p += 4) {
        int b = p >> 1, j = p & 1;
        float s = 0.f;
        for (int h = lane; h < H_; h += 64) s += xmean[b * H_ + h] * w[j * H_ + h];
        s = wave64_sum(s);
        if (lane == 0) dopnor[p] = s / (float)S_ + bias[j];
    }
}

__global__ void gain_kernel(const float* __restrict__ xmean,
                            const float* __restrict__ gw,
                            const float* __restrict__ gb,
                            float* __restrict__ qscale) {
    int wave = threadIdx.x >> 6, lane = threadIdx.x & 63;
    for (int p = wave; p < B_ * N_; p += 4) {
        int b = p >> 2, n = p & 3;
        float s = 0.f;
        for (int h = lane; h < H_; h += 64) s += xmean[b * H_ + h] * gw[n * H_ + h];
        s = wave64_sum(s);
        if (lane == 0) qscale[p] = (1.f + s / (float)S_ + gb[n]) * 0.0625f;
    }
}

// ---------------------------------------------------------------------------
// GEMM: C(MxN) = epilogue( A(MxK) @ W(NxK)^T + bias )
// Round-10: BK=64 + both-sides XOR swizzle (r9, kept) + DOUBLE-BUFFERED
// staging (r2-flash pattern: issue next tile's global_load_lds -> compute
// current -> vmcnt(0)+barrier). Rationale: N=1024 gemm_bt grids are 512
// blocks -> only 2 blocks/CU resident (grid-limited TLP), so per-iter
// staging latency (~500-900cyc) was fully exposed between the 2 barriers.
// Dbuf hides it under compute; LDS 64 KB still admits 2 blocks -> no TLP
// loss. Accumulation order unchanged (bit-identical results).
// modes: 0 plain->bf16; 1 gate; 2 noise; 3 residual; 4 silu; 5 plain->fp32;
//        6 V^T store
// ---------------------------------------------------------------------------
__global__ __launch_bounds__(256) void gemm_bt(
    const unsigned short* __restrict__ A, const unsigned short* __restrict__ W,
    const float* __restrict__ bias, void* __restrict__ Cout,
    const unsigned short* __restrict__ X, const float* __restrict__ scal,
    int K, int Nout, int mode) {
    __shared__ unsigned short As[2][128 * 64];
    __shared__ unsigned short Bs[2][128 * 64];
    int tid = threadIdx.x;
    int wave = tid >> 6, lane = tid & 63;
    int quad = lane >> 4, l16 = lane & 15;
    int rx = l16 & 7;
    int bm = blockIdx.x * 128;
    int bn = blockIdx.y * 128;
    int mw = (wave >> 1) * 64, nw = (wave & 1) * 64;

    int srow = lane >> 3;                // 0..7: row within 8-row chunk
    int scol = ((lane & 7) ^ srow) * 8;  // pre-swizzled source col (shorts)

    f32x4 acc[4][4];
#pragma unroll
    for (int i = 0; i < 4; i++)
#pragma unroll
        for (int j = 0; j < 4; j++)
#pragma unroll
            for (int r = 0; r < 4; r++) acc[i][j][r] = 0.f;

    // prologue: stage tile kk=0 into buffer 0
#pragma unroll
    for (int k = 0; k < 4; k++) {
        int c = 4 * wave + k;
        gl_lds16(A + (size_t)(bm + 8 * c + srow) * K + scol, As[0] + c * 512);
        gl_lds16(W + (size_t)(bn + 8 * c + srow) * K + scol, Bs[0] + c * 512);
    }
    asm volatile("s_waitcnt vmcnt(0)" ::: "memory");
    __syncthreads();

    int cur = 0;
    for (int kk = 0; kk < K; kk += 64) {
        // issue next tile's loads into the other buffer (fly under compute)
        if (kk + 64 < K) {
            int nb = cur ^ 1;
#pragma unroll
            for (int k = 0; k < 4; k++) {
                int c = 4 * wave + k;
                gl_lds16(A + (size_t)(bm + 8 * c + srow) * K + kk + 64 + scol,
                         As[nb] + c * 512);
                gl_lds16(W + (size_t)(bn + 8 * c + srow) * K + kk + 64 + scol,
                         Bs[nb] + c * 512);
            }
        }

        const unsigned short* Ac = As[cur];
        const unsigned short* Bc = Bs[cur];
#pragma unroll
        for (int ks = 0; ks < 2; ks++) {
            short8 af[4], bfr[4];
#pragma unroll
            for (int i = 0; i < 4; i++)
                af[i] = *(const short8*)&Ac[(mw + i * 16 + l16) * 64 +
                                            (((ks * 4 + quad) ^ rx) * 8)];
#pragma unroll
            for (int j = 0; j < 4; j++)
                bfr[j] = *(const short8*)&Bc[(nw + j * 16 + l16) * 64 +
                                             (((ks * 4 + quad) ^ rx) * 8)];
#pragma unroll
            for (int i = 0; i < 4; i++)
#pragma unroll
                for (int j = 0; j < 4; j++)
                    acc[i][j] = __builtin_amdgcn_mfma_f32_16x16x32_bf16(af[i], bfr[j], acc[i][j], 0, 0, 0);
        }

        asm volatile("s_waitcnt vmcnt(0)" ::: "memory");
        __syncthreads();
        cur ^= 1;
    }

    if (mode == 6) {
#pragma unroll
        for (int i = 0; i < 4; i++) {
#pragma unroll
            for (int j = 0; j < 4; j++) {
                int col = bn + nw + j * 16 + l16;
                float bv = bias ? bias[col] : 0.f;
                int n = col >> 8, d = col & 255;
                int row0 = bm + mw + i * 16 + quad * 4;
                int b = row0 >> 11, s0 = row0 & 2047;
                union { unsigned short u[4]; uint2 v; } pk;
#pragma unroll
                for (int r = 0; r < 4; r++) pk.u[r] = f2bf(acc[i][j][r] + bv);
                *(uint2*)((unsigned short*)Cout +
                          ((size_t)(b * N_ + n) * D_ + d) * S_ + s0) = pk.v;
            }
        }
        return;
    }

#pragma unroll
    for (int i = 0; i < 4; i++) {
#pragma unroll
        for (int j = 0; j < 4; j++) {
            int col = bn + nw + j * 16 + l16;
            float bv = bias ? bias[col] : 0.f;
#pragma unroll
            for (int r = 0; r < 4; r++) {
                int row = bm + mw + i * 16 + quad * 4 + r;
                float v = acc[i][j][r] + bv;
                size_t off = (size_t)row * Nout + col;
                if (mode == 5) {
                    ((float*)Cout)[off] = v;
                    continue;
                }
                float outv;
                if (mode == 0) {
                    outv = v;
                } else if (mode == 1) {
                    float sig = 1.f / (1.f + __expf(-v));
                    float dop = scal[(row >> 11) * 2];
                    outv = bf2f(X[off]) * (1.f + dop * sig);
                } else if (mode == 2) {
                    float nor = scal[(row >> 11) * 2 + 1];
                    outv = bf2f(X[off]) + nor * tanhf(v);
                } else if (mode == 3) {
                    outv = v + bf2f(X[off]);
                } else {
                    outv = v * (1.f / (1.f + __expf(-v)));
                }
                ((unsigned short*)Cout)[off] = f2bf(outv);
            }
        }
    }
}

// ---------------------------------------------------------------------------
// Fused QKV GEMM: W is (3H x H) fused [q;k;v] for one layer. N=3072.
// r9 single-buffer BK=64 + swizzle kept (grid 1536 blocks -> 3 resident/CU;
// dbuf's 64KB LDS would cut TLP 3->2, net-negative risk).
// col block (64-aligned) selects destination: 0 -> Q, 1 -> K, 2 -> V^T store.
// ---------------------------------------------------------------------------
__global__ __launch_bounds__(256) void gemm_qkv(
    const unsigned short* __restrict__ A, const unsigned short* __restrict__ W,
    const float* __restrict__ qb, const float* __restrict__ kb,
    const float* __restrict__ vbb, unsigned short* __restrict__ Qo,
    unsigned short* __restrict__ Ko, unsigned short* __restrict__ Vt) {
    __shared__ unsigned short As[128 * 64];
    __shared__ unsigned short Bs[128 * 64];
    const int K = H_;
    int tid = threadIdx.x;
    int wave = tid >> 6, lane = tid & 63;
    int quad = lane >> 4, l16 = lane & 15;
    int rx = l16 & 7;
    int bm = blockIdx.x * 128;
    int bn = blockIdx.y * 128;
    int mw = (wave >> 1) * 64, nw = (wave & 1) * 64;

    int srow = lane >> 3;
    int scol = ((lane & 7) ^ srow) * 8;

    f32x4 acc[4][4];
#pragma unroll
    for (int i = 0; i < 4; i++)
#pragma unroll
        for (int j = 0; j < 4; j++)
#pragma unroll
            for (int r = 0; r < 4; r++) acc[i][j][r] = 0.f;

    for (int kk = 0; kk < K; kk += 64) {
        __syncthreads();
#pragma unroll
        for (int k = 0; k < 4; k++) {
            int c = 4 * wave + k;
            gl_lds16(A + (size_t)(bm + 8 * c + srow) * K + kk + scol, As + c * 512);
            gl_lds16(W + (size_t)(bn + 8 * c + srow) * K + kk + scol, Bs + c * 512);
        }
        __syncthreads();

#pragma unroll
        for (int ks = 0; ks < 2; ks++) {
            short8 af[4], bfr[4];
#pragma unroll
            for (int i = 0; i < 4; i++)
                af[i] = *(const short8*)&As[(mw + i * 16 + l16) * 64 +
                                            (((ks * 4 + quad) ^ rx) * 8)];
#pragma unroll
            for (int j = 0; j < 4; j++)
                bfr[j] = *(const short8*)&Bs[(nw + j * 16 + l16) * 64 +
                                             (((ks * 4 + quad) ^ rx) * 8)];
#pragma unroll
            for (int i = 0; i < 4; i++)
#pragma unroll
                for (int j = 0; j < 4; j++)
                    acc[i][j] = __builtin_amdgcn_mfma_f32_16x16x32_bf16(af[i], bfr[j], acc[i][j], 0, 0, 0);
        }
    }

    int sel = (bn + nw) >> 10;   // uniform per block-half
    if (sel == 2) {
#pragma unroll
        for (int i = 0; i < 4; i++) {
#pragma unroll
            for (int j = 0; j < 4; j++) {
                int c2 = ((bn + nw) & 1023) + j * 16 + l16;
                float bv = vbb[c2];
                int n = c2 >> 8, d = c2 & 255;
                int row0 = bm + mw + i * 16 + quad * 4;
                int b = row0 >> 11, s0 = row0 & 2047;
                union { unsigned short u[4]; uint2 v; } pk;
#pragma unroll
                for (int r = 0; r < 4; r++) pk.u[r] = f2bf(acc[i][j][r] + bv);
                *(uint2*)(Vt + ((size_t)(b * N_ + n) * D_ + d) * S_ + s0) = pk.v;
            }
        }
    } else {
        unsigned short* Co = (sel == 0) ? Qo : Ko;
        const float* bias = (sel == 0) ? qb : kb;
#pragma unroll
        for (int i = 0; i < 4; i++) {
#pragma unroll
            for (int j = 0; j < 4; j++) {
                int c2 = ((bn + nw) & 1023) + j * 16 + l16;
                float bv = bias[c2];
#pragma unroll
                for (int r = 0; r < 4; r++) {
                    int row = bm + mw + i * 16 + quad * 4 + r;
                    Co[(size_t)row * H_ + c2] = f2bf(acc[i][j][r] + bv);
                }
            }
        }
    }
}

// ---------------------------------------------------------------------------
// Flash attention (round-2/9 kernel, measured 123 us — unchanged).
// 512 thr = 8 waves x 16 q-rows, full t-range. Grid (S/128, B*N) = 256
// blocks, 1 block/CU, 2 waves/SIMD. Double-buffered K/V via global_load_lds
// (linear LDS dest), both-sides XOR swizzle (slot ^= row&7), one
// vmcnt(0)+barrier per tile. Ones-tile row-sum in Vones. Defer-max THR=8.
// LDS: 2*32K (K) + 2*32K (V) + 2.25K + 18K (Pl) = 148 KiB.
// ---------------------------------------------------------------------------
__global__ __launch_bounds__(512) void flash_attn(
    const unsigned short* __restrict__ Q, const unsigned short* __restrict__ Kg,
    const unsigned short* __restrict__ VT, const float* __restrict__ qscale,
    unsigned short* __restrict__ O) {
    __shared__ unsigned short Kb[2][64 * 256];   // [buf][row*256 + col], swizzled slots
    __shared__ unsigned short Vb[2][256 * 64];   // [buf][d*64 + col], swizzled slots
    __shared__ unsigned short Vones[16][72];     // ones tile for row-sum (padded)
    __shared__ unsigned short Pl[8][16][72];

    int tid = threadIdx.x;
    int wave = tid >> 6, lane = tid & 63;
    int quad = lane >> 4, l16 = lane & 15;
    int rx = l16 & 7;                            // read-side swizzle mask
    int bnh = blockIdx.y;
    size_t base = ((size_t)(bnh >> 2) * S_) * H_ + (size_t)(bnh & 3) * D_;
    size_t vtbase = (size_t)bnh * D_ * S_;
    int qw = blockIdx.x * 128 + wave * 16;
    float scale = qscale[bnh];

    for (int c = tid; c < 16 * 72; c += 512) {
        int rr = c / 72, cc = c - rr * 72;
        Vones[rr][cc] = (rr == 0) ? (unsigned short)0x3F80 : (unsigned short)0;
    }

    // staging source-side swizzle masks (per-lane constants)
    int l5 = lane >> 5;                 // K: which of 2 rows in a 1KB chunk
    int ks = lane & 31;                 // K: lds slot within row (16B units)
    int vrow = lane >> 3;               // V: which of 8 rows in a 1KB chunk
    int vs = lane & 7;                  // V: lds slot within row
    int vmask = vrow & 7;

    short8 qf[8];
#pragma unroll
    for (int kk = 0; kk < 8; kk++)
        qf[kk] = *(const short8*)(Q + base +
            (size_t)(qw + l16) * H_ + kk * 32 + quad * 8);

    f32x4 o[16], osum;
#pragma unroll
    for (int c = 0; c < 16; c++)
#pragma unroll
        for (int r = 0; r < 4; r++) o[c][r] = 0.f;
#pragma unroll
    for (int r = 0; r < 4; r++) osum[r] = 0.f;
    float mrow[4];
#pragma unroll
    for (int r = 0; r < 4; r++) mrow[r] = -1e30f;

    // prologue: stage tile 0 into buffer 0
    {
#pragma unroll
        for (int k = 0; k < 4; k++) {
            int chunk = 4 * wave + k;
            int kmask = (2 * k + l5) & 7;       // row&7 of the LDS row written
            int grow = 2 * chunk + l5;
            int gcol = ((ks ^ kmask)) * 8;
            gl_lds16(Kg + base + (size_t)grow * H_ + gcol, &Kb[0][chunk * 512]);
        }
#pragma unroll
        for (int k = 0; k < 4; k++) {
            int chunk = 4 * wave + k;
            int d = 8 * chunk + vrow;
            int gcol = ((vs ^ vmask)) * 8;
            gl_lds16(VT + vtbase + (size_t)d * S_ + gcol, &Vb[0][chunk * 512]);
        }
    }
    asm volatile("s_waitcnt vmcnt(0)" ::: "memory");
    __syncthreads();

    int cur = 0;
    for (int t0 = 0; t0 < S_; t0 += 64) {
        // issue next tile's loads into the other buffer (fly under compute)
        if (t0 + 64 < S_) {
            int nb = cur ^ 1;
#pragma unroll
            for (int k = 0; k < 4; k++) {
                int chunk = 4 * wave + k;
                int kmask = (2 * k + l5) & 7;
                int grow = t0 + 64 + 2 * chunk + l5;
                int gcol = ((ks ^ kmask)) * 8;
                gl_lds16(Kg + base + (size_t)grow * H_ + gcol, &Kb[nb][chunk * 512]);
            }
#pragma unroll
            for (int k = 0; k < 4; k++) {
                int chunk = 4 * wave + k;
                int d = 8 * chunk + vrow;
                int gcol = ((vs ^ vmask)) * 8;
                gl_lds16(VT + vtbase + (size_t)d * S_ + t0 + 64 + gcol, &Vb[nb][chunk * 512]);
            }
        }

        const unsigned short* Kc = Kb[cur];
        const unsigned short* Vc = Vb[cur];

        // QK^T for this wave's 16 rows (swizzled K reads)
        f32x4 s[4];
#pragma unroll
        for (int j = 0; j < 4; j++)
#pragma unroll
            for (int r = 0; r < 4; r++) s[j][r] = 0.f;
#pragma unroll
        for (int j = 0; j < 4; j++)
#pragma unroll
            for (int kk = 0; kk < 8; kk++) {
                short8 kf = *(const short8*)&Kc[(j * 16 + l16) * 256 +
                                                ((4 * kk + quad) ^ rx) * 8];
                s[j] = __builtin_amdgcn_mfma_f32_16x16x32_bf16(qf[kk], kf, s[j], 0, 0, 0);
            }

        // online softmax with defer-max (THR=8)
        float sv[4][4], mx[4];
        bool ok = true;
#pragma unroll
        for (int r = 0; r < 4; r++) {
#pragma unroll
            for (int j = 0; j < 4; j++) sv[r][j] = s[j][r] * scale;
            float m0 = fmaxf(fmaxf(sv[r][0], sv[r][1]), fmaxf(sv[r][2], sv[r][3]));
            for (int m = 8; m >= 1; m >>= 1) m0 = fmaxf(m0, __shfl_xor(m0, m, 64));
            mx[r] = m0;
            ok = ok && (m0 <= mrow[r] + 8.f);
        }
        if (__all(ok)) {
#pragma unroll
            for (int r = 0; r < 4; r++)
#pragma unroll
                for (int j = 0; j < 4; j++)
                    Pl[wave][quad * 4 + r][j * 16 + l16] =
                        f2bf(__expf(sv[r][j] - mrow[r]));
        } else {
            float alpha[4];
#pragma unroll
            for (int r = 0; r < 4; r++) {
                float mnew = fmaxf(mrow[r], mx[r]);
                alpha[r] = __expf(mrow[r] - mnew);
                mrow[r] = mnew;
#pragma unroll
                for (int j = 0; j < 4; j++)
                    Pl[wave][quad * 4 + r][j * 16 + l16] =
                        f2bf(__expf(sv[r][j] - mnew));
            }
#pragma unroll
            for (int c = 0; c < 16; c++)
#pragma unroll
                for (int r = 0; r < 4; r++) o[c][r] *= alpha[r];
#pragma unroll
            for (int r = 0; r < 4; r++) osum[r] *= alpha[r];
        }

        // PV (swizzled V reads)
        short8 pf0 = *(const short8*)&Pl[wave][l16][quad * 8];
        short8 pf1 = *(const short8*)&Pl[wave][l16][32 + quad * 8];
#pragma unroll
        for (int c = 0; c < 16; c++) {
            short8 vf0 = *(const short8*)&Vc[(c * 16 + l16) * 64 + (quad ^ rx) * 8];
            o[c] = __builtin_amdgcn_mfma_f32_16x16x32_bf16(pf0, vf0, o[c], 0, 0, 0);
            short8 vf1 = *(const short8*)&Vc[(c * 16 + l16) * 64 + ((4 | quad) ^ rx) * 8];
            o[c] = __builtin_amdgcn_mfma_f32_16x16x32_bf16(pf1, vf1, o[c], 0, 0, 0);
        }
        {
            short8 vs0 = *(const short8*)&Vones[l16][quad * 8];
            short8 vs1 = *(const short8*)&Vones[l16][32 + quad * 8];
            osum = __builtin_amdgcn_mfma_f32_16x16x32_bf16(pf0, vs0, osum, 0, 0, 0);
            osum = __builtin_amdgcn_mfma_f32_16x16x32_bf16(pf1, vs1, osum, 0, 0, 0);
        }

        // next tile must have landed; all waves done reading current buffers
        asm volatile("s_waitcnt vmcnt(0)" ::: "memory");
        __syncthreads();
        cur ^= 1;
    }

    float invl[4];
#pragma unroll
    for (int r = 0; r < 4; r++)
        invl[r] = 1.f / __shfl(osum[r], (lane & 48), 64);
#pragma unroll
    for (int c = 0; c < 16; c++)
#pragma unroll
        for (int r = 0; r < 4; r++) {
            int row = qw + quad * 4 + r;
            int d = c * 16 + l16;
            O[base + (size_t)row * H_ + d] = f2bf(o[c][r] * invl[r]);
        }
}

// ---------------------------------------------------------------------------
__global__ __launch_bounds__(256) void ln_kernel(
    const unsigned short* __restrict__ y, const float* __restrict__ g,
    const float* __restrict__ bta, unsigned short* __restrict__ out) {
    int row = blockIdx.x;
    size_t ro = (size_t)row * H_;
    int tid = threadIdx.x;
    float t[4]; float s = 0.f, s2 = 0.f;
#pragma unroll
    for (int i = 0; i < 4; i++) {
        int h = i * 256 + tid;
        float v = bf2f(y[ro + h]);
        t[i] = v; s += v; s2 += v * v;
    }
    s = wave64_sum(s); s2 = wave64_sum(s2);
    __shared__ float sh[8];
    int wave = tid >> 6, lane = tid & 63;
    if (lane == 0) { sh[wave] = s; sh[4 + wave] = s2; }
    __syncthreads();
    s  = sh[0] + sh[1] + sh[2] + sh[3];
    s2 = sh[4] + sh[5] + sh[6] + sh[7];
    float mu = s * (1.f / H_);
    float var = s2 * (1.f / H_) - mu * mu;
    float inv = rsqrtf(var + EPSF);
#pragma unroll
    for (int i = 0; i < 4; i++) {
        int h = i * 256 + tid;
        out[ro + h] = f2bf((t[i] - mu) * inv * g[h] + bta[h]);
    }
}

// ---------------------------------------------------------------------------
extern "C" void kernel_launch(void* const* d_in, const int* in_sizes, int n_in,
                              void* d_out, int out_size, void* d_ws, size_t ws_size,
                              hipStream_t stream) {
    const int*   ids          = (const int*)d_in[0];
    const float* embed        = (const float*)d_in[1];
    const float* nm_gate_w    = (const float*)d_in[2];
    const float* nm_gate_b    = (const float*)d_in[3];
    const float* nm_filter_w  = (const float*)d_in[4];
    const float* nm_filter_b  = (const float*)d_in[5];
    const float* nm_ctx_w     = (const float*)d_in[6];
    const float* nm_ctx_b     = (const float*)d_in[7];
    const float* q_w          = (const float*)d_in[8];
    const float* q_b          = (const float*)d_in[9];
    const float* k_w          = (const float*)d_in[10];
    const float* k_b          = (const float*)d_in[11];
    const float* v_w          = (const float*)d_in[12];
    const float* v_b          = (const float*)d_in[13];
    const float* gain_w       = (const float*)d_in[14];
    const float* gain_b       = (const float*)d_in[15];
    const float* attn_ow      = (const float*)d_in[16];
    const float* attn_ob      = (const float*)d_in[17];
    const float* en_w         = (const float*)d_in[18];
    const float* en_b         = (const float*)d_in[19];
    const float* plastic_w    = (const float*)d_in[20];
    const float* fix_w        = (const float*)d_in[21];
    const float* fix_b        = (const float*)d_in[22];
    const float* ln_g         = (const float*)d_in[23];
    const float* ln_b         = (const float*)d_in[24];
    const float* out_w        = (const float*)d_in[25];
    const float* out_b        = (const float*)d_in[26];

    size_t T  = (size_t)B_ * S_ * H_;
    size_t smallBytes = ((size_t)B_ * H_ + 2 * B_ + B_ * N_ + 8) * sizeof(float);
    size_t megaElems  = 26 * WH_ + WH_ / 4;
    size_t need_base  = 4 * T * 2 + smallBytes + 2 * WH_;
    size_t need_mega  = 4 * T * 2 + smallBytes + 2 * megaElems;
    if (ws_size < need_base) return;
    bool mega = ws_size >= need_mega;

    unsigned short* X   = (unsigned short*)d_ws;
    unsigned short* Qb  = X + T;
    unsigned short* Kb  = Qb + T;
    unsigned short* Vb  = Kb + T;
    float* xmean  = (float*)(Vb + T);
    float* dopnor = xmean + (size_t)B_ * H_;
    float* qscale = dopnor + 2 * B_;
    unsigned short* Wbase = (unsigned short*)(qscale + B_ * N_ + 8);
#define WOFF(k) (Wbase + (size_t)(k) * WH_)

    const int M   = B_ * S_;
    const int W8  = (int)(WH_ / 8);
    const int WG  = (W8 + 255) / 256;
    const int W84 = (int)(4 * WH_ / 8);
    const int WG4 = (W84 + 255) / 256;
    const int W8o = V_ * H_ / 8;
    const int WGo = (W8o + 255) / 256;

    if (mega) {
        wcvt_kernel<<<WG,  256, 0, stream>>>(nm_gate_w,   WOFF(0), W8);
        wcvt_kernel<<<WG,  256, 0, stream>>>(nm_filter_w, WOFF(1), W8);
        wcvt_qkv<<<WG4, 256, 0, stream>>>(q_w, WOFF(2), W84, 0);
        wcvt_qkv<<<WG4, 256, 0, stream>>>(k_w, WOFF(2), W84, 1);
        wcvt_qkv<<<WG4, 256, 0, stream>>>(v_w, WOFF(2), W84, 2);
        wcvt_kernel<<<WG4, 256, 0, stream>>>(attn_ow, WOFF(14), W84);
        wcvt_kernel<<<WG4, 256, 0, stream>>>(en_w,    WOFF(18), W84);
        wadd_kernel<<<WG4, 256, 0, stream>>>(fix_w, plastic_w, WOFF(22), W84);
        wcvt_kernel<<<WGo, 256, 0, stream>>>(out_w, WOFF(26), W8o);
    }

    gather_kernel<<<dim3((int)(T / 256)), 256, 0, stream>>>(ids, embed, X);

    hipMemsetAsync(xmean, 0, (size_t)B_ * H_ * sizeof(float), stream);
    mean_kernel<<<dim3(B_ * H_ / 256, 16), 256, 0, stream>>>(X, xmean);
    nm_kernel<<<1, 256, 0, stream>>>(xmean, nm_ctx_w, nm_ctx_b, dopnor);

    const unsigned short* Wp;
    if (mega) Wp = WOFF(0);
    else { wcvt_kernel<<<WG, 256, 0, stream>>>(nm_gate_w, Wbase, W8); Wp = Wbase; }
    gemm_bt<<<dim3(M / 128, H_ / 128), 256, 0, stream>>>(
        X, Wp, nm_gate_b, Qb, X, dopnor, H_, H_, 1);
    if (mega) Wp = WOFF(1);
    else { wcvt_kernel<<<WG, 256, 0, stream>>>(nm_filter_w, Wbase, W8); Wp = Wbase; }
    gemm_bt<<<dim3(M / 128, H_ / 128), 256, 0, stream>>>(
        Qb, Wp, nm_filter_b, X, Qb, dopnor, H_, H_, 2);

    for (int l = 0; l < L_; l++) {
        size_t wo = (size_t)l * WH_;
        size_t bo = (size_t)l * H_;
        hipMemsetAsync(xmean, 0, (size_t)B_ * H_ * sizeof(float), stream);
        mean_kernel<<<dim3(B_ * H_ / 256, 16), 256, 0, stream>>>(X, xmean);
        gain_kernel<<<1, 256, 0, stream>>>(xmean, gain_w + (size_t)l * N_ * H_,
                                           gain_b + (size_t)l * N_, qscale);

        if (mega) {
            gemm_qkv<<<dim3(M / 128, 3 * H_ / 128), 256, 0, stream>>>(
                X, WOFF(2) + (size_t)l * 3 * WH_, q_b + bo, k_b + bo, v_b + bo,
                Qb, Kb, Vb);
        } else {
            wcvt_kernel<<<WG, 256, 0, stream>>>(q_w + wo, Wbase, W8);
            gemm_bt<<<dim3(M / 128, H_ / 128), 256, 0, stream>>>(
                X, Wbase, q_b + bo, Qb, nullptr, nullptr, H_, H_, 0);
            wcvt_kernel<<<WG, 256, 0, stream>>>(k_w + wo, Wbase, W8);
            gemm_bt<<<dim3(M / 128, H_ / 128), 256, 0, stream>>>(
                X, Wbase, k_b + bo, Kb, nullptr, nullptr, H_, H_, 0);
            wcvt_kernel<<<WG, 256, 0, stream>>>(v_w + wo, Wbase, W8);
            gemm_bt<<<dim3(M / 128, H_ / 128), 256, 0, stream>>>(
                X, Wbase, v_b + bo, Vb, nullptr, nullptr, H_, H_, 6);
        }

        flash_attn<<<dim3(S_ / 128, B_ * N_), 512, 0, stream>>>(
            Qb, Kb, Vb, qscale, Qb);

        if (mega) Wp = WOFF(14) + wo;
        else { wcvt_kernel<<<WG, 256, 0, stream>>>(attn_ow + wo, Wbase, W8); Wp = Wbase; }
        gemm_bt<<<dim3(M / 128, H_ / 128), 256, 0, stream>>>(
            Qb, Wp, attn_ob + bo, Kb, X, nullptr, H_, H_, 3);
        if (mega) Wp = WOFF(18) + wo;
        else { wcvt_kernel<<<WG, 256, 0, stream>>>(en_w + wo, Wbase, W8); Wp = Wbase; }
        gemm_bt<<<dim3(M / 128, H_ / 128), 256, 0, stream>>>(
            Kb, Wp, en_b + bo, Vb, nullptr, nullptr, H_, H_, 4);
        if (mega) Wp = WOFF(22) + wo;
        else { wadd_kernel<<<WG, 256, 0, stream>>>(fix_w + wo, plastic_w + wo, Wbase, W8); Wp = Wbase; }
        gemm_bt<<<dim3(M / 128, H_ / 128), 256, 0, stream>>>(
            Vb, Wp, fix_b + bo, Qb, nullptr, nullptr, H_, H_, 0);
        ln_kernel<<<dim3(M), 256, 0, stream>>>(Qb, ln_g + bo, ln_b + bo, X);
    }

    if (mega) Wp = WOFF(26);
    else { wcvt_kernel<<<WGo, 256, 0, stream>>>(out_w, Wbase, W8o); Wp = Wbase; }
    gemm_bt<<<dim3(M / 128, V_ / 128), 256, 0, stream>>>(
        X, Wp, out_b, (float*)d_out, nullptr, nullptr, H_, V_, 5);
#undef WOFF
}